// Round 1
// baseline (14911.349 us; speedup 1.0000x reference)
//
#include <hip/hip_runtime.h>
#include <hip/hip_bf16.h>

// ---------------- constants ----------------
#define Bq 32
#define Tq 16
#define Gq 512
#define NSEQ 528           // T + G
#define Cq 384
#define Hq 6
#define Sq 128
#define Kg 32              // GROUP_SIZE
#define ROWS (Bq*NSEQ)     // 16896
#define LS 386             // padded LDS row stride (float2-friendly, conflict-free)

__device__ __forceinline__ float gelu_f(float x){
    return 0.5f * x * (1.0f + erff(x * 0.70710678118654752f));
}

// ---------------- build X = concat(prompt, x) ----------------
__global__ void __launch_bounds__(256) build_x(const float* __restrict__ xin,
    const float* __restrict__ pe, float* __restrict__ X, long total)
{
    long gid = (long)blockIdx.x*256 + threadIdx.x;
    if (gid >= total) return;
    int  c   = (int)(gid % Cq);
    long row = gid / Cq;
    int  p   = (int)(row % NSEQ);
    long b   = row / NSEQ;
    float v = (p < Tq) ? pe[p*Cq + c] : xin[(b*Gq + (p - Tq))*Cq + c];
    X[gid] = v;
}

// ---------------- LayerNorm, one wave per row ----------------
__global__ void __launch_bounds__(256) ln_rows(const float* __restrict__ in,
    const float* __restrict__ gw, const float* __restrict__ bw,
    float* __restrict__ out, int rows)
{
    int w = threadIdx.x >> 6, lane = threadIdx.x & 63;
    int row = blockIdx.x*4 + w;
    if (row >= rows) return;
    const float* xr = in + (long)row*Cq;
    float v[6]; float s = 0.f, s2 = 0.f;
#pragma unroll
    for (int j = 0; j < 6; j++){ float x = xr[lane + 64*j]; v[j] = x; s += x; s2 += x*x; }
#pragma unroll
    for (int m = 1; m < 64; m <<= 1){ s += __shfl_xor(s, m); s2 += __shfl_xor(s2, m); }
    float mean = s * (1.f/384.f);
    float var  = s2 * (1.f/384.f) - mean*mean;
    float rs   = rsqrtf(var + 1e-5f);
    float* orow = out + (long)row*Cq;
#pragma unroll
    for (int j = 0; j < 6; j++){
        int c = lane + 64*j;
        orow[c] = (v[j] - mean) * rs * gw[c] + bw[c];
    }
}

// ---------------- generic fp32 GEMM: C = epi(A @ W^T) ----------------
// A: M x K row-major, W: N x K row-major, C: M x N.
// epi: 0 none, 1 +bias, 2 gelu(+bias), 3 C += (acc + bias)  (in-place residual)
__global__ void __launch_bounds__(256) gemm_f32(const float* __restrict__ A,
    const float* __restrict__ W, const float* __restrict__ bias,
    float* __restrict__ C, int M, int N, int K, int epi)
{
    __shared__ float As[16][65];
    __shared__ float Ws[16][65];
    int tid = threadIdx.x;
    int m0 = blockIdx.y*64, n0 = blockIdx.x*64;
    int tm = tid >> 4, tn = tid & 15;
    int lr = tid >> 2;           // 0..63
    int lc4 = (tid & 3) * 4;     // 0,4,8,12
    float acc[4][4] = {};
    for (int k0 = 0; k0 < K; k0 += 16){
        {
            int m = m0 + lr;
            float4 v = make_float4(0.f,0.f,0.f,0.f);
            if (m < M) v = *(const float4*)(A + (long)m*K + k0 + lc4);
            As[lc4+0][lr] = v.x; As[lc4+1][lr] = v.y; As[lc4+2][lr] = v.z; As[lc4+3][lr] = v.w;
            int n = n0 + lr;
            float4 wv = make_float4(0.f,0.f,0.f,0.f);
            if (n < N) wv = *(const float4*)(W + (long)n*K + k0 + lc4);
            Ws[lc4+0][lr] = wv.x; Ws[lc4+1][lr] = wv.y; Ws[lc4+2][lr] = wv.z; Ws[lc4+3][lr] = wv.w;
        }
        __syncthreads();
#pragma unroll
        for (int kk = 0; kk < 16; kk++){
            float a[4], bb[4];
#pragma unroll
            for (int i = 0; i < 4; i++) a[i]  = As[kk][tm + 16*i];
#pragma unroll
            for (int j = 0; j < 4; j++) bb[j] = Ws[kk][tn + 16*j];
#pragma unroll
            for (int i = 0; i < 4; i++)
#pragma unroll
                for (int j = 0; j < 4; j++) acc[i][j] += a[i]*bb[j];
        }
        __syncthreads();
    }
#pragma unroll
    for (int i = 0; i < 4; i++){
        int m = m0 + tm + 16*i; if (m >= M) continue;
#pragma unroll
        for (int j = 0; j < 4; j++){
            int n = n0 + tn + 16*j; if (n >= N) continue;
            float v = acc[i][j];
            if (epi >= 1 && bias) v += bias[n];
            if (epi == 2) v = gelu_f(v);
            long off = (long)m*N + n;
            if (epi == 3) v += C[off];
            C[off] = v;
        }
    }
}

// ---------------- global attention: one wave per query row ----------------
// qkv: (B, NSEQ, 1152) with channel = comp*384 + h*64 + d. out: (B, NSEQ, 384).
__global__ void __launch_bounds__(256) attn_global(const float* __restrict__ qkv,
    const float* __restrict__ mask, float* __restrict__ out)
{
    __shared__ float qsh[4][64];
    __shared__ float sc[4][NSEQ];
    int blk = blockIdx.x;
    int qt = blk % 132; int bh = blk / 132;
    int h = bh % Hq;    int b = bh / Hq;
    int lane = threadIdx.x & 63, w = threadIdx.x >> 6;
    int qi = qt*4 + w;
    qsh[w][lane] = qkv[((long)(b*NSEQ + qi))*1152 + h*64 + lane];
    __syncthreads();
    const float* kbase = qkv + ((long)b*NSEQ)*1152 + 384 + h*64;
    const float* mrow  = mask + ((long)b*Gq + qi)*Gq;
    for (int j0 = 0; j0 < NSEQ; j0 += 64){
        int j = j0 + lane;
        if (j < NSEQ){
            const float4* kr4 = (const float4*)(kbase + (long)j*1152);
            float s = 0.f;
#pragma unroll
            for (int d4 = 0; d4 < 16; d4++){
                float4 kv = kr4[d4];
                s += qsh[w][4*d4+0]*kv.x + qsh[w][4*d4+1]*kv.y
                   + qsh[w][4*d4+2]*kv.z + qsh[w][4*d4+3]*kv.w;
            }
            s *= 0.125f;
            if (qi < Gq && j < Gq) s -= 100000.0f * mrow[j];
            sc[w][j] = s;
        }
    }
    float mx = -3e38f;
    for (int t = 0; t < 9; t++){ int j = lane + 64*t; if (j < NSEQ) mx = fmaxf(mx, sc[w][j]); }
#pragma unroll
    for (int m = 1; m < 64; m <<= 1) mx = fmaxf(mx, __shfl_xor(mx, m));
    float sm = 0.f;
    for (int t = 0; t < 9; t++){
        int j = lane + 64*t;
        if (j < NSEQ){ float e = expf(sc[w][j] - mx); sc[w][j] = e; sm += e; }
    }
#pragma unroll
    for (int m = 1; m < 64; m <<= 1) sm += __shfl_xor(sm, m);
    float inv = 1.0f / sm;
    const float* vbase = qkv + ((long)b*NSEQ)*1152 + 768 + h*64;
    float o = 0.f;
    for (int j = 0; j < NSEQ; j++) o += sc[w][j] * vbase[(long)j*1152 + lane];
    out[((long)(b*NSEQ + qi))*Cq + h*64 + lane] = o * inv;
}

// ---------------- adapter up-projection + combine ----------------
// out = gate*(hid @ uw^T + ub + src) + (res ? res : 0)
__global__ void __launch_bounds__(256) adapter_up(const float* __restrict__ hid,
    const float* __restrict__ uw, const float* __restrict__ ub,
    const float* __restrict__ src, const float* __restrict__ res,
    const float* __restrict__ gatep, float* __restrict__ out, long total)
{
    long gid = (long)blockIdx.x*256 + threadIdx.x;
    if (gid >= total) return;
    long m = gid / Cq; int c = (int)(gid % Cq);
    const float* hr = hid + m*16;
    const float* ur = uw + c*16;
    float acc = 0.f;
#pragma unroll
    for (int r = 0; r < 16; r++) acc += hr[r]*ur[r];
    float gate = gatep ? gatep[0] : 1.0f;
    float v = gate * (acc + ub[c] + src[gid]);
    if (res) v += res[gid];
    out[gid] = v;
}

// ---------------- fused local branch: one block per group ----------------
// gather(idx) -> LN(n3) -> per-head QKV -> 32x32 attn -> proj + residual
// -> max+mean pool over K -> gelu(bn) + 0.4*center -> vis (B*S, 384)
__global__ void __launch_bounds__(512) local_attn(const float* __restrict__ Xf,
    const int* __restrict__ idx, const int* __restrict__ cidx,
    const float* __restrict__ g3, const float* __restrict__ b3,
    const float* __restrict__ qw, const float* __restrict__ pw,
    const float* __restrict__ pb, const float* __restrict__ bng,
    const float* __restrict__ bnb, float* __restrict__ vis)
{
    __shared__ float xln[32*LS];
    __shared__ float aout[32*LS];
    __shared__ float qh[32*65];
    __shared__ float kh[32*65];
    __shared__ float vh[32*65];
    __shared__ float sc[32*33];
    __shared__ float srow[32];
    __shared__ int   rows[32];
    int g = blockIdx.x;
    int tid = threadIdx.x;
    int lane = tid & 63, w = tid >> 6;
    if (tid < 32) rows[tid] = idx[g*Kg + tid];
    __syncthreads();
    // phase 0: gather + LN (one wave per token, 4 tokens per wave)
    for (int t = w; t < 32; t += 8){
        const float* xr = Xf + (long)rows[t]*Cq;
        float v[6]; float s = 0.f, s2 = 0.f;
#pragma unroll
        for (int j = 0; j < 6; j++){ float x = xr[lane + 64*j]; v[j] = x; s += x; s2 += x*x; }
#pragma unroll
        for (int m = 1; m < 64; m <<= 1){ s += __shfl_xor(s, m); s2 += __shfl_xor(s2, m); }
        float mean = s * (1.f/384.f);
        float var  = s2 * (1.f/384.f) - mean*mean;
        float rs   = rsqrtf(var + 1e-5f);
#pragma unroll
        for (int j = 0; j < 6; j++){
            int c = lane + 64*j;
            xln[t*LS + c] = (v[j] - mean)*rs*g3[c] + b3[c];
        }
    }
    __syncthreads();
    int tx = tid & 31, ty = tid >> 5;   // token lane, output-channel group
    for (int h = 0; h < Hq; h++){
        // per-head QKV: 192 out-chans, ty handles oc = ty + 16r, r<12
        {
            float acc[12];
            const float* wp[12];
#pragma unroll
            for (int r = 0; r < 12; r++){
                acc[r] = 0.f;
                int oc = ty + 16*r;
                wp[r] = qw + (long)((oc >> 6)*Cq + h*64 + (oc & 63))*Cq;
            }
            const float* xp = xln + tx*LS;
            for (int k = 0; k < Cq; k += 2){
                float2 xv = *(const float2*)(xp + k);
#pragma unroll
                for (int r = 0; r < 12; r++){
                    float2 wv = *(const float2*)(wp[r] + k);
                    acc[r] += xv.x*wv.x + xv.y*wv.y;
                }
            }
#pragma unroll
            for (int r = 0; r < 12; r++){
                int oc = ty + 16*r; int d = oc & 63;
                float* dst = (oc < 64) ? qh : (oc < 128 ? kh : vh);
                dst[tx*65 + d] = acc[r];
            }
        }
        __syncthreads();
        // scores 32x32
        {
            int j = tx; int i0 = ty;
#pragma unroll
            for (int ii = 0; ii < 2; ii++){
                int i = i0 + 16*ii;
                const float* qp = qh + i*65; const float* kp = kh + j*65;
                float s = 0.f;
#pragma unroll
                for (int d = 0; d < 64; d++) s += qp[d]*kp[d];
                sc[i*33 + j] = s*0.125f;
            }
        }
        __syncthreads();
        if (tid < 32){
            float mx = -3e38f;
            for (int j = 0; j < 32; j++) mx = fmaxf(mx, sc[tid*33 + j]);
            float sm = 0.f;
            for (int j = 0; j < 32; j++){
                float e = expf(sc[tid*33 + j] - mx); sc[tid*33 + j] = e; sm += e;
            }
            srow[tid] = 1.f/sm;
        }
        __syncthreads();
        // PV
        {
            int d = tid & 63; int i0 = tid >> 6;
#pragma unroll
            for (int ii = 0; ii < 4; ii++){
                int i = i0 + 8*ii;
                const float* pp = sc + i*33;
                float o = 0.f;
#pragma unroll
                for (int j = 0; j < 32; j++) o += pp[j]*vh[j*65 + d];
                aout[i*LS + h*64 + d] = o * srow[i];
            }
        }
        __syncthreads();
    }
    // phase 2: proj + bias + residual, then pool over tokens (lanes 0..31 per half-wave)
    int crow = cidx[g];
    const float* ap = aout + tx*LS;
#pragma unroll
    for (int r0 = 0; r0 < 24; r0 += 8){
        float po[8];
        const float* wpp[8];
#pragma unroll
        for (int r = 0; r < 8; r++){ po[r] = 0.f; wpp[r] = pw + (long)(ty + 16*(r0 + r))*Cq; }
        for (int k = 0; k < Cq; k += 2){
            float2 av = *(const float2*)(ap + k);
#pragma unroll
            for (int r = 0; r < 8; r++){
                float2 wv = *(const float2*)(wpp[r] + k);
                po[r] += av.x*wv.x + av.y*wv.y;
            }
        }
#pragma unroll
        for (int r = 0; r < 8; r++){
            int c = ty + 16*(r0 + r);
            float val = po[r] + pb[c] + Xf[(long)rows[tx]*Cq + c];
            float mx = val, sm = val;
#pragma unroll
            for (int m = 1; m < 32; m <<= 1){
                mx = fmaxf(mx, __shfl_xor(mx, m));
                sm += __shfl_xor(sm, m);
            }
            if ((tid & 31) == 0){
                float lc = mx + sm*(1.f/32.f);
                float u = lc * bng[c] * 0.9999950000374997f + bnb[c];  // rsqrt(1+1e-5)
                u = gelu_f(u);
                vis[(long)g*Cq + c] = u + 0.4f * Xf[(long)crow*Cq + c];
            }
        }
    }
}

// ---------------- inverse-distance interpolation + residual ----------------
__global__ void __launch_bounds__(128) interp_k(const float* __restrict__ Xf,
    const float* __restrict__ vis, const float* __restrict__ c1,
    const float* __restrict__ c2, float* __restrict__ newx)
{
    __shared__ float wsh[128];
    __shared__ float tot[2];
    int bn = blockIdx.x; int b = bn >> 9; int n = bn & 511;
    int tid = threadIdx.x;
    const float* p1 = c1 + (long)bn*3;
    float x1 = p1[0], y1 = p1[1], z1 = p1[2];
    const float* p2 = c2 + ((long)b*Sq + tid)*3;
    float x2 = p2[0], y2 = p2[1], z2 = p2[2];
    float d = (x1*x1 + y1*y1 + z1*z1) + (x2*x2 + y2*y2 + z2*z2)
            - 2.f*(x1*x2 + y1*y2 + z1*z2);
    float wv = 1.f/(d + 1e-8f);
    wsh[tid] = wv;
    float ss = wv;
#pragma unroll
    for (int m = 1; m < 64; m <<= 1) ss += __shfl_xor(ss, m);
    if ((tid & 63) == 0) tot[tid >> 6] = ss;
    __syncthreads();
    float inv = 1.f/(tot[0] + tot[1]);
    const float* vb = vis + (long)b*Sq*Cq;
    float a0 = 0.f, a1 = 0.f, a2 = 0.f;
    for (int s = 0; s < Sq; s++){
        float wq = wsh[s];
        const float* vr = vb + s*Cq + tid;
        a0 += wq*vr[0]; a1 += wq*vr[128]; a2 += wq*vr[256];
    }
    const float* xr = Xf + ((long)(b*NSEQ + Tq + n))*Cq;
    float* orow = newx + (long)bn*Cq;
    orow[tid]       = xr[tid]       + 0.4f*a0*inv;
    orow[tid + 128] = xr[tid + 128] + 0.4f*a1*inv;
    orow[tid + 256] = xr[tid + 256] + 0.4f*a2*inv;
}

// ---------------- launch ----------------
extern "C" void kernel_launch(void* const* d_in, const int* in_sizes, int n_in,
                              void* d_out, int out_size, void* d_ws, size_t ws_size,
                              hipStream_t stream)
{
    const float* x_in  = (const float*)d_in[0];
    const float* mask  = (const float*)d_in[1];
    const float* c1p   = (const float*)d_in[2];
    const float* c2p   = (const float*)d_in[3];
    // d_in[4] = neighborhood (unused by reference)
    const float* pe    = (const float*)d_in[5];
    const float* n1g   = (const float*)d_in[6];
    const float* n1b   = (const float*)d_in[7];
    const float* qkvw  = (const float*)d_in[8];
    const float* projw = (const float*)d_in[9];
    const float* projb = (const float*)d_in[10];
    const float* n2g   = (const float*)d_in[11];
    const float* n2b   = (const float*)d_in[12];
    const float* fc1w  = (const float*)d_in[13];
    const float* fc1b  = (const float*)d_in[14];
    const float* fc2w  = (const float*)d_in[15];
    const float* fc2b  = (const float*)d_in[16];
    const float* gate  = (const float*)d_in[17];
    const float* addw  = (const float*)d_in[18];
    const float* addb  = (const float*)d_in[19];
    const float* aduw  = (const float*)d_in[20];
    const float* adub  = (const float*)d_in[21];
    const float* ad1dw = (const float*)d_in[22];
    const float* ad1db = (const float*)d_in[23];
    const float* ad1uw = (const float*)d_in[24];
    const float* ad1ub = (const float*)d_in[25];
    const float* bng   = (const float*)d_in[26];
    const float* bnb   = (const float*)d_in[27];
    const float* a1qkvw= (const float*)d_in[28];
    const float* a1pw  = (const float*)d_in[29];
    const float* a1pb  = (const float*)d_in[30];
    const float* n3g   = (const float*)d_in[31];
    const float* n3b   = (const float*)d_in[32];
    const int*   idxp  = (const int*)d_in[33];
    const int*   cidxp = (const int*)d_in[34];

    float* ws = (float*)d_ws;
    float* X  = ws;                        // 16896 x 384
    float* Bb = X  + (long)ROWS*Cq;        // 16896 x 384 (ln_out / newx)
    float* Ab = Bb + (long)ROWS*Cq;        // 16896 x 1536 (qkv / mlp hidden)
    float* C1 = Ab + (long)ROWS*1536;      // 16896 x 384 (attn_out / x_fn)
    float* D1 = C1 + (long)ROWS*Cq;        // 16896 x 16  (adapter hidden)
    float* V  = D1 + (long)ROWS*16;        // 4096 x 384  (vis_x)

    long totX = (long)ROWS*Cq;             // 6488064

    build_x<<<25344, 256, 0, stream>>>(x_in, pe, X, totX);
    ln_rows<<<4224, 256, 0, stream>>>(X, n1g, n1b, Bb, ROWS);
    gemm_f32<<<dim3(18, 264), 256, 0, stream>>>(Bb, qkvw, nullptr, Ab, ROWS, 1152, 384, 0);
    attn_global<<<25344, 256, 0, stream>>>(Ab, mask, C1);
    gemm_f32<<<dim3(6, 264), 256, 0, stream>>>(C1, projw, projb, X, ROWS, 384, 384, 3);
    ln_rows<<<4224, 256, 0, stream>>>(X, n2g, n2b, Bb, ROWS);
    gemm_f32<<<dim3(24, 264), 256, 0, stream>>>(Bb, fc1w, fc1b, Ab, ROWS, 1536, 384, 2);
    gemm_f32<<<dim3(6, 264), 256, 0, stream>>>(Ab, fc2w, fc2b, C1, ROWS, 384, 1536, 1);
    gemm_f32<<<dim3(1, 264), 256, 0, stream>>>(C1, addw, addb, D1, ROWS, 16, 384, 2);
    adapter_up<<<25344, 256, 0, stream>>>(D1, aduw, adub, C1, X, gate, X, totX);
    local_attn<<<4096, 512, 0, stream>>>(X, idxp, cidxp, n3g, n3b, a1qkvw, a1pw, a1pb,
                                         bng, bnb, V);
    interp_k<<<16384, 128, 0, stream>>>(X, V, c1p, c2p, Bb);
    gemm_f32<<<dim3(1, 256), 256, 0, stream>>>(Bb, ad1dw, ad1db, D1, Bq*Gq, 16, 384, 2);
    adapter_up<<<24576, 256, 0, stream>>>(D1, ad1uw, ad1ub, Bb, nullptr, nullptr,
                                          (float*)d_out, (long)Bq*Gq*Cq);
}

// Round 2
// 6336.537 us; speedup vs baseline: 2.3532x; 2.3532x over previous
//
#include <hip/hip_runtime.h>
#include <hip/hip_bf16.h>

// ---------------- constants ----------------
#define Bq 32
#define Tq 16
#define Gq 512
#define NSEQ 528           // T + G
#define Cq 384
#define Hq 6
#define Sq 128
#define Kg 32              // GROUP_SIZE
#define ROWS (Bq*NSEQ)     // 16896
#define HPAD 68            // per-head LDS row stride (16B-aligned rows)
#define APAD 388           // attention-out LDS row stride (16B-aligned rows)

__device__ __forceinline__ float gelu_f(float x){
    return 0.5f * x * (1.0f + erff(x * 0.70710678118654752f));
}

// ---------------- build X = concat(prompt, x) ----------------
__global__ void __launch_bounds__(256) build_x(const float* __restrict__ xin,
    const float* __restrict__ pe, float* __restrict__ X, long total)
{
    long gid = (long)blockIdx.x*256 + threadIdx.x;
    if (gid >= total) return;
    int  c   = (int)(gid % Cq);
    long row = gid / Cq;
    int  p   = (int)(row % NSEQ);
    long b   = row / NSEQ;
    float v = (p < Tq) ? pe[p*Cq + c] : xin[(b*Gq + (p - Tq))*Cq + c];
    X[gid] = v;
}

// ---------------- LayerNorm, one wave per row ----------------
__global__ void __launch_bounds__(256) ln_rows(const float* __restrict__ in,
    const float* __restrict__ gw, const float* __restrict__ bw,
    float* __restrict__ out, int rows)
{
    int w = threadIdx.x >> 6, lane = threadIdx.x & 63;
    int row = blockIdx.x*4 + w;
    if (row >= rows) return;
    const float* xr = in + (long)row*Cq;
    float v[6]; float s = 0.f, s2 = 0.f;
#pragma unroll
    for (int j = 0; j < 6; j++){ float x = xr[lane + 64*j]; v[j] = x; s += x; s2 += x*x; }
#pragma unroll
    for (int m = 1; m < 64; m <<= 1){ s += __shfl_xor(s, m); s2 += __shfl_xor(s2, m); }
    float mean = s * (1.f/384.f);
    float var  = s2 * (1.f/384.f) - mean*mean;
    float rs   = rsqrtf(var + 1e-5f);
    float* orow = out + (long)row*Cq;
#pragma unroll
    for (int j = 0; j < 6; j++){
        int c = lane + 64*j;
        orow[c] = (v[j] - mean) * rs * gw[c] + bw[c];
    }
}

// ---------------- generic fp32 GEMM: C = epi(A @ W^T) ----------------
// A: M x K row-major, W: N x K row-major, C: M x N.
// epi: 0 none, 1 +bias, 2 gelu(+bias), 3 C += (acc + bias)  (in-place residual)
// 64x64 tile, 4x4 register blocking with CONTIGUOUS fragments -> ds_read_b128.
__global__ void __launch_bounds__(256) gemm_f32(const float* __restrict__ A,
    const float* __restrict__ W, const float* __restrict__ bias,
    float* __restrict__ C, int M, int N, int K, int epi)
{
    __shared__ float As[16][HPAD];
    __shared__ float Ws[16][HPAD];
    int tid = threadIdx.x;
    int m0 = blockIdx.y*64, n0 = blockIdx.x*64;
    int tm = tid >> 4, tn = tid & 15;
    int lr = tid >> 2;           // 0..63
    int lc4 = (tid & 3) * 4;     // 0,4,8,12
    float acc[4][4] = {};
    for (int k0 = 0; k0 < K; k0 += 16){
        {
            int m = m0 + lr;
            float4 v = make_float4(0.f,0.f,0.f,0.f);
            if (m < M) v = *(const float4*)(A + (long)m*K + k0 + lc4);
            As[lc4+0][lr] = v.x; As[lc4+1][lr] = v.y; As[lc4+2][lr] = v.z; As[lc4+3][lr] = v.w;
            int n = n0 + lr;
            float4 wv = make_float4(0.f,0.f,0.f,0.f);
            if (n < N) wv = *(const float4*)(W + (long)n*K + k0 + lc4);
            Ws[lc4+0][lr] = wv.x; Ws[lc4+1][lr] = wv.y; Ws[lc4+2][lr] = wv.z; Ws[lc4+3][lr] = wv.w;
        }
        __syncthreads();
#pragma unroll
        for (int kk = 0; kk < 16; kk++){
            float4 a4 = *(const float4*)&As[kk][4*tm];
            float4 b4 = *(const float4*)&Ws[kk][4*tn];
            float a[4] = {a4.x, a4.y, a4.z, a4.w};
            float bb[4] = {b4.x, b4.y, b4.z, b4.w};
#pragma unroll
            for (int i = 0; i < 4; i++)
#pragma unroll
                for (int j = 0; j < 4; j++) acc[i][j] += a[i]*bb[j];
        }
        __syncthreads();
    }
#pragma unroll
    for (int i = 0; i < 4; i++){
        int m = m0 + 4*tm + i; if (m >= M) continue;
#pragma unroll
        for (int j = 0; j < 4; j++){
            int n = n0 + 4*tn + j; if (n >= N) continue;
            float v = acc[i][j];
            if (epi >= 1 && bias) v += bias[n];
            if (epi == 2) v = gelu_f(v);
            long off = (long)m*N + n;
            if (epi == 3) v += C[off];
            C[off] = v;
        }
    }
}

// ---------------- global attention: one wave per query row ----------------
// qkv: (B, NSEQ, 1152) with channel = comp*384 + h*64 + d. out: (B, NSEQ, 384).
__global__ void __launch_bounds__(256) attn_global(const float* __restrict__ qkv,
    const float* __restrict__ mask, float* __restrict__ out)
{
    __shared__ float qsh[4][64];
    __shared__ float sc[4][NSEQ];
    int blk = blockIdx.x;
    int qt = blk % 132; int bh = blk / 132;
    int h = bh % Hq;    int b = bh / Hq;
    int lane = threadIdx.x & 63, w = threadIdx.x >> 6;
    int qi = qt*4 + w;
    qsh[w][lane] = qkv[((long)(b*NSEQ + qi))*1152 + h*64 + lane];
    __syncthreads();
    const float* kbase = qkv + ((long)b*NSEQ)*1152 + 384 + h*64;
    const float* mrow  = mask + ((long)b*Gq + qi)*Gq;
    for (int j0 = 0; j0 < NSEQ; j0 += 64){
        int j = j0 + lane;
        if (j < NSEQ){
            const float4* kr4 = (const float4*)(kbase + (long)j*1152);
            float s = 0.f;
#pragma unroll
            for (int d4 = 0; d4 < 16; d4++){
                float4 kv = kr4[d4];
                s += qsh[w][4*d4+0]*kv.x + qsh[w][4*d4+1]*kv.y
                   + qsh[w][4*d4+2]*kv.z + qsh[w][4*d4+3]*kv.w;
            }
            s *= 0.125f;
            if (qi < Gq && j < Gq) s -= 100000.0f * mrow[j];
            sc[w][j] = s;
        }
    }
    float mx = -3e38f;
    for (int t = 0; t < 9; t++){ int j = lane + 64*t; if (j < NSEQ) mx = fmaxf(mx, sc[w][j]); }
#pragma unroll
    for (int m = 1; m < 64; m <<= 1) mx = fmaxf(mx, __shfl_xor(mx, m));
    float sm = 0.f;
    for (int t = 0; t < 9; t++){
        int j = lane + 64*t;
        if (j < NSEQ){ float e = expf(sc[w][j] - mx); sc[w][j] = e; sm += e; }
    }
#pragma unroll
    for (int m = 1; m < 64; m <<= 1) sm += __shfl_xor(sm, m);
    float inv = 1.0f / sm;
    const float* vbase = qkv + ((long)b*NSEQ)*1152 + 768 + h*64;
    float o = 0.f;
    for (int j = 0; j < NSEQ; j++) o += sc[w][j] * vbase[(long)j*1152 + lane];
    out[((long)(b*NSEQ + qi))*Cq + h*64 + lane] = o * inv;
}

// ---------------- adapter up-projection + combine ----------------
__global__ void __launch_bounds__(256) adapter_up(const float* __restrict__ hid,
    const float* __restrict__ uw, const float* __restrict__ ub,
    const float* __restrict__ src, const float* __restrict__ res,
    const float* __restrict__ gatep, float* __restrict__ out, long total)
{
    long gid = (long)blockIdx.x*256 + threadIdx.x;
    if (gid >= total) return;
    long m = gid / Cq; int c = (int)(gid % Cq);
    const float* hr = hid + m*16;
    const float* ur = uw + c*16;
    float acc = 0.f;
#pragma unroll
    for (int r = 0; r < 16; r++) acc += hr[r]*ur[r];
    float gate = gatep ? gatep[0] : 1.0f;
    float v = gate * (acc + ub[c] + src[gid]);
    if (res) v += res[gid];
    out[gid] = v;
}

// ---------------- fused local branch v2: gather precomputed QKV ----------------
// QKVl: (16896, 1152) = LN3(X) @ a1_qkv_w^T, channel = comp*384 + h*64 + d.
// Per group: gather q/k/v rows -> 32x32 attn -> proj + residual -> max+mean pool
// -> gelu(bn) + 0.4*center -> vis (B*S, 384)
__global__ void __launch_bounds__(512) local_attn(const float* __restrict__ Xf,
    const float* __restrict__ QKVl,
    const int* __restrict__ idx, const int* __restrict__ cidx,
    const float* __restrict__ pw, const float* __restrict__ pb,
    const float* __restrict__ bng, const float* __restrict__ bnb,
    float* __restrict__ vis)
{
    __shared__ float qh[32*HPAD];
    __shared__ float kh[32*HPAD];
    __shared__ float vh[32*HPAD];
    __shared__ float sc[32*33];
    __shared__ float aout[32*APAD];
    __shared__ float srow[32];
    __shared__ int   rows[32];
    int g = blockIdx.x;
    int tid = threadIdx.x;
    if (tid < 32) rows[tid] = idx[g*Kg + tid];
    __syncthreads();
    int tok = tid >> 4;            // 0..31
    int d4  = (tid & 15) * 4;      // 0,4,...,60
    int tx  = tid & 31, ty = tid >> 5;   // for scores / proj
    for (int h = 0; h < Hq; h++){
        // gather q,k,v for this head (float4 per comp per thread)
        {
            const float* base = QKVl + (long)rows[tok]*1152 + h*64 + d4;
            float4 qv = *(const float4*)(base);
            float4 kv = *(const float4*)(base + 384);
            float4 vv = *(const float4*)(base + 768);
            *(float4*)&qh[tok*HPAD + d4] = qv;
            *(float4*)&kh[tok*HPAD + d4] = kv;
            *(float4*)&vh[tok*HPAD + d4] = vv;
        }
        __syncthreads();
        // scores 32x32 (each thread: 2 rows)
#pragma unroll
        for (int ii = 0; ii < 2; ii++){
            int i = ty + 16*ii;
            const float* qp = qh + i*HPAD;
            const float* kp = kh + tx*HPAD;
            float s = 0.f;
#pragma unroll
            for (int d16 = 0; d16 < 16; d16++){
                float4 q4 = *(const float4*)(qp + 4*d16);
                float4 k4 = *(const float4*)(kp + 4*d16);
                s += q4.x*k4.x + q4.y*k4.y + q4.z*k4.z + q4.w*k4.w;
            }
            sc[i*33 + tx] = s * 0.125f;
        }
        __syncthreads();
        if (tid < 32){
            float mx = -3e38f;
            for (int j = 0; j < 32; j++) mx = fmaxf(mx, sc[tid*33 + j]);
            float sm = 0.f;
            for (int j = 0; j < 32; j++){
                float e = expf(sc[tid*33 + j] - mx); sc[tid*33 + j] = e; sm += e;
            }
            srow[tid] = 1.f/sm;
        }
        __syncthreads();
        // PV: each thread 4 (row, dim) outputs
        {
            int d = tid & 63; int i0 = tid >> 6;
#pragma unroll
            for (int ii = 0; ii < 4; ii++){
                int i = i0 + 8*ii;
                const float* pp = sc + i*33;
                float o = 0.f;
#pragma unroll
                for (int j = 0; j < 32; j++) o += pp[j]*vh[j*HPAD + d];
                aout[i*APAD + h*64 + d] = o * srow[i];
            }
        }
        __syncthreads();
    }
    // proj + bias + residual, then pool over tokens
    int crow = cidx[g];
    const float* ap = aout + tx*APAD;
#pragma unroll
    for (int r0 = 0; r0 < 24; r0 += 8){
        float po[8];
        const float* wpp[8];
#pragma unroll
        for (int r = 0; r < 8; r++){ po[r] = 0.f; wpp[r] = pw + (long)(ty + 16*(r0 + r))*Cq; }
        for (int k = 0; k < Cq; k += 4){
            float4 av = *(const float4*)(ap + k);
#pragma unroll
            for (int r = 0; r < 8; r++){
                float4 wv = *(const float4*)(wpp[r] + k);
                po[r] += av.x*wv.x + av.y*wv.y + av.z*wv.z + av.w*wv.w;
            }
        }
#pragma unroll
        for (int r = 0; r < 8; r++){
            int c = ty + 16*(r0 + r);
            float val = po[r] + pb[c] + Xf[(long)rows[tx]*Cq + c];
            float mx = val, sm = val;
#pragma unroll
            for (int m = 1; m < 32; m <<= 1){
                mx = fmaxf(mx, __shfl_xor(mx, m));
                sm += __shfl_xor(sm, m);
            }
            if ((tid & 31) == 0){
                float lc = mx + sm*(1.f/32.f);
                float u = lc * bng[c] * 0.9999950000374997f + bnb[c];  // rsqrt(1+1e-5)
                u = gelu_f(u);
                vis[(long)g*Cq + c] = u + 0.4f * Xf[(long)crow*Cq + c];
            }
        }
    }
}

// ---------------- inverse-distance interpolation + residual ----------------
__global__ void __launch_bounds__(128) interp_k(const float* __restrict__ Xf,
    const float* __restrict__ vis, const float* __restrict__ c1,
    const float* __restrict__ c2, float* __restrict__ newx)
{
    __shared__ float wsh[128];
    __shared__ float tot[2];
    int bn = blockIdx.x; int b = bn >> 9; int n = bn & 511;
    int tid = threadIdx.x;
    const float* p1 = c1 + (long)bn*3;
    float x1 = p1[0], y1 = p1[1], z1 = p1[2];
    const float* p2 = c2 + ((long)b*Sq + tid)*3;
    float x2 = p2[0], y2 = p2[1], z2 = p2[2];
    float d = (x1*x1 + y1*y1 + z1*z1) + (x2*x2 + y2*y2 + z2*z2)
            - 2.f*(x1*x2 + y1*y2 + z1*z2);
    float wv = 1.f/(d + 1e-8f);
    wsh[tid] = wv;
    float ss = wv;
#pragma unroll
    for (int m = 1; m < 64; m <<= 1) ss += __shfl_xor(ss, m);
    if ((tid & 63) == 0) tot[tid >> 6] = ss;
    __syncthreads();
    float inv = 1.f/(tot[0] + tot[1]);
    const float* vb = vis + (long)b*Sq*Cq;
    float a0 = 0.f, a1 = 0.f, a2 = 0.f;
    for (int s = 0; s < Sq; s++){
        float wq = wsh[s];
        const float* vr = vb + s*Cq + tid;
        a0 += wq*vr[0]; a1 += wq*vr[128]; a2 += wq*vr[256];
    }
    const float* xr = Xf + ((long)(b*NSEQ + Tq + n))*Cq;
    float* orow = newx + (long)bn*Cq;
    orow[tid]       = xr[tid]       + 0.4f*a0*inv;
    orow[tid + 128] = xr[tid + 128] + 0.4f*a1*inv;
    orow[tid + 256] = xr[tid + 256] + 0.4f*a2*inv;
}

// ---------------- launch ----------------
extern "C" void kernel_launch(void* const* d_in, const int* in_sizes, int n_in,
                              void* d_out, int out_size, void* d_ws, size_t ws_size,
                              hipStream_t stream)
{
    const float* x_in  = (const float*)d_in[0];
    const float* mask  = (const float*)d_in[1];
    const float* c1p   = (const float*)d_in[2];
    const float* c2p   = (const float*)d_in[3];
    const float* pe    = (const float*)d_in[5];
    const float* n1g   = (const float*)d_in[6];
    const float* n1b   = (const float*)d_in[7];
    const float* qkvw  = (const float*)d_in[8];
    const float* projw = (const float*)d_in[9];
    const float* projb = (const float*)d_in[10];
    const float* n2g   = (const float*)d_in[11];
    const float* n2b   = (const float*)d_in[12];
    const float* fc1w  = (const float*)d_in[13];
    const float* fc1b  = (const float*)d_in[14];
    const float* fc2w  = (const float*)d_in[15];
    const float* fc2b  = (const float*)d_in[16];
    const float* gate  = (const float*)d_in[17];
    const float* addw  = (const float*)d_in[18];
    const float* addb  = (const float*)d_in[19];
    const float* aduw  = (const float*)d_in[20];
    const float* adub  = (const float*)d_in[21];
    const float* ad1dw = (const float*)d_in[22];
    const float* ad1db = (const float*)d_in[23];
    const float* ad1uw = (const float*)d_in[24];
    const float* ad1ub = (const float*)d_in[25];
    const float* bng   = (const float*)d_in[26];
    const float* bnb   = (const float*)d_in[27];
    const float* a1qkvw= (const float*)d_in[28];
    const float* a1pw  = (const float*)d_in[29];
    const float* a1pb  = (const float*)d_in[30];
    const float* n3g   = (const float*)d_in[31];
    const float* n3b   = (const float*)d_in[32];
    const int*   idxp  = (const int*)d_in[33];
    const int*   cidxp = (const int*)d_in[34];

    float* ws = (float*)d_ws;
    float* X  = ws;                        // 16896 x 384
    float* Bb = X  + (long)ROWS*Cq;        // 16896 x 384 (ln_out / newx)
    float* Ab = Bb + (long)ROWS*Cq;        // 16896 x 1536 (qkv / mlp hidden / local qkv)
    float* C1 = Ab + (long)ROWS*1536;      // 16896 x 384 (attn_out / x_fn)
    float* D1 = C1 + (long)ROWS*Cq;        // 16896 x 16  (adapter hidden)
    float* V  = D1 + (long)ROWS*16;        // 4096 x 384  (vis_x)

    long totX = (long)ROWS*Cq;             // 6488064

    build_x<<<25344, 256, 0, stream>>>(x_in, pe, X, totX);
    ln_rows<<<4224, 256, 0, stream>>>(X, n1g, n1b, Bb, ROWS);
    gemm_f32<<<dim3(18, 264), 256, 0, stream>>>(Bb, qkvw, nullptr, Ab, ROWS, 1152, 384, 0);
    attn_global<<<25344, 256, 0, stream>>>(Ab, mask, C1);
    gemm_f32<<<dim3(6, 264), 256, 0, stream>>>(C1, projw, projb, X, ROWS, 384, 384, 3);
    ln_rows<<<4224, 256, 0, stream>>>(X, n2g, n2b, Bb, ROWS);
    gemm_f32<<<dim3(24, 264), 256, 0, stream>>>(Bb, fc1w, fc1b, Ab, ROWS, 1536, 384, 2);
    gemm_f32<<<dim3(6, 264), 256, 0, stream>>>(Ab, fc2w, fc2b, C1, ROWS, 384, 1536, 1);
    gemm_f32<<<dim3(1, 264), 256, 0, stream>>>(C1, addw, addb, D1, ROWS, 16, 384, 2);
    adapter_up<<<25344, 256, 0, stream>>>(D1, aduw, adub, C1, X, gate, X, totX);
    // local branch: hoisted LN3 + QKV on unique rows, then fused gather-attn
    ln_rows<<<4224, 256, 0, stream>>>(X, n3g, n3b, Bb, ROWS);
    gemm_f32<<<dim3(18, 264), 256, 0, stream>>>(Bb, a1qkvw, nullptr, Ab, ROWS, 1152, 384, 0);
    local_attn<<<4096, 512, 0, stream>>>(X, Ab, idxp, cidxp, a1pw, a1pb, bng, bnb, V);
    interp_k<<<16384, 128, 0, stream>>>(X, V, c1p, c2p, Bb);
    gemm_f32<<<dim3(1, 256), 256, 0, stream>>>(Bb, ad1dw, ad1db, D1, Bq*Gq, 16, 384, 2);
    adapter_up<<<24576, 256, 0, stream>>>(D1, ad1uw, ad1ub, Bb, nullptr, nullptr,
                                          (float*)d_out, (long)Bq*Gq*Cq);
}

// Round 3
// 3410.666 us; speedup vs baseline: 4.3720x; 1.8579x over previous
//
#include <hip/hip_runtime.h>
#include <hip/hip_bf16.h>

// ---------------- constants ----------------
#define Bq 32
#define Tq 16
#define Gq 512
#define NSEQ 528           // T + G
#define Cq 384
#define Hq 6
#define Sq 128
#define Kg 32              // GROUP_SIZE
#define ROWS (Bq*NSEQ)     // 16896
#define HPAD 68            // fp32 LDS row stride (16B-aligned rows)
#define LROWS (Bq*Sq*Kg)   // 131072 local tokens

typedef unsigned short u16;
typedef short bf16x8 __attribute__((ext_vector_type(8)));   // 8 bf16 in 4 VGPRs
typedef float f32x4  __attribute__((ext_vector_type(4)));

__device__ __forceinline__ float gelu_f(float x){
    return 0.5f * x * (1.0f + erff(x * 0.70710678118654752f));
}
__device__ __forceinline__ u16 f2b(float x){
    union { float f; unsigned u; } v; v.f = x;
    return (u16)((v.u + 0x7fffu + ((v.u >> 16) & 1u)) >> 16);
}
__device__ __forceinline__ float b2f(u16 h){
    union { float f; unsigned u; } v; v.u = ((unsigned)h) << 16; return v.f;
}

// ---------------- build X = concat(prompt, x) ----------------
__global__ void __launch_bounds__(256) build_x(const float* __restrict__ xin,
    const float* __restrict__ pe, float* __restrict__ X, long total)
{
    long gid = (long)blockIdx.x*256 + threadIdx.x;
    if (gid >= total) return;
    int  c   = (int)(gid % Cq);
    long row = gid / Cq;
    int  p   = (int)(row % NSEQ);
    long b   = row / NSEQ;
    float v = (p < Tq) ? pe[p*Cq + c] : xin[(b*Gq + (p - Tq))*Cq + c];
    X[gid] = v;
}

// ---------------- weight conversion fp32 -> bf16 (6 matrices) ----------------
__global__ void __launch_bounds__(256) conv6(const float* __restrict__ s0,
    const float* __restrict__ s1, const float* __restrict__ s2,
    const float* __restrict__ s3, const float* __restrict__ s4,
    const float* __restrict__ s5, u16* __restrict__ dst)
{
    long i = (long)blockIdx.x*256 + threadIdx.x;
    if (i >= 2359296) return;
    float v;
    if      (i <  442368) v = s0[i];
    else if (i <  589824) v = s1[i -  442368];
    else if (i < 1179648) v = s2[i -  589824];
    else if (i < 1769472) v = s3[i - 1179648];
    else if (i < 2211840) v = s4[i - 1769472];
    else                  v = s5[i - 2211840];
    dst[i] = f2b(v);
}

// ---------------- LayerNorm, one wave per row, bf16 out ----------------
__global__ void __launch_bounds__(256) ln_rows(const float* __restrict__ in,
    const float* __restrict__ gw, const float* __restrict__ bw,
    u16* __restrict__ out, int rows)
{
    int w = threadIdx.x >> 6, lane = threadIdx.x & 63;
    int row = blockIdx.x*4 + w;
    if (row >= rows) return;
    const float* xr = in + (long)row*Cq;
    float v[6]; float s = 0.f, s2 = 0.f;
#pragma unroll
    for (int j = 0; j < 6; j++){ float x = xr[lane + 64*j]; v[j] = x; s += x; s2 += x*x; }
#pragma unroll
    for (int m = 1; m < 64; m <<= 1){ s += __shfl_xor(s, m); s2 += __shfl_xor(s2, m); }
    float mean = s * (1.f/384.f);
    float var  = s2 * (1.f/384.f) - mean*mean;
    float rs   = rsqrtf(var + 1e-5f);
    u16* orow = out + (long)row*Cq;
#pragma unroll
    for (int j = 0; j < 6; j++){
        int c = lane + 64*j;
        orow[c] = f2b((v[j] - mean) * rs * gw[c] + bw[c]);
    }
}

// ---------------- bf16 MFMA GEMM: C = epi(A @ W^T) ----------------
// A: M x K bf16 row-major, W: N x K bf16 row-major. M%128==0, N%128==0, K%32==0.
// epi: 0 none->f32, 1 +bias->f32, 2 gelu(+bias)->bf16, 3 Cf += acc+bias (f32 RMW),
//      4 +bias->bf16
__global__ void __launch_bounds__(256) gemm_bf16(const u16* __restrict__ A,
    const u16* __restrict__ W, const float* __restrict__ bias,
    float* __restrict__ Cf, u16* __restrict__ Cb, int M, int N, int K, int epi)
{
    __shared__ u16 As[128*40];   // 32 data + 8 pad bf16 per row
    __shared__ u16 Ws[128*40];
    int t = threadIdx.x;
    int m0 = blockIdx.y*128, n0 = blockIdx.x*128;
    int wv = t >> 6, lane = t & 63;
    int wm = (wv >> 1)*64, wn = (wv & 1)*64;
    int fm = lane & 15;            // row-in-tile for both A and W frags
    int fk = (lane >> 4) * 8;      // k offset (8 bf16)
    int sr = t >> 2;               // staging row 0..63
    int sc8 = (t & 3) * 8;         // staging col (bf16)
    f32x4 acc[4][4];
#pragma unroll
    for (int i = 0; i < 4; i++)
#pragma unroll
        for (int j = 0; j < 4; j++) acc[i][j] = (f32x4){0.f,0.f,0.f,0.f};

    for (int k0 = 0; k0 < K; k0 += 32){
        *(uint4*)&As[sr*40 + sc8]      = *(const uint4*)(A + (long)(m0+sr)*K    + k0 + sc8);
        *(uint4*)&As[(sr+64)*40 + sc8] = *(const uint4*)(A + (long)(m0+sr+64)*K + k0 + sc8);
        *(uint4*)&Ws[sr*40 + sc8]      = *(const uint4*)(W + (long)(n0+sr)*K    + k0 + sc8);
        *(uint4*)&Ws[(sr+64)*40 + sc8] = *(const uint4*)(W + (long)(n0+sr+64)*K + k0 + sc8);
        __syncthreads();
        bf16x8 af[4], bf[4];
#pragma unroll
        for (int im = 0; im < 4; im++) af[im] = *(const bf16x8*)&As[(wm + im*16 + fm)*40 + fk];
#pragma unroll
        for (int in = 0; in < 4; in++) bf[in] = *(const bf16x8*)&Ws[(wn + in*16 + fm)*40 + fk];
#pragma unroll
        for (int im = 0; im < 4; im++)
#pragma unroll
            for (int in = 0; in < 4; in++)
                acc[im][in] = __builtin_amdgcn_mfma_f32_16x16x32_bf16(af[im], bf[in], acc[im][in], 0, 0, 0);
        __syncthreads();
    }
    int lr = lane >> 4, lc = lane & 15;
#pragma unroll
    for (int im = 0; im < 4; im++){
#pragma unroll
        for (int in = 0; in < 4; in++){
#pragma unroll
            for (int r = 0; r < 4; r++){
                int m = m0 + wm + im*16 + lr*4 + r;
                int n = n0 + wn + in*16 + lc;
                float v = acc[im][in][r];
                if (epi >= 1 && bias) v += bias[n];
                if (epi == 2) v = gelu_f(v);
                long off = (long)m*N + n;
                if (epi == 3) v += Cf[off];
                if (epi == 2 || epi == 4) Cb[off] = f2b(v);
                else                      Cf[off] = v;
            }
        }
    }
}

// ---------------- generic fp32 GEMM (small adapters only) ----------------
__global__ void __launch_bounds__(256) gemm_f32(const float* __restrict__ A,
    const float* __restrict__ W, const float* __restrict__ bias,
    float* __restrict__ C, int M, int N, int K, int epi)
{
    __shared__ float As[16][HPAD];
    __shared__ float Ws[16][HPAD];
    int tid = threadIdx.x;
    int m0 = blockIdx.y*64, n0 = blockIdx.x*64;
    int tm = tid >> 4, tn = tid & 15;
    int lr = tid >> 2;
    int lc4 = (tid & 3) * 4;
    float acc[4][4] = {};
    for (int k0 = 0; k0 < K; k0 += 16){
        {
            int m = m0 + lr;
            float4 v = make_float4(0.f,0.f,0.f,0.f);
            if (m < M) v = *(const float4*)(A + (long)m*K + k0 + lc4);
            As[lc4+0][lr] = v.x; As[lc4+1][lr] = v.y; As[lc4+2][lr] = v.z; As[lc4+3][lr] = v.w;
            int n = n0 + lr;
            float4 wv = make_float4(0.f,0.f,0.f,0.f);
            if (n < N) wv = *(const float4*)(W + (long)n*K + k0 + lc4);
            Ws[lc4+0][lr] = wv.x; Ws[lc4+1][lr] = wv.y; Ws[lc4+2][lr] = wv.z; Ws[lc4+3][lr] = wv.w;
        }
        __syncthreads();
#pragma unroll
        for (int kk = 0; kk < 16; kk++){
            float4 a4 = *(const float4*)&As[kk][4*tm];
            float4 b4 = *(const float4*)&Ws[kk][4*tn];
            float a[4] = {a4.x, a4.y, a4.z, a4.w};
            float bb[4] = {b4.x, b4.y, b4.z, b4.w};
#pragma unroll
            for (int i = 0; i < 4; i++)
#pragma unroll
                for (int j = 0; j < 4; j++) acc[i][j] += a[i]*bb[j];
        }
        __syncthreads();
    }
#pragma unroll
    for (int i = 0; i < 4; i++){
        int m = m0 + 4*tm + i; if (m >= M) continue;
#pragma unroll
        for (int j = 0; j < 4; j++){
            int n = n0 + 4*tn + j; if (n >= N) continue;
            float v = acc[i][j];
            if (epi >= 1 && bias) v += bias[n];
            if (epi == 2) v = gelu_f(v);
            long off = (long)m*N + n;
            if (epi == 3) v += C[off];
            C[off] = v;
        }
    }
}

// ---------------- global attention: one wave per query row, bf16 out ----------
__global__ void __launch_bounds__(256) attn_global(const float* __restrict__ qkv,
    const float* __restrict__ mask, u16* __restrict__ out)
{
    __shared__ float qsh[4][64];
    __shared__ float sc[4][NSEQ];
    int blk = blockIdx.x;
    int qt = blk % 132; int bh = blk / 132;
    int h = bh % Hq;    int b = bh / Hq;
    int lane = threadIdx.x & 63, w = threadIdx.x >> 6;
    int qi = qt*4 + w;
    qsh[w][lane] = qkv[((long)(b*NSEQ + qi))*1152 + h*64 + lane];
    __syncthreads();
    const float* kbase = qkv + ((long)b*NSEQ)*1152 + 384 + h*64;
    const float* mrow  = mask + ((long)b*Gq + qi)*Gq;
    for (int j0 = 0; j0 < NSEQ; j0 += 64){
        int j = j0 + lane;
        if (j < NSEQ){
            const float4* kr4 = (const float4*)(kbase + (long)j*1152);
            float s = 0.f;
#pragma unroll
            for (int d4 = 0; d4 < 16; d4++){
                float4 kv = kr4[d4];
                s += qsh[w][4*d4+0]*kv.x + qsh[w][4*d4+1]*kv.y
                   + qsh[w][4*d4+2]*kv.z + qsh[w][4*d4+3]*kv.w;
            }
            s *= 0.125f;
            if (qi < Gq && j < Gq) s -= 100000.0f * mrow[j];
            sc[w][j] = s;
        }
    }
    float mx = -3e38f;
    for (int t = 0; t < 9; t++){ int j = lane + 64*t; if (j < NSEQ) mx = fmaxf(mx, sc[w][j]); }
#pragma unroll
    for (int m = 1; m < 64; m <<= 1) mx = fmaxf(mx, __shfl_xor(mx, m));
    float sm = 0.f;
    for (int t = 0; t < 9; t++){
        int j = lane + 64*t;
        if (j < NSEQ){ float e = expf(sc[w][j] - mx); sc[w][j] = e; sm += e; }
    }
#pragma unroll
    for (int m = 1; m < 64; m <<= 1) sm += __shfl_xor(sm, m);
    float inv = 1.0f / sm;
    const float* vbase = qkv + ((long)b*NSEQ)*1152 + 768 + h*64;
    float o = 0.f;
    for (int j = 0; j < NSEQ; j++) o += sc[w][j] * vbase[(long)j*1152 + lane];
    out[((long)(b*NSEQ + qi))*Cq + h*64 + lane] = f2b(o * inv);
}

// ---------------- adapter up-projection + combine ----------------
__global__ void __launch_bounds__(256) adapter_up(const float* __restrict__ hid,
    const float* __restrict__ uw, const float* __restrict__ ub,
    const float* __restrict__ src, const float* __restrict__ res,
    const float* __restrict__ gatep, float* __restrict__ out, long total)
{
    long gid = (long)blockIdx.x*256 + threadIdx.x;
    if (gid >= total) return;
    long m = gid / Cq; int c = (int)(gid % Cq);
    const float* hr = hid + m*16;
    const float* ur = uw + c*16;
    float acc = 0.f;
#pragma unroll
    for (int r = 0; r < 16; r++) acc += hr[r]*ur[r];
    float gate = gatep ? gatep[0] : 1.0f;
    float v = gate * (acc + ub[c] + src[gid]);
    if (res) v += res[gid];
    out[gid] = v;
}

// ---------------- local branch v3: attention only, bf16 aout ----------------
// QKVl: (16896, 1152) fp32. aout16: (131072, 384) bf16 attention output.
__global__ void __launch_bounds__(512) local_attn(const float* __restrict__ QKVl,
    const int* __restrict__ idx, u16* __restrict__ aout16)
{
    __shared__ float qh[32*HPAD];
    __shared__ float kh[32*HPAD];
    __shared__ float vh[32*HPAD];
    __shared__ float sc[32*33];
    __shared__ float srow[32];
    __shared__ int   rows[32];
    int g = blockIdx.x;
    int tid = threadIdx.x;
    if (tid < 32) rows[tid] = idx[g*Kg + tid];
    __syncthreads();
    int tok = tid >> 4;
    int d4  = (tid & 15) * 4;
    int tx  = tid & 31, ty = tid >> 5;
    for (int h = 0; h < Hq; h++){
        {
            const float* base = QKVl + (long)rows[tok]*1152 + h*64 + d4;
            float4 qv = *(const float4*)(base);
            float4 kv = *(const float4*)(base + 384);
            float4 vv = *(const float4*)(base + 768);
            *(float4*)&qh[tok*HPAD + d4] = qv;
            *(float4*)&kh[tok*HPAD + d4] = kv;
            *(float4*)&vh[tok*HPAD + d4] = vv;
        }
        __syncthreads();
#pragma unroll
        for (int ii = 0; ii < 2; ii++){
            int i = ty + 16*ii;
            const float* qp = qh + i*HPAD;
            const float* kp = kh + tx*HPAD;
            float s = 0.f;
#pragma unroll
            for (int d16 = 0; d16 < 16; d16++){
                float4 q4 = *(const float4*)(qp + 4*d16);
                float4 k4 = *(const float4*)(kp + 4*d16);
                s += q4.x*k4.x + q4.y*k4.y + q4.z*k4.z + q4.w*k4.w;
            }
            sc[i*33 + tx] = s * 0.125f;
        }
        __syncthreads();
        if (tid < 32){
            float mx = -3e38f;
            for (int j = 0; j < 32; j++) mx = fmaxf(mx, sc[tid*33 + j]);
            float sm = 0.f;
            for (int j = 0; j < 32; j++){
                float e = expf(sc[tid*33 + j] - mx); sc[tid*33 + j] = e; sm += e;
            }
            srow[tid] = 1.f/sm;
        }
        __syncthreads();
        {
            int d = tid & 63; int i0 = tid >> 6;
#pragma unroll
            for (int ii = 0; ii < 4; ii++){
                int i = i0 + 8*ii;
                const float* pp = sc + i*33;
                float o = 0.f;
#pragma unroll
                for (int j = 0; j < 32; j++) o += pp[j]*vh[j*HPAD + d];
                aout16[((long)(g*32 + i))*Cq + h*64 + d] = f2b(o * srow[i]);
            }
        }
        __syncthreads();
    }
}

// ---------------- pool: residual + max/mean + BN-gelu + center ----------------
__global__ void __launch_bounds__(128) pool_k(const u16* __restrict__ proj16,
    const float* __restrict__ Xf, const int* __restrict__ idx,
    const int* __restrict__ cidx, const float* __restrict__ bng,
    const float* __restrict__ bnb, float* __restrict__ vis)
{
    __shared__ int rows[32];
    int g = blockIdx.x;
    int tid = threadIdx.x;
    if (tid < 32) rows[tid] = idx[g*Kg + tid];
    __syncthreads();
    int crow = cidx[g];
    for (int c = tid; c < Cq; c += 128){
        float mx = -3e38f, sm = 0.f;
        for (int t = 0; t < 32; t++){
            float p = b2f(proj16[((long)(g*32 + t))*Cq + c]);
            float val = p + Xf[(long)rows[t]*Cq + c];
            mx = fmaxf(mx, val); sm += val;
        }
        float lc = mx + sm*(1.f/32.f);
        float u = gelu_f(lc * bng[c] * 0.9999950000374997f + bnb[c]);
        vis[(long)g*Cq + c] = u + 0.4f * Xf[(long)crow*Cq + c];
    }
}

// ---------------- inverse-distance interpolation + residual ----------------
__global__ void __launch_bounds__(128) interp_k(const float* __restrict__ Xf,
    const float* __restrict__ vis, const float* __restrict__ c1,
    const float* __restrict__ c2, float* __restrict__ newx)
{
    __shared__ float wsh[128];
    __shared__ float tot[2];
    int bn = blockIdx.x; int b = bn >> 9; int n = bn & 511;
    int tid = threadIdx.x;
    const float* p1 = c1 + (long)bn*3;
    float x1 = p1[0], y1 = p1[1], z1 = p1[2];
    const float* p2 = c2 + ((long)b*Sq + tid)*3;
    float x2 = p2[0], y2 = p2[1], z2 = p2[2];
    float d = (x1*x1 + y1*y1 + z1*z1) + (x2*x2 + y2*y2 + z2*z2)
            - 2.f*(x1*x2 + y1*y2 + z1*z2);
    float wv = 1.f/(d + 1e-8f);
    wsh[tid] = wv;
    float ss = wv;
#pragma unroll
    for (int m = 1; m < 64; m <<= 1) ss += __shfl_xor(ss, m);
    if ((tid & 63) == 0) tot[tid >> 6] = ss;
    __syncthreads();
    float inv = 1.f/(tot[0] + tot[1]);
    const float* vb = vis + (long)b*Sq*Cq;
    float a0 = 0.f, a1 = 0.f, a2 = 0.f;
    for (int s = 0; s < Sq; s++){
        float wq = wsh[s];
        const float* vr = vb + s*Cq + tid;
        a0 += wq*vr[0]; a1 += wq*vr[128]; a2 += wq*vr[256];
    }
    const float* xr = Xf + ((long)(b*NSEQ + Tq + n))*Cq;
    float* orow = newx + (long)bn*Cq;
    orow[tid]       = xr[tid]       + 0.4f*a0*inv;
    orow[tid + 128] = xr[tid + 128] + 0.4f*a1*inv;
    orow[tid + 256] = xr[tid + 256] + 0.4f*a2*inv;
}

// ---------------- launch ----------------
extern "C" void kernel_launch(void* const* d_in, const int* in_sizes, int n_in,
                              void* d_out, int out_size, void* d_ws, size_t ws_size,
                              hipStream_t stream)
{
    const float* x_in  = (const float*)d_in[0];
    const float* mask  = (const float*)d_in[1];
    const float* c1p   = (const float*)d_in[2];
    const float* c2p   = (const float*)d_in[3];
    const float* pe    = (const float*)d_in[5];
    const float* n1g   = (const float*)d_in[6];
    const float* n1b   = (const float*)d_in[7];
    const float* qkvw  = (const float*)d_in[8];
    const float* projw = (const float*)d_in[9];
    const float* projb = (const float*)d_in[10];
    const float* n2g   = (const float*)d_in[11];
    const float* n2b   = (const float*)d_in[12];
    const float* fc1w  = (const float*)d_in[13];
    const float* fc1b  = (const float*)d_in[14];
    const float* fc2w  = (const float*)d_in[15];
    const float* fc2b  = (const float*)d_in[16];
    const float* gate  = (const float*)d_in[17];
    const float* addw  = (const float*)d_in[18];
    const float* addb  = (const float*)d_in[19];
    const float* aduw  = (const float*)d_in[20];
    const float* adub  = (const float*)d_in[21];
    const float* ad1dw = (const float*)d_in[22];
    const float* ad1db = (const float*)d_in[23];
    const float* ad1uw = (const float*)d_in[24];
    const float* ad1ub = (const float*)d_in[25];
    const float* bng   = (const float*)d_in[26];
    const float* bnb   = (const float*)d_in[27];
    const float* a1qkvw= (const float*)d_in[28];
    const float* a1pw  = (const float*)d_in[29];
    const float* a1pb  = (const float*)d_in[30];
    const float* n3g   = (const float*)d_in[31];
    const float* n3b   = (const float*)d_in[32];
    const int*   idxp  = (const int*)d_in[33];
    const int*   cidxp = (const int*)d_in[34];

    // ---- workspace layout (bytes) ----
    char* w = (char*)d_ws;
    float* X    = (float*)w;                       // 16896x384 f32 = 25952256 B
    u16*   WB   = (u16*)(w + 25952256);            // 2359296 bf16  =  4718592 B
    u16*   Bb16 = (u16*)(w + 30670848);            // 16896x384 bf16 = 12976128 B
    char*  BIG1 = w + 43646976;                    // 100663296 B
    char*  BIG2 = BIG1 + 100663296;                // 100663296 B
    float* D1   = (float*)(BIG2 + 100663296);      // 16896x16 f32 = 1081344 B
    float* V    = D1 + ROWS*16;                    // 4096x384 f32 = 6291456 B

    u16* qkvw16  = WB;
    u16* projw16 = WB +  442368;
    u16* fc1w16  = WB +  589824;
    u16* fc2w16  = WB + 1179648;
    u16* a1qkv16 = WB + 1769472;
    u16* a1pw16  = WB + 2211840;

    float* QKV    = (float*)BIG1;   // 16896x1152 f32 (77.9 MB)
    float* C1     = (float*)BIG1;   // 16896x384 f32 x_fn (after attn done)
    u16*   proj16 = (u16*)BIG1;     // 131072x384 bf16 (100.7 MB)
    u16*   hid16  = (u16*)BIG2;     // 16896x1536 bf16 (51.9 MB)
    u16*   aout16 = (u16*)BIG2;     // 131072x384 bf16 (100.7 MB)
    float* newx   = (float*)BIG2;   // 16384x384 f32 (25.2 MB)

    long totX = (long)ROWS*Cq;

    conv6<<<9216, 256, 0, stream>>>(qkvw, projw, fc1w, fc2w, a1qkvw, a1pw, WB);
    build_x<<<25344, 256, 0, stream>>>(x_in, pe, X, totX);
    ln_rows<<<4224, 256, 0, stream>>>(X, n1g, n1b, Bb16, ROWS);
    gemm_bf16<<<dim3(9, 132), 256, 0, stream>>>(Bb16, qkvw16, nullptr, QKV, nullptr,
                                                ROWS, 1152, Cq, 0);
    attn_global<<<25344, 256, 0, stream>>>(QKV, mask, Bb16);
    gemm_bf16<<<dim3(3, 132), 256, 0, stream>>>(Bb16, projw16, projb, X, nullptr,
                                                ROWS, Cq, Cq, 3);
    ln_rows<<<4224, 256, 0, stream>>>(X, n2g, n2b, Bb16, ROWS);
    gemm_bf16<<<dim3(12, 132), 256, 0, stream>>>(Bb16, fc1w16, fc1b, nullptr, hid16,
                                                 ROWS, 1536, Cq, 2);
    gemm_bf16<<<dim3(3, 132), 256, 0, stream>>>(hid16, fc2w16, fc2b, C1, nullptr,
                                                ROWS, Cq, 1536, 1);
    gemm_f32<<<dim3(1, 264), 256, 0, stream>>>(C1, addw, addb, D1, ROWS, 16, Cq, 2);
    adapter_up<<<25344, 256, 0, stream>>>(D1, aduw, adub, C1, X, gate, X, totX);
    // local branch
    ln_rows<<<4224, 256, 0, stream>>>(X, n3g, n3b, Bb16, ROWS);
    gemm_bf16<<<dim3(9, 132), 256, 0, stream>>>(Bb16, a1qkv16, nullptr, QKV, nullptr,
                                                ROWS, 1152, Cq, 0);
    local_attn<<<4096, 512, 0, stream>>>(QKV, idxp, aout16);
    gemm_bf16<<<dim3(3, 1024), 256, 0, stream>>>(aout16, a1pw16, a1pb, nullptr, proj16,
                                                 LROWS, Cq, Cq, 4);
    pool_k<<<4096, 128, 0, stream>>>(proj16, X, idxp, cidxp, bng, bnb, V);
    interp_k<<<16384, 128, 0, stream>>>(X, V, c1p, c2p, newx);
    gemm_f32<<<dim3(1, 256), 256, 0, stream>>>(newx, ad1dw, ad1db, D1, Bq*Gq, 16, Cq, 2);
    adapter_up<<<24576, 256, 0, stream>>>(D1, ad1uw, ad1ub, newx, nullptr, nullptr,
                                          (float*)d_out, (long)Bq*Gq*Cq);
}

// Round 4
// 1560.715 us; speedup vs baseline: 9.5542x; 2.1853x over previous
//
#include <hip/hip_runtime.h>
#include <hip/hip_bf16.h>

// ---------------- constants ----------------
#define Bq 32
#define Tq 16
#define Gq 512
#define NSEQ 528           // T + G
#define Cq 384
#define Hq 6
#define Sq 128
#define Kg 32              // GROUP_SIZE
#define ROWS (Bq*NSEQ)     // 16896
#define HPAD 68            // fp32 LDS row stride (16B-aligned rows)
#define LROWS (Bq*Sq*Kg)   // 131072 local tokens

typedef unsigned short u16;
typedef short bf16x8 __attribute__((ext_vector_type(8)));   // 8 bf16 in 4 VGPRs
typedef float f32x4  __attribute__((ext_vector_type(4)));

__device__ __forceinline__ float gelu_f(float x){
    return 0.5f * x * (1.0f + erff(x * 0.70710678118654752f));
}
__device__ __forceinline__ u16 f2b(float x){
    union { float f; unsigned u; } v; v.f = x;
    return (u16)((v.u + 0x7fffu + ((v.u >> 16) & 1u)) >> 16);
}
__device__ __forceinline__ float b2f(u16 h){
    union { float f; unsigned u; } v; v.u = ((unsigned)h) << 16; return v.f;
}

// ---------------- build X = concat(prompt, x) ----------------
__global__ void __launch_bounds__(256) build_x(const float* __restrict__ xin,
    const float* __restrict__ pe, float* __restrict__ X, long total)
{
    long gid = (long)blockIdx.x*256 + threadIdx.x;
    if (gid >= total) return;
    int  c   = (int)(gid % Cq);
    long row = gid / Cq;
    int  p   = (int)(row % NSEQ);
    long b   = row / NSEQ;
    float v = (p < Tq) ? pe[p*Cq + c] : xin[(b*Gq + (p - Tq))*Cq + c];
    X[gid] = v;
}

// ---------------- weight conversion fp32 -> bf16 (6 matrices) ----------------
__global__ void __launch_bounds__(256) conv6(const float* __restrict__ s0,
    const float* __restrict__ s1, const float* __restrict__ s2,
    const float* __restrict__ s3, const float* __restrict__ s4,
    const float* __restrict__ s5, u16* __restrict__ dst)
{
    long i = (long)blockIdx.x*256 + threadIdx.x;
    if (i >= 2359296) return;
    float v;
    if      (i <  442368) v = s0[i];
    else if (i <  589824) v = s1[i -  442368];
    else if (i < 1179648) v = s2[i -  589824];
    else if (i < 1769472) v = s3[i - 1179648];
    else if (i < 2211840) v = s4[i - 1769472];
    else                  v = s5[i - 2211840];
    dst[i] = f2b(v);
}

// ---------------- LayerNorm, one wave per row, bf16 out ----------------
__global__ void __launch_bounds__(256) ln_rows(const float* __restrict__ in,
    const float* __restrict__ gw, const float* __restrict__ bw,
    u16* __restrict__ out, int rows)
{
    int w = threadIdx.x >> 6, lane = threadIdx.x & 63;
    int row = blockIdx.x*4 + w;
    if (row >= rows) return;
    const float* xr = in + (long)row*Cq;
    float v[6]; float s = 0.f, s2 = 0.f;
#pragma unroll
    for (int j = 0; j < 6; j++){ float x = xr[lane + 64*j]; v[j] = x; s += x; s2 += x*x; }
#pragma unroll
    for (int m = 1; m < 64; m <<= 1){ s += __shfl_xor(s, m); s2 += __shfl_xor(s2, m); }
    float mean = s * (1.f/384.f);
    float var  = s2 * (1.f/384.f) - mean*mean;
    float rs   = rsqrtf(var + 1e-5f);
    u16* orow = out + (long)row*Cq;
#pragma unroll
    for (int j = 0; j < 6; j++){
        int c = lane + 64*j;
        orow[c] = f2b((v[j] - mean) * rs * gw[c] + bw[c]);
    }
}

// ---------------- bf16 MFMA GEMM: C = epi(A @ W^T) ----------------
// A: M x K bf16 row-major, W: N x K bf16 row-major. M%128==0, N%128==0, K%32==0.
// epi: 0 none->f32, 1 +bias->f32, 2 gelu(+bias)->bf16, 3 Cf += acc+bias (f32 RMW),
//      4 (+bias if given)->bf16
__global__ void __launch_bounds__(256) gemm_bf16(const u16* __restrict__ A,
    const u16* __restrict__ W, const float* __restrict__ bias,
    float* __restrict__ Cf, u16* __restrict__ Cb, int M, int N, int K, int epi)
{
    __shared__ u16 As[128*40];   // 32 data + 8 pad bf16 per row
    __shared__ u16 Ws[128*40];
    int t = threadIdx.x;
    int m0 = blockIdx.y*128, n0 = blockIdx.x*128;
    int wv = t >> 6, lane = t & 63;
    int wm = (wv >> 1)*64, wn = (wv & 1)*64;
    int fm = lane & 15;            // row-in-tile for both A and W frags
    int fk = (lane >> 4) * 8;      // k offset (8 bf16)
    int sr = t >> 2;               // staging row 0..63
    int sc8 = (t & 3) * 8;         // staging col (bf16)
    f32x4 acc[4][4];
#pragma unroll
    for (int i = 0; i < 4; i++)
#pragma unroll
        for (int j = 0; j < 4; j++) acc[i][j] = (f32x4){0.f,0.f,0.f,0.f};

    for (int k0 = 0; k0 < K; k0 += 32){
        *(uint4*)&As[sr*40 + sc8]      = *(const uint4*)(A + (long)(m0+sr)*K    + k0 + sc8);
        *(uint4*)&As[(sr+64)*40 + sc8] = *(const uint4*)(A + (long)(m0+sr+64)*K + k0 + sc8);
        *(uint4*)&Ws[sr*40 + sc8]      = *(const uint4*)(W + (long)(n0+sr)*K    + k0 + sc8);
        *(uint4*)&Ws[(sr+64)*40 + sc8] = *(const uint4*)(W + (long)(n0+sr+64)*K + k0 + sc8);
        __syncthreads();
        bf16x8 af[4], bf[4];
#pragma unroll
        for (int im = 0; im < 4; im++) af[im] = *(const bf16x8*)&As[(wm + im*16 + fm)*40 + fk];
#pragma unroll
        for (int in = 0; in < 4; in++) bf[in] = *(const bf16x8*)&Ws[(wn + in*16 + fm)*40 + fk];
#pragma unroll
        for (int im = 0; im < 4; im++)
#pragma unroll
            for (int in = 0; in < 4; in++)
                acc[im][in] = __builtin_amdgcn_mfma_f32_16x16x32_bf16(af[im], bf[in], acc[im][in], 0, 0, 0);
        __syncthreads();
    }
    int lr = lane >> 4, lc = lane & 15;
#pragma unroll
    for (int im = 0; im < 4; im++){
#pragma unroll
        for (int in = 0; in < 4; in++){
#pragma unroll
            for (int r = 0; r < 4; r++){
                int m = m0 + wm + im*16 + lr*4 + r;
                int n = n0 + wn + in*16 + lc;
                float v = acc[im][in][r];
                if (epi >= 1 && bias) v += bias[n];
                if (epi == 2) v = gelu_f(v);
                long off = (long)m*N + n;
                if (epi == 3) v += Cf[off];
                if (epi == 2 || epi == 4) Cb[off] = f2b(v);
                else                      Cf[off] = v;
            }
        }
    }
}

// ---------------- generic fp32 GEMM (small adapters only) ----------------
__global__ void __launch_bounds__(256) gemm_f32(const float* __restrict__ A,
    const float* __restrict__ W, const float* __restrict__ bias,
    float* __restrict__ C, int M, int N, int K, int epi)
{
    __shared__ float As[16][HPAD];
    __shared__ float Ws[16][HPAD];
    int tid = threadIdx.x;
    int m0 = blockIdx.y*64, n0 = blockIdx.x*64;
    int tm = tid >> 4, tn = tid & 15;
    int lr = tid >> 2;
    int lc4 = (tid & 3) * 4;
    float acc[4][4] = {};
    for (int k0 = 0; k0 < K; k0 += 16){
        {
            int m = m0 + lr;
            float4 v = make_float4(0.f,0.f,0.f,0.f);
            if (m < M) v = *(const float4*)(A + (long)m*K + k0 + lc4);
            As[lc4+0][lr] = v.x; As[lc4+1][lr] = v.y; As[lc4+2][lr] = v.z; As[lc4+3][lr] = v.w;
            int n = n0 + lr;
            float4 wv = make_float4(0.f,0.f,0.f,0.f);
            if (n < N) wv = *(const float4*)(W + (long)n*K + k0 + lc4);
            Ws[lc4+0][lr] = wv.x; Ws[lc4+1][lr] = wv.y; Ws[lc4+2][lr] = wv.z; Ws[lc4+3][lr] = wv.w;
        }
        __syncthreads();
#pragma unroll
        for (int kk = 0; kk < 16; kk++){
            float4 a4 = *(const float4*)&As[kk][4*tm];
            float4 b4 = *(const float4*)&Ws[kk][4*tn];
            float a[4] = {a4.x, a4.y, a4.z, a4.w};
            float bb[4] = {b4.x, b4.y, b4.z, b4.w};
#pragma unroll
            for (int i = 0; i < 4; i++)
#pragma unroll
                for (int j = 0; j < 4; j++) acc[i][j] += a[i]*bb[j];
        }
        __syncthreads();
    }
#pragma unroll
    for (int i = 0; i < 4; i++){
        int m = m0 + 4*tm + i; if (m >= M) continue;
#pragma unroll
        for (int j = 0; j < 4; j++){
            int n = n0 + 4*tn + j; if (n >= N) continue;
            float v = acc[i][j];
            if (epi >= 1 && bias) v += bias[n];
            if (epi == 2) v = gelu_f(v);
            long off = (long)m*N + n;
            if (epi == 3) v += C[off];
            C[off] = v;
        }
    }
}

// ---------------- flash-style MFMA global attention ----------------
// QKVg: (16896, 1152) bf16, channel = comp*384 + h*64 + d.
// Block: (b, h, qt) — 4 waves x 16 queries = 64-query tile; loop 32-key chunks.
// out: (16896, 384) bf16.
__global__ void __launch_bounds__(256) attn_mfma(const u16* __restrict__ QKVg,
    const float* __restrict__ mask, u16* __restrict__ out)
{
    __shared__ u16 Ks[32*72];       // 32 keys x 64 d (+8 pad)
    __shared__ u16 Vt[64*40];       // 64 d x 32 keys (+8 pad), transposed
    __shared__ u16 Pb[4][16*40];    // per-wave P tile 16 q x 32 keys (+8 pad)
    int blk = blockIdx.x;
    int qt = blk % 9; int bh = blk / 9;
    int h = bh % Hq;  int b = bh / Hq;
    int t = threadIdx.x; int w = t >> 6; int lane = t & 63;
    int q0 = qt*64 + w*16;
    int fr  = lane & 15;          // fragment row (query for A, key/d-col for B)
    int fko = (lane >> 4) * 8;    // fragment k offset
    int colj = lane & 15;         // C-layout col
    int rgrp = (lane >> 4) * 4;   // C-layout row base

    // Q fragments straight from global (row-major bf16), clamp OOB rows
    int qrow = q0 + fr; int qrc = qrow < NSEQ ? qrow : NSEQ-1;
    const u16* qbase = QKVg + (long)(b*NSEQ + qrc)*1152 + h*64;
    bf16x8 aq0 = *(const bf16x8*)(qbase + fko);
    bf16x8 aq1 = *(const bf16x8*)(qbase + 32 + fko);

    f32x4 oacc[4];
#pragma unroll
    for (int d = 0; d < 4; d++) oacc[d] = (f32x4){0.f,0.f,0.f,0.f};
    float mrun[4], lrun[4];
#pragma unroll
    for (int r = 0; r < 4; r++){ mrun[r] = -1e30f; lrun[r] = 0.f; }

    int skey = t >> 3;            // staging: key 0..31
    int sd8  = (t & 7) * 8;       // staging: d offset

    for (int kc = 0; kc < 17; kc++){
        __syncthreads();
        {
            int j = kc*32 + skey;
            bf16x8 kv = {0,0,0,0,0,0,0,0};
            bf16x8 vv = {0,0,0,0,0,0,0,0};
            if (j < NSEQ){
                const u16* kb = QKVg + (long)(b*NSEQ + j)*1152 + 384 + h*64 + sd8;
                kv = *(const bf16x8*)kb;
                vv = *(const bf16x8*)(kb + 384);
            }
            *(bf16x8*)&Ks[skey*72 + sd8] = kv;
#pragma unroll
            for (int e = 0; e < 8; e++) Vt[(sd8+e)*40 + skey] = (u16)vv[e];
        }
        __syncthreads();
        // scores: 2 key-subtiles x (2 MFMAs over d)
        f32x4 s[2];
#pragma unroll
        for (int sub = 0; sub < 2; sub++){
            bf16x8 bk0 = *(const bf16x8*)&Ks[(sub*16 + fr)*72 + fko];
            bf16x8 bk1 = *(const bf16x8*)&Ks[(sub*16 + fr)*72 + 32 + fko];
            f32x4 z = (f32x4){0.f,0.f,0.f,0.f};
            z = __builtin_amdgcn_mfma_f32_16x16x32_bf16(aq0, bk0, z, 0, 0, 0);
            z = __builtin_amdgcn_mfma_f32_16x16x32_bf16(aq1, bk1, z, 0, 0, 0);
            s[sub] = z;
        }
        // scale + mask + key-padding
#pragma unroll
        for (int sub = 0; sub < 2; sub++){
#pragma unroll
            for (int r = 0; r < 4; r++){
                int qi = q0 + rgrp + r;
                int jj = kc*32 + sub*16 + colj;
                float sv = s[sub][r] * 0.125f;
                if (jj < Gq && qi < Gq) sv -= 100000.0f * mask[((long)b*Gq + qi)*Gq + jj];
                if (jj >= NSEQ) sv = -1e30f;
                s[sub][r] = sv;
            }
        }
        // online softmax (16-lane row groups)
        float alpha[4];
#pragma unroll
        for (int r = 0; r < 4; r++){
            float mx = fmaxf(s[0][r], s[1][r]);
#pragma unroll
            for (int mm = 1; mm < 16; mm <<= 1) mx = fmaxf(mx, __shfl_xor(mx, mm));
            float mnew = fmaxf(mrun[r], mx);
            alpha[r] = __expf(mrun[r] - mnew);
            mrun[r] = mnew;
            float p0 = __expf(s[0][r] - mnew);
            float p1 = __expf(s[1][r] - mnew);
            s[0][r] = p0; s[1][r] = p1;
            float ps = p0 + p1;
#pragma unroll
            for (int mm = 1; mm < 16; mm <<= 1) ps += __shfl_xor(ps, mm);
            lrun[r] = lrun[r]*alpha[r] + ps;
        }
        // P -> LDS (A-layout round trip), rescale O
#pragma unroll
        for (int sub = 0; sub < 2; sub++)
#pragma unroll
            for (int r = 0; r < 4; r++)
                Pb[w][(rgrp + r)*40 + sub*16 + colj] = f2b(s[sub][r]);
#pragma unroll
        for (int d = 0; d < 4; d++)
#pragma unroll
            for (int r = 0; r < 4; r++) oacc[d][r] *= alpha[r];
        __syncthreads();
        bf16x8 ap = *(const bf16x8*)&Pb[w][fr*40 + fko];
#pragma unroll
        for (int d = 0; d < 4; d++){
            bf16x8 bv = *(const bf16x8*)&Vt[(d*16 + fr)*40 + fko];
            oacc[d] = __builtin_amdgcn_mfma_f32_16x16x32_bf16(ap, bv, oacc[d], 0, 0, 0);
        }
    }
    // epilogue
#pragma unroll
    for (int r = 0; r < 4; r++){
        int qi = q0 + rgrp + r;
        if (qi < NSEQ){
            float inv = 1.0f / lrun[r];
#pragma unroll
            for (int d = 0; d < 4; d++)
                out[((long)(b*NSEQ + qi))*Cq + h*64 + d*16 + colj] = f2b(oacc[d][r]*inv);
        }
    }
}

// ---------------- adapter up-projection + combine ----------------
__global__ void __launch_bounds__(256) adapter_up(const float* __restrict__ hid,
    const float* __restrict__ uw, const float* __restrict__ ub,
    const float* __restrict__ src, const float* __restrict__ res,
    const float* __restrict__ gatep, float* __restrict__ out, long total)
{
    long gid = (long)blockIdx.x*256 + threadIdx.x;
    if (gid >= total) return;
    long m = gid / Cq; int c = (int)(gid % Cq);
    const float* hr = hid + m*16;
    const float* ur = uw + c*16;
    float acc = 0.f;
#pragma unroll
    for (int r = 0; r < 16; r++) acc += hr[r]*ur[r];
    float gate = gatep ? gatep[0] : 1.0f;
    float v = gate * (acc + ub[c] + src[gid]);
    if (res) v += res[gid];
    out[gid] = v;
}

// ---------------- local branch: attention only, bf16 QKV in/out ----------------
__global__ void __launch_bounds__(512) local_attn(const u16* __restrict__ QKVg,
    const int* __restrict__ idx, u16* __restrict__ aout16)
{
    __shared__ float qh[32*HPAD];
    __shared__ float kh[32*HPAD];
    __shared__ float vh[32*HPAD];
    __shared__ float sc[32*33];
    __shared__ float srow[32];
    __shared__ int   rows[32];
    int g = blockIdx.x;
    int tid = threadIdx.x;
    if (tid < 32) rows[tid] = idx[g*Kg + tid];
    __syncthreads();
    int tok = tid >> 4;
    int d4  = (tid & 15) * 4;
    int tx  = tid & 31, ty = tid >> 5;
    for (int h = 0; h < Hq; h++){
        {
            const u16* base = QKVg + (long)rows[tok]*1152 + h*64 + d4;
            ushort4 qv = *(const ushort4*)(base);
            ushort4 kv = *(const ushort4*)(base + 384);
            ushort4 vv = *(const ushort4*)(base + 768);
            float* qd = qh + tok*HPAD + d4;
            float* kd = kh + tok*HPAD + d4;
            float* vd = vh + tok*HPAD + d4;
            qd[0]=b2f(qv.x); qd[1]=b2f(qv.y); qd[2]=b2f(qv.z); qd[3]=b2f(qv.w);
            kd[0]=b2f(kv.x); kd[1]=b2f(kv.y); kd[2]=b2f(kv.z); kd[3]=b2f(kv.w);
            vd[0]=b2f(vv.x); vd[1]=b2f(vv.y); vd[2]=b2f(vv.z); vd[3]=b2f(vv.w);
        }
        __syncthreads();
#pragma unroll
        for (int ii = 0; ii < 2; ii++){
            int i = ty + 16*ii;
            const float* qp = qh + i*HPAD;
            const float* kp = kh + tx*HPAD;
            float s = 0.f;
#pragma unroll
            for (int d16 = 0; d16 < 16; d16++){
                float4 q4 = *(const float4*)(qp + 4*d16);
                float4 k4 = *(const float4*)(kp + 4*d16);
                s += q4.x*k4.x + q4.y*k4.y + q4.z*k4.z + q4.w*k4.w;
            }
            sc[i*33 + tx] = s * 0.125f;
        }
        __syncthreads();
        if (tid < 32){
            float mx = -3e38f;
            for (int j = 0; j < 32; j++) mx = fmaxf(mx, sc[tid*33 + j]);
            float sm = 0.f;
            for (int j = 0; j < 32; j++){
                float e = __expf(sc[tid*33 + j] - mx); sc[tid*33 + j] = e; sm += e;
            }
            srow[tid] = 1.f/sm;
        }
        __syncthreads();
        {
            int d = tid & 63; int i0 = tid >> 6;
#pragma unroll
            for (int ii = 0; ii < 4; ii++){
                int i = i0 + 8*ii;
                const float* pp = sc + i*33;
                float o = 0.f;
#pragma unroll
                for (int j = 0; j < 32; j++) o += pp[j]*vh[j*HPAD + d];
                aout16[((long)(g*32 + i))*Cq + h*64 + d] = f2b(o * srow[i]);
            }
        }
        __syncthreads();
    }
}

// ---------------- pool: residual + max/mean + BN-gelu + center ----------------
__global__ void __launch_bounds__(128) pool_k(const u16* __restrict__ proj16,
    const float* __restrict__ Xf, const int* __restrict__ idx,
    const int* __restrict__ cidx, const float* __restrict__ bng,
    const float* __restrict__ bnb, float* __restrict__ vis)
{
    __shared__ int rows[32];
    int g = blockIdx.x;
    int tid = threadIdx.x;
    if (tid < 32) rows[tid] = idx[g*Kg + tid];
    __syncthreads();
    int crow = cidx[g];
    for (int c = tid; c < Cq; c += 128){
        float mx = -3e38f, sm = 0.f;
        for (int t = 0; t < 32; t++){
            float p = b2f(proj16[((long)(g*32 + t))*Cq + c]);
            float val = p + Xf[(long)rows[t]*Cq + c];
            mx = fmaxf(mx, val); sm += val;
        }
        float lc = mx + sm*(1.f/32.f);
        float u = gelu_f(lc * bng[c] * 0.9999950000374997f + bnb[c]);
        vis[(long)g*Cq + c] = u + 0.4f * Xf[(long)crow*Cq + c];
    }
}

// ---------------- inverse-distance interpolation + residual ----------------
__global__ void __launch_bounds__(128) interp_k(const float* __restrict__ Xf,
    const float* __restrict__ vis, const float* __restrict__ c1,
    const float* __restrict__ c2, float* __restrict__ newx)
{
    __shared__ float wsh[128];
    __shared__ float tot[2];
    int bn = blockIdx.x; int b = bn >> 9; int n = bn & 511;
    int tid = threadIdx.x;
    const float* p1 = c1 + (long)bn*3;
    float x1 = p1[0], y1 = p1[1], z1 = p1[2];
    const float* p2 = c2 + ((long)b*Sq + tid)*3;
    float x2 = p2[0], y2 = p2[1], z2 = p2[2];
    float d = (x1*x1 + y1*y1 + z1*z1) + (x2*x2 + y2*y2 + z2*z2)
            - 2.f*(x1*x2 + y1*y2 + z1*z2);
    float wv = 1.f/(d + 1e-8f);
    wsh[tid] = wv;
    float ss = wv;
#pragma unroll
    for (int m = 1; m < 64; m <<= 1) ss += __shfl_xor(ss, m);
    if ((tid & 63) == 0) tot[tid >> 6] = ss;
    __syncthreads();
    float inv = 1.f/(tot[0] + tot[1]);
    const float* vb = vis + (long)b*Sq*Cq;
    float a0 = 0.f, a1 = 0.f, a2 = 0.f;
    for (int s = 0; s < Sq; s++){
        float wq = wsh[s];
        const float* vr = vb + s*Cq + tid;
        a0 += wq*vr[0]; a1 += wq*vr[128]; a2 += wq*vr[256];
    }
    const float* xr = Xf + ((long)(b*NSEQ + Tq + n))*Cq;
    float* orow = newx + (long)bn*Cq;
    orow[tid]       = xr[tid]       + 0.4f*a0*inv;
    orow[tid + 128] = xr[tid + 128] + 0.4f*a1*inv;
    orow[tid + 256] = xr[tid + 256] + 0.4f*a2*inv;
}

// ---------------- launch ----------------
extern "C" void kernel_launch(void* const* d_in, const int* in_sizes, int n_in,
                              void* d_out, int out_size, void* d_ws, size_t ws_size,
                              hipStream_t stream)
{
    const float* x_in  = (const float*)d_in[0];
    const float* mask  = (const float*)d_in[1];
    const float* c1p   = (const float*)d_in[2];
    const float* c2p   = (const float*)d_in[3];
    const float* pe    = (const float*)d_in[5];
    const float* n1g   = (const float*)d_in[6];
    const float* n1b   = (const float*)d_in[7];
    const float* qkvw  = (const float*)d_in[8];
    const float* projw = (const float*)d_in[9];
    const float* projb = (const float*)d_in[10];
    const float* n2g   = (const float*)d_in[11];
    const float* n2b   = (const float*)d_in[12];
    const float* fc1w  = (const float*)d_in[13];
    const float* fc1b  = (const float*)d_in[14];
    const float* fc2w  = (const float*)d_in[15];
    const float* fc2b  = (const float*)d_in[16];
    const float* gate  = (const float*)d_in[17];
    const float* addw  = (const float*)d_in[18];
    const float* addb  = (const float*)d_in[19];
    const float* aduw  = (const float*)d_in[20];
    const float* adub  = (const float*)d_in[21];
    const float* ad1dw = (const float*)d_in[22];
    const float* ad1db = (const float*)d_in[23];
    const float* ad1uw = (const float*)d_in[24];
    const float* ad1ub = (const float*)d_in[25];
    const float* bng   = (const float*)d_in[26];
    const float* bnb   = (const float*)d_in[27];
    const float* a1qkvw= (const float*)d_in[28];
    const float* a1pw  = (const float*)d_in[29];
    const float* a1pb  = (const float*)d_in[30];
    const float* n3g   = (const float*)d_in[31];
    const float* n3b   = (const float*)d_in[32];
    const int*   idxp  = (const int*)d_in[33];
    const int*   cidxp = (const int*)d_in[34];

    // ---- workspace layout (bytes), total 252.4 MB ----
    char* w = (char*)d_ws;
    float* X    = (float*)w;                       // 16896x384 f32   [0, 25952256)
    u16*   WB   = (u16*)(w + 25952256);            // bf16 weights    [.., 30670848)
    u16*   Bb16 = (u16*)(w + 30670848);            // 16896x384 bf16  [.., 43646976)
    char*  R1   = w + 43646976;                    // 100663296 B (hid16 / aout16)
    char*  R2   = R1 + 100663296;                  // 100663296 B (QKVg / C1 / proj16 / newx)
    float* D1   = (float*)(R2 + 100663296);        // 16896x16 f32
    float* V    = D1 + ROWS*16;                    // 4096x384 f32

    u16* qkvw16  = WB;
    u16* projw16 = WB +  442368;
    u16* fc1w16  = WB +  589824;
    u16* fc2w16  = WB + 1179648;
    u16* a1qkv16 = WB + 1769472;
    u16* a1pw16  = WB + 2211840;

    u16*   hid16  = (u16*)R1;       // 16896x1536 bf16 (MLP phase)
    u16*   aout16 = (u16*)R1;       // 131072x384 bf16 (local phase)
    u16*   QKVg   = (u16*)R2;       // 16896x1152 bf16 (38.9 MB; global then local)
    float* C1     = (float*)R2;     // 16896x384 f32 x_fn (MLP/adapter phase)
    u16*   proj16 = (u16*)R2;       // 131072x384 bf16 (local proj)
    float* newx   = (float*)R2;     // 16384x384 f32 (interp out)

    long totX = (long)ROWS*Cq;

    conv6<<<9216, 256, 0, stream>>>(qkvw, projw, fc1w, fc2w, a1qkvw, a1pw, WB);
    build_x<<<25344, 256, 0, stream>>>(x_in, pe, X, totX);
    ln_rows<<<4224, 256, 0, stream>>>(X, n1g, n1b, Bb16, ROWS);
    gemm_bf16<<<dim3(9, 132), 256, 0, stream>>>(Bb16, qkvw16, nullptr, nullptr, QKVg,
                                                ROWS, 1152, Cq, 4);
    attn_mfma<<<1728, 256, 0, stream>>>(QKVg, mask, Bb16);
    gemm_bf16<<<dim3(3, 132), 256, 0, stream>>>(Bb16, projw16, projb, X, nullptr,
                                                ROWS, Cq, Cq, 3);
    ln_rows<<<4224, 256, 0, stream>>>(X, n2g, n2b, Bb16, ROWS);
    gemm_bf16<<<dim3(12, 132), 256, 0, stream>>>(Bb16, fc1w16, fc1b, nullptr, hid16,
                                                 ROWS, 1536, Cq, 2);
    gemm_bf16<<<dim3(3, 132), 256, 0, stream>>>(hid16, fc2w16, fc2b, C1, nullptr,
                                                ROWS, Cq, 1536, 1);
    gemm_f32<<<dim3(1, 264), 256, 0, stream>>>(C1, addw, addb, D1, ROWS, 16, Cq, 2);
    adapter_up<<<25344, 256, 0, stream>>>(D1, aduw, adub, C1, X, gate, X, totX);
    // local branch
    ln_rows<<<4224, 256, 0, stream>>>(X, n3g, n3b, Bb16, ROWS);
    gemm_bf16<<<dim3(9, 132), 256, 0, stream>>>(Bb16, a1qkv16, nullptr, nullptr, QKVg,
                                                ROWS, 1152, Cq, 4);
    local_attn<<<4096, 512, 0, stream>>>(QKVg, idxp, aout16);
    gemm_bf16<<<dim3(3, 1024), 256, 0, stream>>>(aout16, a1pw16, a1pb, nullptr, proj16,
                                                 LROWS, Cq, Cq, 4);
    pool_k<<<4096, 128, 0, stream>>>(proj16, X, idxp, cidxp, bng, bnb, V);
    interp_k<<<16384, 128, 0, stream>>>(X, V, c1p, c2p, newx);
    gemm_f32<<<dim3(1, 256), 256, 0, stream>>>(newx, ad1dw, ad1db, D1, Bq*Gq, 16, Cq, 2);
    adapter_up<<<24576, 256, 0, stream>>>(D1, ad1uw, ad1ub, newx, nullptr, nullptr,
                                          (float*)d_out, (long)Bq*Gq*Cq);
}

// Round 5
// 1031.736 us; speedup vs baseline: 14.4527x; 1.5127x over previous
//
#include <hip/hip_runtime.h>
#include <hip/hip_bf16.h>

// ---------------- constants ----------------
#define Bq 32
#define Tq 16
#define Gq 512
#define NSEQ 528           // T + G
#define Cq 384
#define Hq 6
#define Sq 128
#define Kg 32              // GROUP_SIZE
#define ROWS (Bq*NSEQ)     // 16896
#define HPAD 68            // fp32 LDS row stride (16B-aligned rows)
#define LROWS (Bq*Sq*Kg)   // 131072 local tokens

typedef unsigned short u16;
typedef short bf16x8 __attribute__((ext_vector_type(8)));   // 8 bf16 in 4 VGPRs
typedef float f32x4  __attribute__((ext_vector_type(4)));

__device__ __forceinline__ float gelu_f(float x){
    return 0.5f * x * (1.0f + erff(x * 0.70710678118654752f));
}
__device__ __forceinline__ u16 f2b(float x){
    union { float f; unsigned u; } v; v.f = x;
    return (u16)((v.u + 0x7fffu + ((v.u >> 16) & 1u)) >> 16);
}
__device__ __forceinline__ float b2f(u16 h){
    union { float f; unsigned u; } v; v.u = ((unsigned)h) << 16; return v.f;
}

// ---------------- build X = concat(prompt, x) ----------------
__global__ void __launch_bounds__(256) build_x(const float* __restrict__ xin,
    const float* __restrict__ pe, float* __restrict__ X, long total)
{
    long gid = (long)blockIdx.x*256 + threadIdx.x;
    if (gid >= total) return;
    int  c   = (int)(gid % Cq);
    long row = gid / Cq;
    int  p   = (int)(row % NSEQ);
    long b   = row / NSEQ;
    float v = (p < Tq) ? pe[p*Cq + c] : xin[(b*Gq + (p - Tq))*Cq + c];
    X[gid] = v;
}

// ---------------- weight conversion fp32 -> bf16 (6 matrices) ----------------
__global__ void __launch_bounds__(256) conv6(const float* __restrict__ s0,
    const float* __restrict__ s1, const float* __restrict__ s2,
    const float* __restrict__ s3, const float* __restrict__ s4,
    const float* __restrict__ s5, u16* __restrict__ dst)
{
    long i = (long)blockIdx.x*256 + threadIdx.x;
    if (i >= 2359296) return;
    float v;
    if      (i <  442368) v = s0[i];
    else if (i <  589824) v = s1[i -  442368];
    else if (i < 1179648) v = s2[i -  589824];
    else if (i < 1769472) v = s3[i - 1179648];
    else if (i < 2211840) v = s4[i - 1769472];
    else                  v = s5[i - 2211840];
    dst[i] = f2b(v);
}

// ---------------- LayerNorm, one wave per row, bf16 out ----------------
__global__ void __launch_bounds__(256) ln_rows(const float* __restrict__ in,
    const float* __restrict__ gw, const float* __restrict__ bw,
    u16* __restrict__ out, int rows)
{
    int w = threadIdx.x >> 6, lane = threadIdx.x & 63;
    int row = blockIdx.x*4 + w;
    if (row >= rows) return;
    const float* xr = in + (long)row*Cq;
    float v[6]; float s = 0.f, s2 = 0.f;
#pragma unroll
    for (int j = 0; j < 6; j++){ float x = xr[lane + 64*j]; v[j] = x; s += x; s2 += x*x; }
#pragma unroll
    for (int m = 1; m < 64; m <<= 1){ s += __shfl_xor(s, m); s2 += __shfl_xor(s2, m); }
    float mean = s * (1.f/384.f);
    float var  = s2 * (1.f/384.f) - mean*mean;
    float rs   = rsqrtf(var + 1e-5f);
    u16* orow = out + (long)row*Cq;
#pragma unroll
    for (int j = 0; j < 6; j++){
        int c = lane + 64*j;
        orow[c] = f2b((v[j] - mean) * rs * gw[c] + bw[c]);
    }
}

// ---------------- bf16 MFMA GEMM: C = epi(A @ W^T) ----------------
// A: M x K bf16 row-major, W: N x K bf16 row-major. M%128==0, N%128==0, K%32==0.
// epi: 0 none->f32, 1 +bias->f32, 2 gelu(+bias)->bf16, 3 Cf += acc+bias (f32 RMW),
//      4 (+bias if given)->bf16
__global__ void __launch_bounds__(256) gemm_bf16(const u16* __restrict__ A,
    const u16* __restrict__ W, const float* __restrict__ bias,
    float* __restrict__ Cf, u16* __restrict__ Cb, int M, int N, int K, int epi)
{
    __shared__ u16 As[128*40];   // 32 data + 8 pad bf16 per row
    __shared__ u16 Ws[128*40];
    int t = threadIdx.x;
    int m0 = blockIdx.y*128, n0 = blockIdx.x*128;
    int wv = t >> 6, lane = t & 63;
    int wm = (wv >> 1)*64, wn = (wv & 1)*64;
    int fm = lane & 15;            // row-in-tile for both A and W frags
    int fk = (lane >> 4) * 8;      // k offset (8 bf16)
    int sr = t >> 2;               // staging row 0..63
    int sc8 = (t & 3) * 8;         // staging col (bf16)
    f32x4 acc[4][4];
#pragma unroll
    for (int i = 0; i < 4; i++)
#pragma unroll
        for (int j = 0; j < 4; j++) acc[i][j] = (f32x4){0.f,0.f,0.f,0.f};

    for (int k0 = 0; k0 < K; k0 += 32){
        *(uint4*)&As[sr*40 + sc8]      = *(const uint4*)(A + (long)(m0+sr)*K    + k0 + sc8);
        *(uint4*)&As[(sr+64)*40 + sc8] = *(const uint4*)(A + (long)(m0+sr+64)*K + k0 + sc8);
        *(uint4*)&Ws[sr*40 + sc8]      = *(const uint4*)(W + (long)(n0+sr)*K    + k0 + sc8);
        *(uint4*)&Ws[(sr+64)*40 + sc8] = *(const uint4*)(W + (long)(n0+sr+64)*K + k0 + sc8);
        __syncthreads();
        bf16x8 af[4], bf[4];
#pragma unroll
        for (int im = 0; im < 4; im++) af[im] = *(const bf16x8*)&As[(wm + im*16 + fm)*40 + fk];
#pragma unroll
        for (int in = 0; in < 4; in++) bf[in] = *(const bf16x8*)&Ws[(wn + in*16 + fm)*40 + fk];
#pragma unroll
        for (int im = 0; im < 4; im++)
#pragma unroll
            for (int in = 0; in < 4; in++)
                acc[im][in] = __builtin_amdgcn_mfma_f32_16x16x32_bf16(af[im], bf[in], acc[im][in], 0, 0, 0);
        __syncthreads();
    }
    int lr = lane >> 4, lc = lane & 15;
#pragma unroll
    for (int im = 0; im < 4; im++){
#pragma unroll
        for (int in = 0; in < 4; in++){
#pragma unroll
            for (int r = 0; r < 4; r++){
                int m = m0 + wm + im*16 + lr*4 + r;
                int n = n0 + wn + in*16 + lc;
                float v = acc[im][in][r];
                if (epi >= 1 && bias) v += bias[n];
                if (epi == 2) v = gelu_f(v);
                long off = (long)m*N + n;
                if (epi == 3) v += Cf[off];
                if (epi == 2 || epi == 4) Cb[off] = f2b(v);
                else                      Cf[off] = v;
            }
        }
    }
}

// ---------------- generic fp32 GEMM (small adapters only) ----------------
__global__ void __launch_bounds__(256) gemm_f32(const float* __restrict__ A,
    const float* __restrict__ W, const float* __restrict__ bias,
    float* __restrict__ C, int M, int N, int K, int epi)
{
    __shared__ float As[16][HPAD];
    __shared__ float Ws[16][HPAD];
    int tid = threadIdx.x;
    int m0 = blockIdx.y*64, n0 = blockIdx.x*64;
    int tm = tid >> 4, tn = tid & 15;
    int lr = tid >> 2;
    int lc4 = (tid & 3) * 4;
    float acc[4][4] = {};
    for (int k0 = 0; k0 < K; k0 += 16){
        {
            int m = m0 + lr;
            float4 v = make_float4(0.f,0.f,0.f,0.f);
            if (m < M) v = *(const float4*)(A + (long)m*K + k0 + lc4);
            As[lc4+0][lr] = v.x; As[lc4+1][lr] = v.y; As[lc4+2][lr] = v.z; As[lc4+3][lr] = v.w;
            int n = n0 + lr;
            float4 wv = make_float4(0.f,0.f,0.f,0.f);
            if (n < N) wv = *(const float4*)(W + (long)n*K + k0 + lc4);
            Ws[lc4+0][lr] = wv.x; Ws[lc4+1][lr] = wv.y; Ws[lc4+2][lr] = wv.z; Ws[lc4+3][lr] = wv.w;
        }
        __syncthreads();
#pragma unroll
        for (int kk = 0; kk < 16; kk++){
            float4 a4 = *(const float4*)&As[kk][4*tm];
            float4 b4 = *(const float4*)&Ws[kk][4*tn];
            float a[4] = {a4.x, a4.y, a4.z, a4.w};
            float bb[4] = {b4.x, b4.y, b4.z, b4.w};
#pragma unroll
            for (int i = 0; i < 4; i++)
#pragma unroll
                for (int j = 0; j < 4; j++) acc[i][j] += a[i]*bb[j];
        }
        __syncthreads();
    }
#pragma unroll
    for (int i = 0; i < 4; i++){
        int m = m0 + 4*tm + i; if (m >= M) continue;
#pragma unroll
        for (int j = 0; j < 4; j++){
            int n = n0 + 4*tn + j; if (n >= N) continue;
            float v = acc[i][j];
            if (epi >= 1 && bias) v += bias[n];
            if (epi == 2) v = gelu_f(v);
            long off = (long)m*N + n;
            if (epi == 3) v += C[off];
            C[off] = v;
        }
    }
}

// ---------------- flash-style MFMA global attention ----------------
__global__ void __launch_bounds__(256) attn_mfma(const u16* __restrict__ QKVg,
    const float* __restrict__ mask, u16* __restrict__ out)
{
    __shared__ u16 Ks[32*72];       // 32 keys x 64 d (+8 pad)
    __shared__ u16 Vt[64*40];       // 64 d x 32 keys (+8 pad), transposed
    __shared__ u16 Pb[4][16*40];    // per-wave P tile 16 q x 32 keys (+8 pad)
    int blk = blockIdx.x;
    int qt = blk % 9; int bh = blk / 9;
    int h = bh % Hq;  int b = bh / Hq;
    int t = threadIdx.x; int w = t >> 6; int lane = t & 63;
    int q0 = qt*64 + w*16;
    int fr  = lane & 15;
    int fko = (lane >> 4) * 8;
    int colj = lane & 15;
    int rgrp = (lane >> 4) * 4;

    int qrow = q0 + fr; int qrc = qrow < NSEQ ? qrow : NSEQ-1;
    const u16* qbase = QKVg + (long)(b*NSEQ + qrc)*1152 + h*64;
    bf16x8 aq0 = *(const bf16x8*)(qbase + fko);
    bf16x8 aq1 = *(const bf16x8*)(qbase + 32 + fko);

    f32x4 oacc[4];
#pragma unroll
    for (int d = 0; d < 4; d++) oacc[d] = (f32x4){0.f,0.f,0.f,0.f};
    float mrun[4], lrun[4];
#pragma unroll
    for (int r = 0; r < 4; r++){ mrun[r] = -1e30f; lrun[r] = 0.f; }

    int skey = t >> 3;
    int sd8  = (t & 7) * 8;

    for (int kc = 0; kc < 17; kc++){
        __syncthreads();
        {
            int j = kc*32 + skey;
            bf16x8 kv = {0,0,0,0,0,0,0,0};
            bf16x8 vv = {0,0,0,0,0,0,0,0};
            if (j < NSEQ){
                const u16* kb = QKVg + (long)(b*NSEQ + j)*1152 + 384 + h*64 + sd8;
                kv = *(const bf16x8*)kb;
                vv = *(const bf16x8*)(kb + 384);
            }
            *(bf16x8*)&Ks[skey*72 + sd8] = kv;
#pragma unroll
            for (int e = 0; e < 8; e++) Vt[(sd8+e)*40 + skey] = (u16)vv[e];
        }
        __syncthreads();
        f32x4 s[2];
#pragma unroll
        for (int sub = 0; sub < 2; sub++){
            bf16x8 bk0 = *(const bf16x8*)&Ks[(sub*16 + fr)*72 + fko];
            bf16x8 bk1 = *(const bf16x8*)&Ks[(sub*16 + fr)*72 + 32 + fko];
            f32x4 z = (f32x4){0.f,0.f,0.f,0.f};
            z = __builtin_amdgcn_mfma_f32_16x16x32_bf16(aq0, bk0, z, 0, 0, 0);
            z = __builtin_amdgcn_mfma_f32_16x16x32_bf16(aq1, bk1, z, 0, 0, 0);
            s[sub] = z;
        }
#pragma unroll
        for (int sub = 0; sub < 2; sub++){
#pragma unroll
            for (int r = 0; r < 4; r++){
                int qi = q0 + rgrp + r;
                int jj = kc*32 + sub*16 + colj;
                float sv = s[sub][r] * 0.125f;
                if (jj < Gq && qi < Gq) sv -= 100000.0f * mask[((long)b*Gq + qi)*Gq + jj];
                if (jj >= NSEQ) sv = -1e30f;
                s[sub][r] = sv;
            }
        }
        float alpha[4];
#pragma unroll
        for (int r = 0; r < 4; r++){
            float mx = fmaxf(s[0][r], s[1][r]);
#pragma unroll
            for (int mm = 1; mm < 16; mm <<= 1) mx = fmaxf(mx, __shfl_xor(mx, mm));
            float mnew = fmaxf(mrun[r], mx);
            alpha[r] = __expf(mrun[r] - mnew);
            mrun[r] = mnew;
            float p0 = __expf(s[0][r] - mnew);
            float p1 = __expf(s[1][r] - mnew);
            s[0][r] = p0; s[1][r] = p1;
            float ps = p0 + p1;
#pragma unroll
            for (int mm = 1; mm < 16; mm <<= 1) ps += __shfl_xor(ps, mm);
            lrun[r] = lrun[r]*alpha[r] + ps;
        }
#pragma unroll
        for (int sub = 0; sub < 2; sub++)
#pragma unroll
            for (int r = 0; r < 4; r++)
                Pb[w][(rgrp + r)*40 + sub*16 + colj] = f2b(s[sub][r]);
#pragma unroll
        for (int d = 0; d < 4; d++)
#pragma unroll
            for (int r = 0; r < 4; r++) oacc[d][r] *= alpha[r];
        __syncthreads();
        bf16x8 ap = *(const bf16x8*)&Pb[w][fr*40 + fko];
#pragma unroll
        for (int d = 0; d < 4; d++){
            bf16x8 bv = *(const bf16x8*)&Vt[(d*16 + fr)*40 + fko];
            oacc[d] = __builtin_amdgcn_mfma_f32_16x16x32_bf16(ap, bv, oacc[d], 0, 0, 0);
        }
    }
#pragma unroll
    for (int r = 0; r < 4; r++){
        int qi = q0 + rgrp + r;
        if (qi < NSEQ){
            float inv = 1.0f / lrun[r];
#pragma unroll
            for (int d = 0; d < 4; d++)
                out[((long)(b*NSEQ + qi))*Cq + h*64 + d*16 + colj] = f2b(oacc[d][r]*inv);
        }
    }
}

// ---------------- adapter up-projection + combine ----------------
__global__ void __launch_bounds__(256) adapter_up(const float* __restrict__ hid,
    const float* __restrict__ uw, const float* __restrict__ ub,
    const float* __restrict__ src, const float* __restrict__ res,
    const float* __restrict__ gatep, float* __restrict__ out, long total)
{
    long gid = (long)blockIdx.x*256 + threadIdx.x;
    if (gid >= total) return;
    long m = gid / Cq; int c = (int)(gid % Cq);
    const float* hr = hid + m*16;
    const float* ur = uw + c*16;
    float acc = 0.f;
#pragma unroll
    for (int r = 0; r < 16; r++) acc += hr[r]*ur[r];
    float gate = gatep ? gatep[0] : 1.0f;
    float v = gate * (acc + ub[c] + src[gid]);
    if (res) v += res[gid];
    out[gid] = v;
}

// ---------------- local branch: MFMA attention, 1 group / 256-thr block ------
// QKVg: (16896, 1152) bf16. aout16: (131072, 384) bf16 attention output.
__global__ void __launch_bounds__(256) local_attn(const u16* __restrict__ QKVg,
    const int* __restrict__ idx, u16* __restrict__ aout16)
{
    __shared__ u16 Qs[32*72];      // 32 tok x 64 d (+8 pad)
    __shared__ u16 Ksm[32*72];
    __shared__ u16 Vt[64*40];      // 64 d x 32 tok (+8 pad)
    __shared__ float sc[32*36];    // scores f32
    __shared__ u16 Pa[32*40];      // P bf16 A-layout
    __shared__ float linv[32];
    __shared__ int rows[32];
    int g = blockIdx.x;
    int t = threadIdx.x;
    int w = t >> 6, lane = t & 63;
    if (t < 32) rows[t] = idx[g*Kg + t];
    __syncthreads();
    int srow = t & 31;             // staging row (varies across lanes -> LDS-friendly)
    int d8   = (t >> 5) * 8;       // staging d offset
    int fr = lane & 15, fko = (lane >> 4)*8;
    int colj = lane & 15, rgrp = (lane >> 4)*4;
    int it = w >> 1, jt = w & 1;   // score tile / PV row tile
    int smrow = w*8 + (lane >> 3); // softmax row
    int smc   = (lane & 7) * 4;    // softmax col group

    for (int h = 0; h < Hq; h++){
        {
            const u16* base = QKVg + (long)rows[srow]*1152 + h*64 + d8;
            bf16x8 qv = *(const bf16x8*)(base);
            bf16x8 kv = *(const bf16x8*)(base + 384);
            bf16x8 vv = *(const bf16x8*)(base + 768);
            *(bf16x8*)&Qs[srow*72 + d8]  = qv;
            *(bf16x8*)&Ksm[srow*72 + d8] = kv;
#pragma unroll
            for (int e = 0; e < 8; e++) Vt[(d8+e)*40 + srow] = (u16)vv[e];
        }
        __syncthreads();
        // QK^T: wave computes 16x16 tile (it, jt)
        {
            bf16x8 a0 = *(const bf16x8*)&Qs[(it*16+fr)*72 + fko];
            bf16x8 a1 = *(const bf16x8*)&Qs[(it*16+fr)*72 + 32 + fko];
            bf16x8 b0 = *(const bf16x8*)&Ksm[(jt*16+fr)*72 + fko];
            bf16x8 b1 = *(const bf16x8*)&Ksm[(jt*16+fr)*72 + 32 + fko];
            f32x4 z = (f32x4){0.f,0.f,0.f,0.f};
            z = __builtin_amdgcn_mfma_f32_16x16x32_bf16(a0, b0, z, 0, 0, 0);
            z = __builtin_amdgcn_mfma_f32_16x16x32_bf16(a1, b1, z, 0, 0, 0);
#pragma unroll
            for (int r = 0; r < 4; r++)
                sc[(it*16 + rgrp + r)*36 + jt*16 + colj] = z[r]*0.125f;
        }
        __syncthreads();
        // softmax: 8-lane groups per row, 4 cols/lane
        {
            float4 s4 = *(const float4*)&sc[smrow*36 + smc];
            float mx = fmaxf(fmaxf(s4.x, s4.y), fmaxf(s4.z, s4.w));
#pragma unroll
            for (int mm = 1; mm < 8; mm <<= 1) mx = fmaxf(mx, __shfl_xor(mx, mm));
            float p0 = __expf(s4.x - mx), p1 = __expf(s4.y - mx);
            float p2 = __expf(s4.z - mx), p3 = __expf(s4.w - mx);
            float sm = p0 + p1 + p2 + p3;
#pragma unroll
            for (int mm = 1; mm < 8; mm <<= 1) sm += __shfl_xor(sm, mm);
            if ((lane & 7) == 0) linv[smrow] = 1.0f / sm;
            Pa[smrow*40 + smc + 0] = f2b(p0);
            Pa[smrow*40 + smc + 1] = f2b(p1);
            Pa[smrow*40 + smc + 2] = f2b(p2);
            Pa[smrow*40 + smc + 3] = f2b(p3);
        }
        __syncthreads();
        // PV: wave w -> row tile (w>>1), d-tiles {w&1, (w&1)+2}
        {
            bf16x8 ap = *(const bf16x8*)&Pa[(it*16+fr)*40 + fko];
#pragma unroll
            for (int dd = 0; dd < 2; dd++){
                int dt = jt + dd*2;
                bf16x8 bv = *(const bf16x8*)&Vt[(dt*16+fr)*40 + fko];
                f32x4 o = (f32x4){0.f,0.f,0.f,0.f};
                o = __builtin_amdgcn_mfma_f32_16x16x32_bf16(ap, bv, o, 0, 0, 0);
#pragma unroll
                for (int r = 0; r < 4; r++){
                    int row = it*16 + rgrp + r;
                    aout16[((long)(g*32 + row))*Cq + h*64 + dt*16 + colj] =
                        f2b(o[r] * linv[row]);
                }
            }
        }
        __syncthreads();
    }
}

// ---------------- pool: residual + max/mean + BN-gelu + center ----------------
__global__ void __launch_bounds__(128) pool_k(const u16* __restrict__ proj16,
    const float* __restrict__ Xf, const int* __restrict__ idx,
    const int* __restrict__ cidx, const float* __restrict__ bng,
    const float* __restrict__ bnb, float* __restrict__ vis)
{
    __shared__ int rows[32];
    int g = blockIdx.x;
    int tid = threadIdx.x;
    if (tid < 32) rows[tid] = idx[g*Kg + tid];
    __syncthreads();
    int crow = cidx[g];
    for (int c = tid; c < Cq; c += 128){
        float mx = -3e38f, sm = 0.f;
        for (int t = 0; t < 32; t++){
            float p = b2f(proj16[((long)(g*32 + t))*Cq + c]);
            float val = p + Xf[(long)rows[t]*Cq + c];
            mx = fmaxf(mx, val); sm += val;
        }
        float lc = mx + sm*(1.f/32.f);
        float u = gelu_f(lc * bng[c] * 0.9999950000374997f + bnb[c]);
        vis[(long)g*Cq + c] = u + 0.4f * Xf[(long)crow*Cq + c];
    }
}

// ---------------- inverse-distance interp: 8 points/block share vis reads ----
__global__ void __launch_bounds__(128) interp_k(const float* __restrict__ Xf,
    const float* __restrict__ vis, const float* __restrict__ c1,
    const float* __restrict__ c2, float* __restrict__ newx)
{
    __shared__ float wsh[8*128];
    __shared__ float inv8[8];
    int blk = blockIdx.x;          // b*64 + ntile
    int b = blk >> 6, nt = blk & 63;
    int tid = threadIdx.x;
#pragma unroll
    for (int i = 0; i < 8; i++){
        int id = tid + i*128;      // 0..1023
        int nl = id >> 7, s = id & 127;
        const float* p1 = c1 + ((long)b*Gq + nt*8 + nl)*3;
        const float* p2 = c2 + ((long)b*Sq + s)*3;
        float x1 = p1[0], y1 = p1[1], z1 = p1[2];
        float x2 = p2[0], y2 = p2[1], z2 = p2[2];
        float d = (x1*x1 + y1*y1 + z1*z1) + (x2*x2 + y2*y2 + z2*z2)
                - 2.f*(x1*x2 + y1*y2 + z1*z2);
        wsh[nl*128 + s] = 1.f/(d + 1e-8f);
    }
    __syncthreads();
    if (tid < 8){
        float sum = 0.f;
        for (int s = 0; s < Sq; s++) sum += wsh[tid*128 + s];
        inv8[tid] = 1.f/sum;
    }
    __syncthreads();
    float acc[8][3];
#pragma unroll
    for (int n = 0; n < 8; n++){ acc[n][0] = 0.f; acc[n][1] = 0.f; acc[n][2] = 0.f; }
    const float* vb = vis + (long)b*Sq*Cq + tid;
    for (int s = 0; s < Sq; s++){
        float v0 = vb[s*Cq], v1 = vb[s*Cq + 128], v2 = vb[s*Cq + 256];
#pragma unroll
        for (int n = 0; n < 8; n++){
            float wq = wsh[n*128 + s];
            acc[n][0] += wq*v0; acc[n][1] += wq*v1; acc[n][2] += wq*v2;
        }
    }
#pragma unroll
    for (int n = 0; n < 8; n++){
        int gn = nt*8 + n;
        const float* xr = Xf + ((long)(b*NSEQ + Tq + gn))*Cq;
        float* orow = newx + ((long)(b*Gq + gn))*Cq;
        float sf = 0.4f * inv8[n];
        orow[tid]       = xr[tid]       + sf*acc[n][0];
        orow[tid + 128] = xr[tid + 128] + sf*acc[n][1];
        orow[tid + 256] = xr[tid + 256] + sf*acc[n][2];
    }
}

// ---------------- launch ----------------
extern "C" void kernel_launch(void* const* d_in, const int* in_sizes, int n_in,
                              void* d_out, int out_size, void* d_ws, size_t ws_size,
                              hipStream_t stream)
{
    const float* x_in  = (const float*)d_in[0];
    const float* mask  = (const float*)d_in[1];
    const float* c1p   = (const float*)d_in[2];
    const float* c2p   = (const float*)d_in[3];
    const float* pe    = (const float*)d_in[5];
    const float* n1g   = (const float*)d_in[6];
    const float* n1b   = (const float*)d_in[7];
    const float* qkvw  = (const float*)d_in[8];
    const float* projw = (const float*)d_in[9];
    const float* projb = (const float*)d_in[10];
    const float* n2g   = (const float*)d_in[11];
    const float* n2b   = (const float*)d_in[12];
    const float* fc1w  = (const float*)d_in[13];
    const float* fc1b  = (const float*)d_in[14];
    const float* fc2w  = (const float*)d_in[15];
    const float* fc2b  = (const float*)d_in[16];
    const float* gate  = (const float*)d_in[17];
    const float* addw  = (const float*)d_in[18];
    const float* addb  = (const float*)d_in[19];
    const float* aduw  = (const float*)d_in[20];
    const float* adub  = (const float*)d_in[21];
    const float* ad1dw = (const float*)d_in[22];
    const float* ad1db = (const float*)d_in[23];
    const float* ad1uw = (const float*)d_in[24];
    const float* ad1ub = (const float*)d_in[25];
    const float* bng   = (const float*)d_in[26];
    const float* bnb   = (const float*)d_in[27];
    const float* a1qkvw= (const float*)d_in[28];
    const float* a1pw  = (const float*)d_in[29];
    const float* a1pb  = (const float*)d_in[30];
    const float* n3g   = (const float*)d_in[31];
    const float* n3b   = (const float*)d_in[32];
    const int*   idxp  = (const int*)d_in[33];
    const int*   cidxp = (const int*)d_in[34];

    // ---- workspace layout (bytes), total 252.4 MB ----
    char* w = (char*)d_ws;
    float* X    = (float*)w;                       // 16896x384 f32   [0, 25952256)
    u16*   WB   = (u16*)(w + 25952256);            // bf16 weights    [.., 30670848)
    u16*   Bb16 = (u16*)(w + 30670848);            // 16896x384 bf16  [.., 43646976)
    char*  R1   = w + 43646976;                    // 100663296 B (hid16 / aout16)
    char*  R2   = R1 + 100663296;                  // 100663296 B (QKVg / C1 / proj16 / newx)
    float* D1   = (float*)(R2 + 100663296);        // 16896x16 f32
    float* V    = D1 + ROWS*16;                    // 4096x384 f32

    u16* qkvw16  = WB;
    u16* projw16 = WB +  442368;
    u16* fc1w16  = WB +  589824;
    u16* fc2w16  = WB + 1179648;
    u16* a1qkv16 = WB + 1769472;
    u16* a1pw16  = WB + 2211840;

    u16*   hid16  = (u16*)R1;       // 16896x1536 bf16 (MLP phase)
    u16*   aout16 = (u16*)R1;       // 131072x384 bf16 (local phase)
    u16*   QKVg   = (u16*)R2;       // 16896x1152 bf16 (38.9 MB; global then local)
    float* C1     = (float*)R2;     // 16896x384 f32 x_fn (MLP/adapter phase)
    u16*   proj16 = (u16*)R2;       // 131072x384 bf16 (local proj)
    float* newx   = (float*)R2;     // 16384x384 f32 (interp out)

    long totX = (long)ROWS*Cq;

    conv6<<<9216, 256, 0, stream>>>(qkvw, projw, fc1w, fc2w, a1qkvw, a1pw, WB);
    build_x<<<25344, 256, 0, stream>>>(x_in, pe, X, totX);
    ln_rows<<<4224, 256, 0, stream>>>(X, n1g, n1b, Bb16, ROWS);
    gemm_bf16<<<dim3(9, 132), 256, 0, stream>>>(Bb16, qkvw16, nullptr, nullptr, QKVg,
                                                ROWS, 1152, Cq, 4);
    attn_mfma<<<1728, 256, 0, stream>>>(QKVg, mask, Bb16);
    gemm_bf16<<<dim3(3, 132), 256, 0, stream>>>(Bb16, projw16, projb, X, nullptr,
                                                ROWS, Cq, Cq, 3);
    ln_rows<<<4224, 256, 0, stream>>>(X, n2g, n2b, Bb16, ROWS);
    gemm_bf16<<<dim3(12, 132), 256, 0, stream>>>(Bb16, fc1w16, fc1b, nullptr, hid16,
                                                 ROWS, 1536, Cq, 2);
    gemm_bf16<<<dim3(3, 132), 256, 0, stream>>>(hid16, fc2w16, fc2b, C1, nullptr,
                                                ROWS, Cq, 1536, 1);
    gemm_f32<<<dim3(1, 264), 256, 0, stream>>>(C1, addw, addb, D1, ROWS, 16, Cq, 2);
    adapter_up<<<25344, 256, 0, stream>>>(D1, aduw, adub, C1, X, gate, X, totX);
    // local branch
    ln_rows<<<4224, 256, 0, stream>>>(X, n3g, n3b, Bb16, ROWS);
    gemm_bf16<<<dim3(9, 132), 256, 0, stream>>>(Bb16, a1qkv16, nullptr, nullptr, QKVg,
                                                ROWS, 1152, Cq, 4);
    local_attn<<<4096, 256, 0, stream>>>(QKVg, idxp, aout16);
    gemm_bf16<<<dim3(3, 1024), 256, 0, stream>>>(aout16, a1pw16, a1pb, nullptr, proj16,
                                                 LROWS, Cq, Cq, 4);
    pool_k<<<4096, 128, 0, stream>>>(proj16, X, idxp, cidxp, bng, bnb, V);
    interp_k<<<2048, 128, 0, stream>>>(X, V, c1p, c2p, newx);
    gemm_f32<<<dim3(1, 256), 256, 0, stream>>>(newx, ad1dw, ad1db, D1, Bq*Gq, 16, Cq, 2);
    adapter_up<<<24576, 256, 0, stream>>>(D1, ad1uw, ad1ub, newx, nullptr, nullptr,
                                          (float*)d_out, (long)Bq*Gq*Cq);
}

// Round 6
// 1012.823 us; speedup vs baseline: 14.7226x; 1.0187x over previous
//
#include <hip/hip_runtime.h>
#include <hip/hip_bf16.h>

// ---------------- constants ----------------
#define Bq 32
#define Tq 16
#define Gq 512
#define NSEQ 528           // T + G
#define Cq 384
#define Hq 6
#define Sq 128
#define Kg 32              // GROUP_SIZE
#define ROWS (Bq*NSEQ)     // 16896
#define HPAD 68            // fp32 LDS row stride (16B-aligned rows)
#define LROWS (Bq*Sq*Kg)   // 131072 local tokens

typedef unsigned short u16;
typedef short bf16x8 __attribute__((ext_vector_type(8)));   // 8 bf16 in 4 VGPRs
typedef float f32x4  __attribute__((ext_vector_type(4)));

__device__ __forceinline__ float gelu_f(float x){
    return 0.5f * x * (1.0f + erff(x * 0.70710678118654752f));
}
__device__ __forceinline__ u16 f2b(float x){
    union { float f; unsigned u; } v; v.f = x;
    return (u16)((v.u + 0x7fffu + ((v.u >> 16) & 1u)) >> 16);
}
__device__ __forceinline__ float b2f(u16 h){
    union { float f; unsigned u; } v; v.u = ((unsigned)h) << 16; return v.f;
}

// ---------------- build X = concat(prompt, x) ----------------
__global__ void __launch_bounds__(256) build_x(const float* __restrict__ xin,
    const float* __restrict__ pe, float* __restrict__ X, long total)
{
    long gid = (long)blockIdx.x*256 + threadIdx.x;
    if (gid >= total) return;
    int  c   = (int)(gid % Cq);
    long row = gid / Cq;
    int  p   = (int)(row % NSEQ);
    long b   = row / NSEQ;
    float v = (p < Tq) ? pe[p*Cq + c] : xin[(b*Gq + (p - Tq))*Cq + c];
    X[gid] = v;
}

// ---------------- weight conversion fp32 -> bf16 (6 matrices) ----------------
__global__ void __launch_bounds__(256) conv6(const float* __restrict__ s0,
    const float* __restrict__ s1, const float* __restrict__ s2,
    const float* __restrict__ s3, const float* __restrict__ s4,
    const float* __restrict__ s5, u16* __restrict__ dst)
{
    long i = (long)blockIdx.x*256 + threadIdx.x;
    if (i >= 2359296) return;
    float v;
    if      (i <  442368) v = s0[i];
    else if (i <  589824) v = s1[i -  442368];
    else if (i < 1179648) v = s2[i -  589824];
    else if (i < 1769472) v = s3[i - 1179648];
    else if (i < 2211840) v = s4[i - 1769472];
    else                  v = s5[i - 2211840];
    dst[i] = f2b(v);
}

// ---------------- mask fp32 -> bf16 additive bias ----------------
__global__ void __launch_bounds__(256) conv_mask(const float* __restrict__ m,
    u16* __restrict__ bias16)
{
    long i = (long)blockIdx.x*256 + threadIdx.x;
    if (i >= (long)Bq*Gq*Gq) return;
    bias16[i] = f2b(-100000.0f * m[i]);
}

// ---------------- LayerNorm, one wave per row, bf16 out ----------------
__global__ void __launch_bounds__(256) ln_rows(const float* __restrict__ in,
    const float* __restrict__ gw, const float* __restrict__ bw,
    u16* __restrict__ out, int rows)
{
    int w = threadIdx.x >> 6, lane = threadIdx.x & 63;
    int row = blockIdx.x*4 + w;
    if (row >= rows) return;
    const float* xr = in + (long)row*Cq;
    float v[6]; float s = 0.f, s2 = 0.f;
#pragma unroll
    for (int j = 0; j < 6; j++){ float x = xr[lane + 64*j]; v[j] = x; s += x; s2 += x*x; }
#pragma unroll
    for (int m = 1; m < 64; m <<= 1){ s += __shfl_xor(s, m); s2 += __shfl_xor(s2, m); }
    float mean = s * (1.f/384.f);
    float var  = s2 * (1.f/384.f) - mean*mean;
    float rs   = rsqrtf(var + 1e-5f);
    u16* orow = out + (long)row*Cq;
#pragma unroll
    for (int j = 0; j < 6; j++){
        int c = lane + 64*j;
        orow[c] = f2b((v[j] - mean) * rs * gw[c] + bw[c]);
    }
}

// ---------------- bf16 MFMA GEMM: C = epi(A @ W^T) ----------------
// epi: 0 none->f32, 1 +bias->f32, 2 gelu(+bias)->bf16, 3 Cf += acc+bias (f32 RMW),
//      4 (+bias if given)->bf16
__global__ void __launch_bounds__(256) gemm_bf16(const u16* __restrict__ A,
    const u16* __restrict__ W, const float* __restrict__ bias,
    float* __restrict__ Cf, u16* __restrict__ Cb, int M, int N, int K, int epi)
{
    __shared__ u16 As[128*40];
    __shared__ u16 Ws[128*40];
    int t = threadIdx.x;
    int m0 = blockIdx.y*128, n0 = blockIdx.x*128;
    int wv = t >> 6, lane = t & 63;
    int wm = (wv >> 1)*64, wn = (wv & 1)*64;
    int fm = lane & 15;
    int fk = (lane >> 4) * 8;
    int sr = t >> 2;
    int sc8 = (t & 3) * 8;
    f32x4 acc[4][4];
#pragma unroll
    for (int i = 0; i < 4; i++)
#pragma unroll
        for (int j = 0; j < 4; j++) acc[i][j] = (f32x4){0.f,0.f,0.f,0.f};

    for (int k0 = 0; k0 < K; k0 += 32){
        *(uint4*)&As[sr*40 + sc8]      = *(const uint4*)(A + (long)(m0+sr)*K    + k0 + sc8);
        *(uint4*)&As[(sr+64)*40 + sc8] = *(const uint4*)(A + (long)(m0+sr+64)*K + k0 + sc8);
        *(uint4*)&Ws[sr*40 + sc8]      = *(const uint4*)(W + (long)(n0+sr)*K    + k0 + sc8);
        *(uint4*)&Ws[(sr+64)*40 + sc8] = *(const uint4*)(W + (long)(n0+sr+64)*K + k0 + sc8);
        __syncthreads();
        bf16x8 af[4], bf[4];
#pragma unroll
        for (int im = 0; im < 4; im++) af[im] = *(const bf16x8*)&As[(wm + im*16 + fm)*40 + fk];
#pragma unroll
        for (int in = 0; in < 4; in++) bf[in] = *(const bf16x8*)&Ws[(wn + in*16 + fm)*40 + fk];
#pragma unroll
        for (int im = 0; im < 4; im++)
#pragma unroll
            for (int in = 0; in < 4; in++)
                acc[im][in] = __builtin_amdgcn_mfma_f32_16x16x32_bf16(af[im], bf[in], acc[im][in], 0, 0, 0);
        __syncthreads();
    }
    int lr = lane >> 4, lc = lane & 15;
#pragma unroll
    for (int im = 0; im < 4; im++){
#pragma unroll
        for (int in = 0; in < 4; in++){
#pragma unroll
            for (int r = 0; r < 4; r++){
                int m = m0 + wm + im*16 + lr*4 + r;
                int n = n0 + wn + in*16 + lc;
                float v = acc[im][in][r];
                if (epi >= 1 && bias) v += bias[n];
                if (epi == 2) v = gelu_f(v);
                long off = (long)m*N + n;
                if (epi == 3) v += Cf[off];
                if (epi == 2 || epi == 4) Cb[off] = f2b(v);
                else                      Cf[off] = v;
            }
        }
    }
}

// ---------------- local proj GEMM with fused pool epilogue ----------------
// A: (131072,384) bf16 attn-out, W: (384,384) bf16, bias: proj_b.
// Per 128-row tile = 4 groups: val = acc + pb + X[idx]; pool max+mean over 32;
// vis = gelu(bn) + 0.4*X[cidx].
__global__ void __launch_bounds__(256) gemm_pool(const u16* __restrict__ A,
    const u16* __restrict__ W, const float* __restrict__ bias,
    const int* __restrict__ idx, const int* __restrict__ cidx,
    const float* __restrict__ Xf, const float* __restrict__ bng,
    const float* __restrict__ bnb, float* __restrict__ vis, int K)
{
    __shared__ u16 As[128*40];
    __shared__ u16 Ws[128*40];
    __shared__ int idxl[128];
    __shared__ int cidxl[4];
    int t = threadIdx.x;
    int m0 = blockIdx.y*128, n0 = blockIdx.x*128;
    if (t < 128) idxl[t] = idx[m0 + t];
    if (t < 4)   cidxl[t] = cidx[(m0 >> 5) + t];
    int wv = t >> 6, lane = t & 63;
    int wm = (wv >> 1)*64, wn = (wv & 1)*64;
    int fm = lane & 15;
    int fk = (lane >> 4) * 8;
    int sr = t >> 2;
    int sc8 = (t & 3) * 8;
    f32x4 acc[4][4];
#pragma unroll
    for (int i = 0; i < 4; i++)
#pragma unroll
        for (int j = 0; j < 4; j++) acc[i][j] = (f32x4){0.f,0.f,0.f,0.f};

    for (int k0 = 0; k0 < K; k0 += 32){
        *(uint4*)&As[sr*40 + sc8]      = *(const uint4*)(A + (long)(m0+sr)*K    + k0 + sc8);
        *(uint4*)&As[(sr+64)*40 + sc8] = *(const uint4*)(A + (long)(m0+sr+64)*K + k0 + sc8);
        *(uint4*)&Ws[sr*40 + sc8]      = *(const uint4*)(W + (long)(n0+sr)*K    + k0 + sc8);
        *(uint4*)&Ws[(sr+64)*40 + sc8] = *(const uint4*)(W + (long)(n0+sr+64)*K + k0 + sc8);
        __syncthreads();
        bf16x8 af[4], bf[4];
#pragma unroll
        for (int im = 0; im < 4; im++) af[im] = *(const bf16x8*)&As[(wm + im*16 + fm)*40 + fk];
#pragma unroll
        for (int in = 0; in < 4; in++) bf[in] = *(const bf16x8*)&Ws[(wn + in*16 + fm)*40 + fk];
#pragma unroll
        for (int im = 0; im < 4; im++)
#pragma unroll
            for (int in = 0; in < 4; in++)
                acc[im][in] = __builtin_amdgcn_mfma_f32_16x16x32_bf16(af[im], bf[in], acc[im][in], 0, 0, 0);
        __syncthreads();
    }
    int lr = lane >> 4, lc = lane & 15;
#pragma unroll
    for (int in = 0; in < 4; in++){
        int c = n0 + wn + in*16 + lc;
        float pb = bias[c];
        float bg = bng[c], bb = bnb[c];
#pragma unroll
        for (int gl = 0; gl < 2; gl++){
            float vmax = -3e38f, vsum = 0.f;
#pragma unroll
            for (int i2 = 0; i2 < 2; i2++){
                int im = gl*2 + i2;
#pragma unroll
                for (int r = 0; r < 4; r++){
                    int rl = wm + im*16 + lr*4 + r;
                    float val = acc[im][in][r] + pb + Xf[(long)idxl[rl]*Cq + c];
                    vmax = fmaxf(vmax, val); vsum += val;
                }
            }
            vmax = fmaxf(vmax, __shfl_xor(vmax, 16)); vsum += __shfl_xor(vsum, 16);
            vmax = fmaxf(vmax, __shfl_xor(vmax, 32)); vsum += __shfl_xor(vsum, 32);
            if (lane < 16){
                int glb = (wm >> 5) + gl;      // 0..3
                float lcv = vmax + vsum*(1.f/32.f);
                float u = gelu_f(lcv*bg*0.9999950000374997f + bb);
                vis[((long)(m0 >> 5) + glb)*Cq + c] = u + 0.4f*Xf[(long)cidxl[glb]*Cq + c];
            }
        }
    }
}

// ---------------- generic fp32 GEMM (small adapters only) ----------------
__global__ void __launch_bounds__(256) gemm_f32(const float* __restrict__ A,
    const float* __restrict__ W, const float* __restrict__ bias,
    float* __restrict__ C, int M, int N, int K, int epi)
{
    __shared__ float As[16][HPAD];
    __shared__ float Ws[16][HPAD];
    int tid = threadIdx.x;
    int m0 = blockIdx.y*64, n0 = blockIdx.x*64;
    int tm = tid >> 4, tn = tid & 15;
    int lr = tid >> 2;
    int lc4 = (tid & 3) * 4;
    float acc[4][4] = {};
    for (int k0 = 0; k0 < K; k0 += 16){
        {
            int m = m0 + lr;
            float4 v = make_float4(0.f,0.f,0.f,0.f);
            if (m < M) v = *(const float4*)(A + (long)m*K + k0 + lc4);
            As[lc4+0][lr] = v.x; As[lc4+1][lr] = v.y; As[lc4+2][lr] = v.z; As[lc4+3][lr] = v.w;
            int n = n0 + lr;
            float4 wv = make_float4(0.f,0.f,0.f,0.f);
            if (n < N) wv = *(const float4*)(W + (long)n*K + k0 + lc4);
            Ws[lc4+0][lr] = wv.x; Ws[lc4+1][lr] = wv.y; Ws[lc4+2][lr] = wv.z; Ws[lc4+3][lr] = wv.w;
        }
        __syncthreads();
#pragma unroll
        for (int kk = 0; kk < 16; kk++){
            float4 a4 = *(const float4*)&As[kk][4*tm];
            float4 b4 = *(const float4*)&Ws[kk][4*tn];
            float a[4] = {a4.x, a4.y, a4.z, a4.w};
            float bb[4] = {b4.x, b4.y, b4.z, b4.w};
#pragma unroll
            for (int i = 0; i < 4; i++)
#pragma unroll
                for (int j = 0; j < 4; j++) acc[i][j] += a[i]*bb[j];
        }
        __syncthreads();
    }
#pragma unroll
    for (int i = 0; i < 4; i++){
        int m = m0 + 4*tm + i; if (m >= M) continue;
#pragma unroll
        for (int j = 0; j < 4; j++){
            int n = n0 + 4*tn + j; if (n >= N) continue;
            float v = acc[i][j];
            if (epi >= 1 && bias) v += bias[n];
            if (epi == 2) v = gelu_f(v);
            long off = (long)m*N + n;
            if (epi == 3) v += C[off];
            C[off] = v;
        }
    }
}

// ---------------- flash-style MFMA global attention v2 ----------------
// 128-query blocks (2 q-subtiles/wave), bf16 mask bias, XCD swizzle (b%8).
// grid 960 = 8 xcd * 4 bhi * 6 h * 5 qt.
__global__ void __launch_bounds__(256) attn_mfma(const u16* __restrict__ QKVg,
    const u16* __restrict__ bias16, u16* __restrict__ out)
{
    __shared__ u16 Ks[32*72];
    __shared__ u16 Vt[64*40];
    __shared__ u16 Pb[4][2][16*40];
    int blk = blockIdx.x;
    int xcd = blk & 7; int r0 = blk >> 3;
    int bb = r0 & 3;  int rr = r0 >> 2;     // rr in [0,30)
    int h = rr % 6;   int qt = rr / 6;      // qt in [0,5)
    int b = xcd + 8*bb;
    int t = threadIdx.x; int w = t >> 6; int lane = t & 63;
    int fr  = lane & 15;
    int fko = (lane >> 4) * 8;
    int colj = lane & 15;
    int rgrp = (lane >> 4) * 4;

    int q0[2]; q0[0] = qt*128 + w*16; q0[1] = q0[0] + 64;
    bf16x8 aq0[2], aq1[2];
#pragma unroll
    for (int p = 0; p < 2; p++){
        int qr = q0[p] + fr; int qrc = qr < NSEQ ? qr : NSEQ-1;
        const u16* qb = QKVg + (long)(b*NSEQ + qrc)*1152 + h*64;
        aq0[p] = *(const bf16x8*)(qb + fko);
        aq1[p] = *(const bf16x8*)(qb + 32 + fko);
    }
    f32x4 oacc[2][4];
    float mrun[2][4], lrun[2][4];
#pragma unroll
    for (int p = 0; p < 2; p++){
#pragma unroll
        for (int d = 0; d < 4; d++) oacc[p][d] = (f32x4){0.f,0.f,0.f,0.f};
#pragma unroll
        for (int r = 0; r < 4; r++){ mrun[p][r] = -1e30f; lrun[p][r] = 0.f; }
    }
    int skey = t >> 3;
    int sd8  = (t & 7) * 8;

    for (int kc = 0; kc < 17; kc++){
        __syncthreads();
        {
            int j = kc*32 + skey;
            bf16x8 kv = {0,0,0,0,0,0,0,0};
            bf16x8 vv = {0,0,0,0,0,0,0,0};
            if (j < NSEQ){
                const u16* kb = QKVg + (long)(b*NSEQ + j)*1152 + 384 + h*64 + sd8;
                kv = *(const bf16x8*)kb;
                vv = *(const bf16x8*)(kb + 384);
            }
            *(bf16x8*)&Ks[skey*72 + sd8] = kv;
#pragma unroll
            for (int e = 0; e < 8; e++) Vt[(sd8+e)*40 + skey] = (u16)vv[e];
        }
        __syncthreads();
#pragma unroll
        for (int p = 0; p < 2; p++){
            f32x4 s[2];
#pragma unroll
            for (int sub = 0; sub < 2; sub++){
                bf16x8 bk0 = *(const bf16x8*)&Ks[(sub*16 + fr)*72 + fko];
                bf16x8 bk1 = *(const bf16x8*)&Ks[(sub*16 + fr)*72 + 32 + fko];
                f32x4 z = (f32x4){0.f,0.f,0.f,0.f};
                z = __builtin_amdgcn_mfma_f32_16x16x32_bf16(aq0[p], bk0, z, 0, 0, 0);
                z = __builtin_amdgcn_mfma_f32_16x16x32_bf16(aq1[p], bk1, z, 0, 0, 0);
                s[sub] = z;
            }
#pragma unroll
            for (int sub = 0; sub < 2; sub++){
#pragma unroll
                for (int r = 0; r < 4; r++){
                    int qi = q0[p] + rgrp + r;
                    int jj = kc*32 + sub*16 + colj;
                    float sv = s[sub][r] * 0.125f;
                    if (jj < Gq && qi < Gq)
                        sv += b2f(bias16[((long)b*Gq + qi)*Gq + jj]);
                    if (jj >= NSEQ) sv = -1e30f;
                    s[sub][r] = sv;
                }
            }
#pragma unroll
            for (int r = 0; r < 4; r++){
                float mx = fmaxf(s[0][r], s[1][r]);
#pragma unroll
                for (int mm = 1; mm < 16; mm <<= 1) mx = fmaxf(mx, __shfl_xor(mx, mm));
                float mnew = fmaxf(mrun[p][r], mx);
                float alpha = __expf(mrun[p][r] - mnew);
                mrun[p][r] = mnew;
                float e0 = __expf(s[0][r] - mnew);
                float e1 = __expf(s[1][r] - mnew);
                s[0][r] = e0; s[1][r] = e1;
                float ps = e0 + e1;
#pragma unroll
                for (int mm = 1; mm < 16; mm <<= 1) ps += __shfl_xor(ps, mm);
                lrun[p][r] = lrun[p][r]*alpha + ps;
#pragma unroll
                for (int d = 0; d < 4; d++) oacc[p][d][r] *= alpha;
            }
#pragma unroll
            for (int sub = 0; sub < 2; sub++)
#pragma unroll
                for (int r = 0; r < 4; r++)
                    Pb[w][p][(rgrp + r)*40 + sub*16 + colj] = f2b(s[sub][r]);
        }
        __syncthreads();
#pragma unroll
        for (int p = 0; p < 2; p++){
            bf16x8 ap = *(const bf16x8*)&Pb[w][p][fr*40 + fko];
#pragma unroll
            for (int d = 0; d < 4; d++){
                bf16x8 bv = *(const bf16x8*)&Vt[(d*16 + fr)*40 + fko];
                oacc[p][d] = __builtin_amdgcn_mfma_f32_16x16x32_bf16(ap, bv, oacc[p][d], 0, 0, 0);
            }
        }
    }
#pragma unroll
    for (int p = 0; p < 2; p++){
#pragma unroll
        for (int r = 0; r < 4; r++){
            int qi = q0[p] + rgrp + r;
            if (qi < NSEQ){
                float inv = 1.0f / lrun[p][r];
#pragma unroll
                for (int d = 0; d < 4; d++)
                    out[((long)(b*NSEQ + qi))*Cq + h*64 + d*16 + colj] = f2b(oacc[p][d][r]*inv);
            }
        }
    }
}

// ---------------- adapter up-projection + combine ----------------
__global__ void __launch_bounds__(256) adapter_up(const float* __restrict__ hid,
    const float* __restrict__ uw, const float* __restrict__ ub,
    const float* __restrict__ src, const float* __restrict__ res,
    const float* __restrict__ gatep, float* __restrict__ out, long total)
{
    long gid = (long)blockIdx.x*256 + threadIdx.x;
    if (gid >= total) return;
    long m = gid / Cq; int c = (int)(gid % Cq);
    const float* hr = hid + m*16;
    const float* ur = uw + c*16;
    float acc = 0.f;
#pragma unroll
    for (int r = 0; r < 16; r++) acc += hr[r]*ur[r];
    float gate = gatep ? gatep[0] : 1.0f;
    float v = gate * (acc + ub[c] + src[gid]);
    if (res) v += res[gid];
    out[gid] = v;
}

// ---------------- local branch: MFMA attention, 1 group / 256-thr block ------
__global__ void __launch_bounds__(256) local_attn(const u16* __restrict__ QKVg,
    const int* __restrict__ idx, u16* __restrict__ aout16)
{
    __shared__ u16 Qs[32*72];
    __shared__ u16 Ksm[32*72];
    __shared__ u16 Vt[64*40];
    __shared__ float sc[32*36];
    __shared__ u16 Pa[32*40];
    __shared__ float linv[32];
    __shared__ int rows[32];
    int g = blockIdx.x;
    int t = threadIdx.x;
    int w = t >> 6, lane = t & 63;
    if (t < 32) rows[t] = idx[g*Kg + t];
    __syncthreads();
    int srow = t & 31;
    int d8   = (t >> 5) * 8;
    int fr = lane & 15, fko = (lane >> 4)*8;
    int colj = lane & 15, rgrp = (lane >> 4)*4;
    int it = w >> 1, jt = w & 1;
    int smrow = w*8 + (lane >> 3);
    int smc   = (lane & 7) * 4;

    for (int h = 0; h < Hq; h++){
        {
            const u16* base = QKVg + (long)rows[srow]*1152 + h*64 + d8;
            bf16x8 qv = *(const bf16x8*)(base);
            bf16x8 kv = *(const bf16x8*)(base + 384);
            bf16x8 vv = *(const bf16x8*)(base + 768);
            *(bf16x8*)&Qs[srow*72 + d8]  = qv;
            *(bf16x8*)&Ksm[srow*72 + d8] = kv;
#pragma unroll
            for (int e = 0; e < 8; e++) Vt[(d8+e)*40 + srow] = (u16)vv[e];
        }
        __syncthreads();
        {
            bf16x8 a0 = *(const bf16x8*)&Qs[(it*16+fr)*72 + fko];
            bf16x8 a1 = *(const bf16x8*)&Qs[(it*16+fr)*72 + 32 + fko];
            bf16x8 b0 = *(const bf16x8*)&Ksm[(jt*16+fr)*72 + fko];
            bf16x8 b1 = *(const bf16x8*)&Ksm[(jt*16+fr)*72 + 32 + fko];
            f32x4 z = (f32x4){0.f,0.f,0.f,0.f};
            z = __builtin_amdgcn_mfma_f32_16x16x32_bf16(a0, b0, z, 0, 0, 0);
            z = __builtin_amdgcn_mfma_f32_16x16x32_bf16(a1, b1, z, 0, 0, 0);
#pragma unroll
            for (int r = 0; r < 4; r++)
                sc[(it*16 + rgrp + r)*36 + jt*16 + colj] = z[r]*0.125f;
        }
        __syncthreads();
        {
            float4 s4 = *(const float4*)&sc[smrow*36 + smc];
            float mx = fmaxf(fmaxf(s4.x, s4.y), fmaxf(s4.z, s4.w));
#pragma unroll
            for (int mm = 1; mm < 8; mm <<= 1) mx = fmaxf(mx, __shfl_xor(mx, mm));
            float p0 = __expf(s4.x - mx), p1 = __expf(s4.y - mx);
            float p2 = __expf(s4.z - mx), p3 = __expf(s4.w - mx);
            float sm = p0 + p1 + p2 + p3;
#pragma unroll
            for (int mm = 1; mm < 8; mm <<= 1) sm += __shfl_xor(sm, mm);
            if ((lane & 7) == 0) linv[smrow] = 1.0f / sm;
            Pa[smrow*40 + smc + 0] = f2b(p0);
            Pa[smrow*40 + smc + 1] = f2b(p1);
            Pa[smrow*40 + smc + 2] = f2b(p2);
            Pa[smrow*40 + smc + 3] = f2b(p3);
        }
        __syncthreads();
        {
            bf16x8 ap = *(const bf16x8*)&Pa[(it*16+fr)*40 + fko];
#pragma unroll
            for (int dd = 0; dd < 2; dd++){
                int dt = jt + dd*2;
                bf16x8 bv = *(const bf16x8*)&Vt[(dt*16+fr)*40 + fko];
                f32x4 o = (f32x4){0.f,0.f,0.f,0.f};
                o = __builtin_amdgcn_mfma_f32_16x16x32_bf16(ap, bv, o, 0, 0, 0);
#pragma unroll
                for (int r = 0; r < 4; r++){
                    int row = it*16 + rgrp + r;
                    aout16[((long)(g*32 + row))*Cq + h*64 + dt*16 + colj] =
                        f2b(o[r] * linv[row]);
                }
            }
        }
        __syncthreads();
    }
}

// ---------------- inverse-distance interp: 8 points/block share vis reads ----
__global__ void __launch_bounds__(128) interp_k(const float* __restrict__ Xf,
    const float* __restrict__ vis, const float* __restrict__ c1,
    const float* __restrict__ c2, float* __restrict__ newx)
{
    __shared__ float wsh[8*128];
    __shared__ float inv8[8];
    int blk = blockIdx.x;
    int b = blk >> 6, nt = blk & 63;
    int tid = threadIdx.x;
#pragma unroll
    for (int i = 0; i < 8; i++){
        int id = tid + i*128;
        int nl = id >> 7, s = id & 127;
        const float* p1 = c1 + ((long)b*Gq + nt*8 + nl)*3;
        const float* p2 = c2 + ((long)b*Sq + s)*3;
        float x1 = p1[0], y1 = p1[1], z1 = p1[2];
        float x2 = p2[0], y2 = p2[1], z2 = p2[2];
        float d = (x1*x1 + y1*y1 + z1*z1) + (x2*x2 + y2*y2 + z2*z2)
                - 2.f*(x1*x2 + y1*y2 + z1*z2);
        wsh[nl*128 + s] = 1.f/(d + 1e-8f);
    }
    __syncthreads();
    if (tid < 8){
        float sum = 0.f;
        for (int s = 0; s < Sq; s++) sum += wsh[tid*128 + s];
        inv8[tid] = 1.f/sum;
    }
    __syncthreads();
    float acc[8][3];
#pragma unroll
    for (int n = 0; n < 8; n++){ acc[n][0] = 0.f; acc[n][1] = 0.f; acc[n][2] = 0.f; }
    const float* vb = vis + (long)b*Sq*Cq + tid;
    for (int s = 0; s < Sq; s++){
        float v0 = vb[s*Cq], v1 = vb[s*Cq + 128], v2 = vb[s*Cq + 256];
#pragma unroll
        for (int n = 0; n < 8; n++){
            float wq = wsh[n*128 + s];
            acc[n][0] += wq*v0; acc[n][1] += wq*v1; acc[n][2] += wq*v2;
        }
    }
#pragma unroll
    for (int n = 0; n < 8; n++){
        int gn = nt*8 + n;
        const float* xr = Xf + ((long)(b*NSEQ + Tq + gn))*Cq;
        float* orow = newx + ((long)(b*Gq + gn))*Cq;
        float sf = 0.4f * inv8[n];
        orow[tid]       = xr[tid]       + sf*acc[n][0];
        orow[tid + 128] = xr[tid + 128] + sf*acc[n][1];
        orow[tid + 256] = xr[tid + 256] + sf*acc[n][2];
    }
}

// ---------------- launch ----------------
extern "C" void kernel_launch(void* const* d_in, const int* in_sizes, int n_in,
                              void* d_out, int out_size, void* d_ws, size_t ws_size,
                              hipStream_t stream)
{
    const float* x_in  = (const float*)d_in[0];
    const float* mask  = (const float*)d_in[1];
    const float* c1p   = (const float*)d_in[2];
    const float* c2p   = (const float*)d_in[3];
    const float* pe    = (const float*)d_in[5];
    const float* n1g   = (const float*)d_in[6];
    const float* n1b   = (const float*)d_in[7];
    const float* qkvw  = (const float*)d_in[8];
    const float* projw = (const float*)d_in[9];
    const float* projb = (const float*)d_in[10];
    const float* n2g   = (const float*)d_in[11];
    const float* n2b   = (const float*)d_in[12];
    const float* fc1w  = (const float*)d_in[13];
    const float* fc1b  = (const float*)d_in[14];
    const float* fc2w  = (const float*)d_in[15];
    const float* fc2b  = (const float*)d_in[16];
    const float* gate  = (const float*)d_in[17];
    const float* addw  = (const float*)d_in[18];
    const float* addb  = (const float*)d_in[19];
    const float* aduw  = (const float*)d_in[20];
    const float* adub  = (const float*)d_in[21];
    const float* ad1dw = (const float*)d_in[22];
    const float* ad1db = (const float*)d_in[23];
    const float* ad1uw = (const float*)d_in[24];
    const float* ad1ub = (const float*)d_in[25];
    const float* bng   = (const float*)d_in[26];
    const float* bnb   = (const float*)d_in[27];
    const float* a1qkvw= (const float*)d_in[28];
    const float* a1pw  = (const float*)d_in[29];
    const float* a1pb  = (const float*)d_in[30];
    const float* n3g   = (const float*)d_in[31];
    const float* n3b   = (const float*)d_in[32];
    const int*   idxp  = (const int*)d_in[33];
    const int*   cidxp = (const int*)d_in[34];

    // ---- workspace layout (bytes), total 252.4 MB ----
    char* w = (char*)d_ws;
    float* X    = (float*)w;                       // 16896x384 f32   [0, 25952256)
    u16*   WB   = (u16*)(w + 25952256);            // bf16 weights
    u16*   Bb16 = (u16*)(w + 30670848);            // 16896x384 bf16
    char*  R1   = w + 43646976;                    // 100663296 B (bias16 / hid16 / aout16)
    char*  R2   = R1 + 100663296;                  // 100663296 B (QKVg / C1 / newx)
    float* D1   = (float*)(R2 + 100663296);        // 16896x16 f32
    float* V    = D1 + ROWS*16;                    // 4096x384 f32

    u16* qkvw16  = WB;
    u16* projw16 = WB +  442368;
    u16* fc1w16  = WB +  589824;
    u16* fc2w16  = WB + 1179648;
    u16* a1qkv16 = WB + 1769472;
    u16* a1pw16  = WB + 2211840;

    u16*   bias16 = (u16*)R1;       // 32x512x512 bf16 (16.8 MB; dead before fc1)
    u16*   hid16  = (u16*)R1;       // 16896x1536 bf16 (MLP phase)
    u16*   aout16 = (u16*)R1;       // 131072x384 bf16 (local phase)
    u16*   QKVg   = (u16*)R2;       // 16896x1152 bf16 (global then local)
    float* C1     = (float*)R2;     // 16896x384 f32 x_fn (MLP/adapter phase)
    float* newx   = (float*)R2;     // 16384x384 f32 (interp out)

    long totX = (long)ROWS*Cq;

    conv6<<<9216, 256, 0, stream>>>(qkvw, projw, fc1w, fc2w, a1qkvw, a1pw, WB);
    conv_mask<<<32768, 256, 0, stream>>>(mask, bias16);
    build_x<<<25344, 256, 0, stream>>>(x_in, pe, X, totX);
    ln_rows<<<4224, 256, 0, stream>>>(X, n1g, n1b, Bb16, ROWS);
    gemm_bf16<<<dim3(9, 132), 256, 0, stream>>>(Bb16, qkvw16, nullptr, nullptr, QKVg,
                                                ROWS, 1152, Cq, 4);
    attn_mfma<<<960, 256, 0, stream>>>(QKVg, bias16, Bb16);
    gemm_bf16<<<dim3(3, 132), 256, 0, stream>>>(Bb16, projw16, projb, X, nullptr,
                                                ROWS, Cq, Cq, 3);
    ln_rows<<<4224, 256, 0, stream>>>(X, n2g, n2b, Bb16, ROWS);
    gemm_bf16<<<dim3(12, 132), 256, 0, stream>>>(Bb16, fc1w16, fc1b, nullptr, hid16,
                                                 ROWS, 1536, Cq, 2);
    gemm_bf16<<<dim3(3, 132), 256, 0, stream>>>(hid16, fc2w16, fc2b, C1, nullptr,
                                                ROWS, Cq, 1536, 1);
    gemm_f32<<<dim3(1, 264), 256, 0, stream>>>(C1, addw, addb, D1, ROWS, 16, Cq, 2);
    adapter_up<<<25344, 256, 0, stream>>>(D1, aduw, adub, C1, X, gate, X, totX);
    // local branch
    ln_rows<<<4224, 256, 0, stream>>>(X, n3g, n3b, Bb16, ROWS);
    gemm_bf16<<<dim3(9, 132), 256, 0, stream>>>(Bb16, a1qkv16, nullptr, nullptr, QKVg,
                                                ROWS, 1152, Cq, 4);
    local_attn<<<4096, 256, 0, stream>>>(QKVg, idxp, aout16);
    gemm_pool<<<dim3(3, 1024), 256, 0, stream>>>(aout16, a1pw16, a1pb, idxp, cidxp,
                                                 X, bng, bnb, V, Cq);
    interp_k<<<2048, 128, 0, stream>>>(X, V, c1p, c2p, newx);
    gemm_f32<<<dim3(1, 256), 256, 0, stream>>>(newx, ad1dw, ad1db, D1, Bq*Gq, 16, Cq, 2);
    adapter_up<<<24576, 256, 0, stream>>>(D1, ad1uw, ad1ub, newx, nullptr, nullptr,
                                          (float*)d_out, (long)Bq*Gq*Cq);
}

// Round 7
// 902.290 us; speedup vs baseline: 16.5261x; 1.1225x over previous
//
#include <hip/hip_runtime.h>
#include <hip/hip_bf16.h>

// ---------------- constants ----------------
#define Bq 32
#define Tq 16
#define Gq 512
#define NSEQ 528           // T + G
#define Cq 384
#define Hq 6
#define Sq 128
#define Kg 32              // GROUP_SIZE
#define ROWS (Bq*NSEQ)     // 16896
#define LROWS (Bq*Sq*Kg)   // 131072 local tokens

typedef unsigned short u16;
typedef short bf16x8 __attribute__((ext_vector_type(8)));   // 8 bf16 in 4 VGPRs
typedef float f32x4  __attribute__((ext_vector_type(4)));

__device__ __forceinline__ float gelu_f(float x){
    return 0.5f * x * (1.0f + erff(x * 0.70710678118654752f));
}
__device__ __forceinline__ u16 f2b(float x){
    union { float f; unsigned u; } v; v.f = x;
    return (u16)((v.u + 0x7fffu + ((v.u >> 16) & 1u)) >> 16);
}
__device__ __forceinline__ float b2f(u16 h){
    union { float f; unsigned u; } v; v.u = ((unsigned)h) << 16; return v.f;
}

// ---------------- build X = concat(prompt, x) ----------------
__global__ void __launch_bounds__(256) build_x(const float* __restrict__ xin,
    const float* __restrict__ pe, float* __restrict__ X, long total)
{
    long gid = (long)blockIdx.x*256 + threadIdx.x;
    if (gid >= total) return;
    int  c   = (int)(gid % Cq);
    long row = gid / Cq;
    int  p   = (int)(row % NSEQ);
    long b   = row / NSEQ;
    float v = (p < Tq) ? pe[p*Cq + c] : xin[(b*Gq + (p - Tq))*Cq + c];
    X[gid] = v;
}

// ---------------- weight conversion fp32 -> bf16 (6 matrices) ----------------
__global__ void __launch_bounds__(256) conv6(const float* __restrict__ s0,
    const float* __restrict__ s1, const float* __restrict__ s2,
    const float* __restrict__ s3, const float* __restrict__ s4,
    const float* __restrict__ s5, u16* __restrict__ dst)
{
    long i = (long)blockIdx.x*256 + threadIdx.x;
    if (i >= 2359296) return;
    float v;
    if      (i <  442368) v = s0[i];
    else if (i <  589824) v = s1[i -  442368];
    else if (i < 1179648) v = s2[i -  589824];
    else if (i < 1769472) v = s3[i - 1179648];
    else if (i < 2211840) v = s4[i - 1769472];
    else                  v = s5[i - 2211840];
    dst[i] = f2b(v);
}

// ---------------- mask fp32 -> bf16 additive bias ----------------
__global__ void __launch_bounds__(256) conv_mask(const float* __restrict__ m,
    u16* __restrict__ bias16)
{
    long i = (long)blockIdx.x*256 + threadIdx.x;
    if (i >= (long)Bq*Gq*Gq) return;
    bias16[i] = f2b(-100000.0f * m[i]);
}

// ---------------- LayerNorm, one wave per row, bf16 out ----------------
__global__ void __launch_bounds__(256) ln_rows(const float* __restrict__ in,
    const float* __restrict__ gw, const float* __restrict__ bw,
    u16* __restrict__ out, int rows)
{
    int w = threadIdx.x >> 6, lane = threadIdx.x & 63;
    int row = blockIdx.x*4 + w;
    if (row >= rows) return;
    const float* xr = in + (long)row*Cq;
    float v[6]; float s = 0.f, s2 = 0.f;
#pragma unroll
    for (int j = 0; j < 6; j++){ float x = xr[lane + 64*j]; v[j] = x; s += x; s2 += x*x; }
#pragma unroll
    for (int m = 1; m < 64; m <<= 1){ s += __shfl_xor(s, m); s2 += __shfl_xor(s2, m); }
    float mean = s * (1.f/384.f);
    float var  = s2 * (1.f/384.f) - mean*mean;
    float rs   = rsqrtf(var + 1e-5f);
    u16* orow = out + (long)row*Cq;
#pragma unroll
    for (int j = 0; j < 6; j++){
        int c = lane + 64*j;
        orow[c] = f2b((v[j] - mean) * rs * gw[c] + bw[c]);
    }
}

// ---------------- bf16 MFMA GEMM: C = epi(A @ W^T) ----------------
// epi: 0 none->f32, 1 +bias->f32, 2 gelu(+bias)->bf16, 3 Cf += acc+bias (f32 RMW),
//      4 (+bias if given)->bf16
__global__ void __launch_bounds__(256) gemm_bf16(const u16* __restrict__ A,
    const u16* __restrict__ W, const float* __restrict__ bias,
    float* __restrict__ Cf, u16* __restrict__ Cb, int M, int N, int K, int epi)
{
    __shared__ u16 As[128*40];
    __shared__ u16 Ws[128*40];
    int t = threadIdx.x;
    int m0 = blockIdx.y*128, n0 = blockIdx.x*128;
    int wv = t >> 6, lane = t & 63;
    int wm = (wv >> 1)*64, wn = (wv & 1)*64;
    int fm = lane & 15;
    int fk = (lane >> 4) * 8;
    int sr = t >> 2;
    int sc8 = (t & 3) * 8;
    f32x4 acc[4][4];
#pragma unroll
    for (int i = 0; i < 4; i++)
#pragma unroll
        for (int j = 0; j < 4; j++) acc[i][j] = (f32x4){0.f,0.f,0.f,0.f};

    for (int k0 = 0; k0 < K; k0 += 32){
        *(uint4*)&As[sr*40 + sc8]      = *(const uint4*)(A + (long)(m0+sr)*K    + k0 + sc8);
        *(uint4*)&As[(sr+64)*40 + sc8] = *(const uint4*)(A + (long)(m0+sr+64)*K + k0 + sc8);
        *(uint4*)&Ws[sr*40 + sc8]      = *(const uint4*)(W + (long)(n0+sr)*K    + k0 + sc8);
        *(uint4*)&Ws[(sr+64)*40 + sc8] = *(const uint4*)(W + (long)(n0+sr+64)*K + k0 + sc8);
        __syncthreads();
        bf16x8 af[4], bf[4];
#pragma unroll
        for (int im = 0; im < 4; im++) af[im] = *(const bf16x8*)&As[(wm + im*16 + fm)*40 + fk];
#pragma unroll
        for (int in = 0; in < 4; in++) bf[in] = *(const bf16x8*)&Ws[(wn + in*16 + fm)*40 + fk];
#pragma unroll
        for (int im = 0; im < 4; im++)
#pragma unroll
            for (int in = 0; in < 4; in++)
                acc[im][in] = __builtin_amdgcn_mfma_f32_16x16x32_bf16(af[im], bf[in], acc[im][in], 0, 0, 0);
        __syncthreads();
    }
    int lr = lane >> 4, lc = lane & 15;
#pragma unroll
    for (int im = 0; im < 4; im++){
#pragma unroll
        for (int in = 0; in < 4; in++){
#pragma unroll
            for (int r = 0; r < 4; r++){
                int m = m0 + wm + im*16 + lr*4 + r;
                int n = n0 + wn + in*16 + lc;
                float v = acc[im][in][r];
                if (epi >= 1 && bias) v += bias[n];
                if (epi == 2) v = gelu_f(v);
                long off = (long)m*N + n;
                if (epi == 3) v += Cf[off];
                if (epi == 2 || epi == 4) Cb[off] = f2b(v);
                else                      Cf[off] = v;
            }
        }
    }
}

// ---------------- local proj GEMM with fused pool epilogue ----------------
__global__ void __launch_bounds__(256) gemm_pool(const u16* __restrict__ A,
    const u16* __restrict__ W, const float* __restrict__ bias,
    const int* __restrict__ idx, const int* __restrict__ cidx,
    const float* __restrict__ Xf, const float* __restrict__ bng,
    const float* __restrict__ bnb, float* __restrict__ vis, int K)
{
    __shared__ u16 As[128*40];
    __shared__ u16 Ws[128*40];
    __shared__ int idxl[128];
    __shared__ int cidxl[4];
    int t = threadIdx.x;
    int m0 = blockIdx.y*128, n0 = blockIdx.x*128;
    if (t < 128) idxl[t] = idx[m0 + t];
    if (t < 4)   cidxl[t] = cidx[(m0 >> 5) + t];
    int wv = t >> 6, lane = t & 63;
    int wm = (wv >> 1)*64, wn = (wv & 1)*64;
    int fm = lane & 15;
    int fk = (lane >> 4) * 8;
    int sr = t >> 2;
    int sc8 = (t & 3) * 8;
    f32x4 acc[4][4];
#pragma unroll
    for (int i = 0; i < 4; i++)
#pragma unroll
        for (int j = 0; j < 4; j++) acc[i][j] = (f32x4){0.f,0.f,0.f,0.f};

    for (int k0 = 0; k0 < K; k0 += 32){
        *(uint4*)&As[sr*40 + sc8]      = *(const uint4*)(A + (long)(m0+sr)*K    + k0 + sc8);
        *(uint4*)&As[(sr+64)*40 + sc8] = *(const uint4*)(A + (long)(m0+sr+64)*K + k0 + sc8);
        *(uint4*)&Ws[sr*40 + sc8]      = *(const uint4*)(W + (long)(n0+sr)*K    + k0 + sc8);
        *(uint4*)&Ws[(sr+64)*40 + sc8] = *(const uint4*)(W + (long)(n0+sr+64)*K + k0 + sc8);
        __syncthreads();
        bf16x8 af[4], bf[4];
#pragma unroll
        for (int im = 0; im < 4; im++) af[im] = *(const bf16x8*)&As[(wm + im*16 + fm)*40 + fk];
#pragma unroll
        for (int in = 0; in < 4; in++) bf[in] = *(const bf16x8*)&Ws[(wn + in*16 + fm)*40 + fk];
#pragma unroll
        for (int im = 0; im < 4; im++)
#pragma unroll
            for (int in = 0; in < 4; in++)
                acc[im][in] = __builtin_amdgcn_mfma_f32_16x16x32_bf16(af[im], bf[in], acc[im][in], 0, 0, 0);
        __syncthreads();
    }
    int lr = lane >> 4, lc = lane & 15;
#pragma unroll
    for (int in = 0; in < 4; in++){
        int c = n0 + wn + in*16 + lc;
        float pb = bias[c];
        float bg = bng[c], bb = bnb[c];
#pragma unroll
        for (int gl = 0; gl < 2; gl++){
            float vmax = -3e38f, vsum = 0.f;
#pragma unroll
            for (int i2 = 0; i2 < 2; i2++){
                int im = gl*2 + i2;
#pragma unroll
                for (int r = 0; r < 4; r++){
                    int rl = wm + im*16 + lr*4 + r;
                    float val = acc[im][in][r] + pb + Xf[(long)idxl[rl]*Cq + c];
                    vmax = fmaxf(vmax, val); vsum += val;
                }
            }
            vmax = fmaxf(vmax, __shfl_xor(vmax, 16)); vsum += __shfl_xor(vsum, 16);
            vmax = fmaxf(vmax, __shfl_xor(vmax, 32)); vsum += __shfl_xor(vsum, 32);
            if (lane < 16){
                int glb = (wm >> 5) + gl;
                float lcv = vmax + vsum*(1.f/32.f);
                float u = gelu_f(lcv*bg*0.9999950000374997f + bb);
                vis[((long)(m0 >> 5) + glb)*Cq + c] = u + 0.4f*Xf[(long)cidxl[glb]*Cq + c];
            }
        }
    }
}

// ---------------- flash-style MFMA global attention v3 ----------------
// 64-q blocks, grid 1728 = 8 xcd * 4 bb * 54 (h*qt); LDS-staged bf16 mask bias;
// unnormalized exp (scores are O(1); masked = -1e5 -> exp==0), single deferred
// l-reduction after the k-loop.
__global__ void __launch_bounds__(256) attn_mfma(const u16* __restrict__ QKVg,
    const u16* __restrict__ bias16, u16* __restrict__ out)
{
    __shared__ u16 Ks[32*72];
    __shared__ u16 Vt[64*40];
    __shared__ u16 Bs[64*36];
    __shared__ u16 Pb[4][16*40];
    int blk = blockIdx.x;
    int xcd = blk & 7; int r0 = blk >> 3;
    int bb = r0 & 3;  int rr = r0 >> 2;     // 0..53
    int h = rr % 6;   int qt = rr / 6;      // 0..8
    int b = xcd + 8*bb;
    int t = threadIdx.x; int w = t >> 6; int lane = t & 63;
    int fr  = lane & 15;
    int fko = (lane >> 4) * 8;
    int colj = lane & 15;
    int rgrp = (lane >> 4) * 4;
    int qb0 = qt*64;
    int q0 = qb0 + w*16;

    int qr = q0 + fr; int qrc = qr < NSEQ ? qr : NSEQ-1;
    const u16* qbase = QKVg + (long)(b*NSEQ + qrc)*1152 + h*64;
    bf16x8 aq0 = *(const bf16x8*)(qbase + fko);
    bf16x8 aq1 = *(const bf16x8*)(qbase + 32 + fko);

    f32x4 oacc[4];
#pragma unroll
    for (int d = 0; d < 4; d++) oacc[d] = (f32x4){0.f,0.f,0.f,0.f};
    float lsum[4] = {0.f, 0.f, 0.f, 0.f};

    int skey = t >> 3;
    int sd8  = (t & 7) * 8;
    int brow = t >> 2;             // bias staging row 0..63
    int bc8  = (t & 3) * 8;        // bias staging col

    for (int kc = 0; kc < 17; kc++){
        __syncthreads();
        {
            int j = kc*32 + skey;
            bf16x8 kv = {0,0,0,0,0,0,0,0};
            bf16x8 vv = {0,0,0,0,0,0,0,0};
            if (j < NSEQ){
                const u16* kb = QKVg + (long)(b*NSEQ + j)*1152 + 384 + h*64 + sd8;
                kv = *(const bf16x8*)kb;
                vv = *(const bf16x8*)(kb + 384);
            }
            *(bf16x8*)&Ks[skey*72 + sd8] = kv;
#pragma unroll
            for (int e = 0; e < 8; e++) Vt[(sd8+e)*40 + skey] = (u16)vv[e];
        }
        {
            int qi = qb0 + brow;
            int jj = kc*32 + bc8;
            uint4 bz = make_uint4(0u,0u,0u,0u);
            if (qi < Gq && jj < Gq)
                bz = *(const uint4*)(bias16 + ((long)b*Gq + qi)*Gq + jj);
            *(uint4*)&Bs[brow*36 + bc8] = bz;
        }
        __syncthreads();
        f32x4 s[2];
#pragma unroll
        for (int sub = 0; sub < 2; sub++){
            bf16x8 bk0 = *(const bf16x8*)&Ks[(sub*16 + fr)*72 + fko];
            bf16x8 bk1 = *(const bf16x8*)&Ks[(sub*16 + fr)*72 + 32 + fko];
            f32x4 z = (f32x4){0.f,0.f,0.f,0.f};
            z = __builtin_amdgcn_mfma_f32_16x16x32_bf16(aq0, bk0, z, 0, 0, 0);
            z = __builtin_amdgcn_mfma_f32_16x16x32_bf16(aq1, bk1, z, 0, 0, 0);
            s[sub] = z;
        }
#pragma unroll
        for (int sub = 0; sub < 2; sub++){
#pragma unroll
            for (int r = 0; r < 4; r++){
                int jj = kc*32 + sub*16 + colj;
                float sv = s[sub][r] * 0.125f
                         + b2f(Bs[(w*16 + rgrp + r)*36 + sub*16 + colj]);
                if (jj >= NSEQ) sv = -1e30f;
                float e = __expf(sv);
                lsum[r] += e;
                Pb[w][(rgrp + r)*40 + sub*16 + colj] = f2b(e);
            }
        }
        __syncthreads();
        bf16x8 ap = *(const bf16x8*)&Pb[w][fr*40 + fko];
#pragma unroll
        for (int d = 0; d < 4; d++){
            bf16x8 bv = *(const bf16x8*)&Vt[(d*16 + fr)*40 + fko];
            oacc[d] = __builtin_amdgcn_mfma_f32_16x16x32_bf16(ap, bv, oacc[d], 0, 0, 0);
        }
    }
#pragma unroll
    for (int r = 0; r < 4; r++){
#pragma unroll
        for (int mm = 1; mm < 16; mm <<= 1) lsum[r] += __shfl_xor(lsum[r], mm);
    }
#pragma unroll
    for (int r = 0; r < 4; r++){
        int qi = q0 + rgrp + r;
        if (qi < NSEQ){
            float inv = 1.0f / lsum[r];
#pragma unroll
            for (int d = 0; d < 4; d++)
                out[((long)(b*NSEQ + qi))*Cq + h*64 + d*16 + colj] = f2b(oacc[d][r]*inv);
        }
    }
}

// ---------------- fused adapter (one wave per row) ----------------
// v_ad = gelu(xfn @ dw^T + db) @ uw^T + ub + xfn
// v    = gate * v_ad + resid(optional)
// write Xout=v; if lng: LN(v) -> ln16 (bf16)
__global__ void __launch_bounds__(256) adapter_fused(const float* __restrict__ xfn,
    const float* __restrict__ resid,
    const float* __restrict__ dw, const float* __restrict__ db,
    const float* __restrict__ uw, const float* __restrict__ ub,
    const float* __restrict__ gatep,
    const float* __restrict__ lng, const float* __restrict__ lnb,
    float* __restrict__ Xout, u16* __restrict__ ln16, int rows)
{
    int w = threadIdx.x >> 6, lane = threadIdx.x & 63;
    int row = blockIdx.x*4 + w;
    if (row >= rows) return;
    const float* xr = xfn + (long)row*Cq;
    float xv[6];
#pragma unroll
    for (int j = 0; j < 6; j++) xv[j] = xr[lane + 64*j];
    float hid[16];
#pragma unroll
    for (int r = 0; r < 16; r++){
        const float* dr = dw + r*Cq;
        float p = 0.f;
#pragma unroll
        for (int j = 0; j < 6; j++) p += xv[j]*dr[lane + 64*j];
#pragma unroll
        for (int mm = 1; mm < 64; mm <<= 1) p += __shfl_xor(p, mm);
        hid[r] = gelu_f(p + db[r]);
    }
    float gate = gatep ? gatep[0] : 1.0f;
    float ov[6];
    float s = 0.f, s2 = 0.f;
#pragma unroll
    for (int j = 0; j < 6; j++){
        int c = lane + 64*j;
        const float* uc = uw + c*16;
        float a = 0.f;
#pragma unroll
        for (int r = 0; r < 16; r++) a += hid[r]*uc[r];
        float v = gate * (a + ub[c] + xv[j]);
        if (resid) v += resid[(long)row*Cq + c];
        ov[j] = v;
        Xout[(long)row*Cq + c] = v;
        s += v; s2 += v*v;
    }
    if (lng){
#pragma unroll
        for (int m = 1; m < 64; m <<= 1){ s += __shfl_xor(s, m); s2 += __shfl_xor(s2, m); }
        float mean = s * (1.f/384.f);
        float var  = s2 * (1.f/384.f) - mean*mean;
        float rs   = rsqrtf(var + 1e-5f);
        u16* orow = ln16 + (long)row*Cq;
#pragma unroll
        for (int j = 0; j < 6; j++){
            int c = lane + 64*j;
            orow[c] = f2b((ov[j] - mean)*rs*lng[c] + lnb[c]);
        }
    }
}

// ---------------- local branch: MFMA attention, 1 group / 256-thr block ------
__global__ void __launch_bounds__(256) local_attn(const u16* __restrict__ QKVg,
    const int* __restrict__ idx, u16* __restrict__ aout16)
{
    __shared__ u16 Qs[32*72];
    __shared__ u16 Ksm[32*72];
    __shared__ u16 Vt[64*40];
    __shared__ float sc[32*36];
    __shared__ u16 Pa[32*40];
    __shared__ float linv[32];
    __shared__ int rows[32];
    int g = blockIdx.x;
    int t = threadIdx.x;
    int w = t >> 6, lane = t & 63;
    if (t < 32) rows[t] = idx[g*Kg + t];
    __syncthreads();
    int srow = t & 31;
    int d8   = (t >> 5) * 8;
    int fr = lane & 15, fko = (lane >> 4)*8;
    int colj = lane & 15, rgrp = (lane >> 4)*4;
    int it = w >> 1, jt = w & 1;
    int smrow = w*8 + (lane >> 3);
    int smc   = (lane & 7) * 4;

    for (int h = 0; h < Hq; h++){
        {
            const u16* base = QKVg + (long)rows[srow]*1152 + h*64 + d8;
            bf16x8 qv = *(const bf16x8*)(base);
            bf16x8 kv = *(const bf16x8*)(base + 384);
            bf16x8 vv = *(const bf16x8*)(base + 768);
            *(bf16x8*)&Qs[srow*72 + d8]  = qv;
            *(bf16x8*)&Ksm[srow*72 + d8] = kv;
#pragma unroll
            for (int e = 0; e < 8; e++) Vt[(d8+e)*40 + srow] = (u16)vv[e];
        }
        __syncthreads();
        {
            bf16x8 a0 = *(const bf16x8*)&Qs[(it*16+fr)*72 + fko];
            bf16x8 a1 = *(const bf16x8*)&Qs[(it*16+fr)*72 + 32 + fko];
            bf16x8 b0 = *(const bf16x8*)&Ksm[(jt*16+fr)*72 + fko];
            bf16x8 b1 = *(const bf16x8*)&Ksm[(jt*16+fr)*72 + 32 + fko];
            f32x4 z = (f32x4){0.f,0.f,0.f,0.f};
            z = __builtin_amdgcn_mfma_f32_16x16x32_bf16(a0, b0, z, 0, 0, 0);
            z = __builtin_amdgcn_mfma_f32_16x16x32_bf16(a1, b1, z, 0, 0, 0);
#pragma unroll
            for (int r = 0; r < 4; r++)
                sc[(it*16 + rgrp + r)*36 + jt*16 + colj] = z[r]*0.125f;
        }
        __syncthreads();
        {
            float4 s4 = *(const float4*)&sc[smrow*36 + smc];
            float mx = fmaxf(fmaxf(s4.x, s4.y), fmaxf(s4.z, s4.w));
#pragma unroll
            for (int mm = 1; mm < 8; mm <<= 1) mx = fmaxf(mx, __shfl_xor(mx, mm));
            float p0 = __expf(s4.x - mx), p1 = __expf(s4.y - mx);
            float p2 = __expf(s4.z - mx), p3 = __expf(s4.w - mx);
            float sm = p0 + p1 + p2 + p3;
#pragma unroll
            for (int mm = 1; mm < 8; mm <<= 1) sm += __shfl_xor(sm, mm);
            if ((lane & 7) == 0) linv[smrow] = 1.0f / sm;
            Pa[smrow*40 + smc + 0] = f2b(p0);
            Pa[smrow*40 + smc + 1] = f2b(p1);
            Pa[smrow*40 + smc + 2] = f2b(p2);
            Pa[smrow*40 + smc + 3] = f2b(p3);
        }
        __syncthreads();
        {
            bf16x8 ap = *(const bf16x8*)&Pa[(it*16+fr)*40 + fko];
#pragma unroll
            for (int dd = 0; dd < 2; dd++){
                int dt = jt + dd*2;
                bf16x8 bv = *(const bf16x8*)&Vt[(dt*16+fr)*40 + fko];
                f32x4 o = (f32x4){0.f,0.f,0.f,0.f};
                o = __builtin_amdgcn_mfma_f32_16x16x32_bf16(ap, bv, o, 0, 0, 0);
#pragma unroll
                for (int r = 0; r < 4; r++){
                    int row = it*16 + rgrp + r;
                    aout16[((long)(g*32 + row))*Cq + h*64 + dt*16 + colj] =
                        f2b(o[r] * linv[row]);
                }
            }
        }
        __syncthreads();
    }
}

// ---------------- inverse-distance interp: 8 points/block share vis reads ----
__global__ void __launch_bounds__(128) interp_k(const float* __restrict__ Xf,
    const float* __restrict__ vis, const float* __restrict__ c1,
    const float* __restrict__ c2, float* __restrict__ newx)
{
    __shared__ float wsh[8*128];
    __shared__ float inv8[8];
    int blk = blockIdx.x;
    int b = blk >> 6, nt = blk & 63;
    int tid = threadIdx.x;
#pragma unroll
    for (int i = 0; i < 8; i++){
        int id = tid + i*128;
        int nl = id >> 7, s = id & 127;
        const float* p1 = c1 + ((long)b*Gq + nt*8 + nl)*3;
        const float* p2 = c2 + ((long)b*Sq + s)*3;
        float x1 = p1[0], y1 = p1[1], z1 = p1[2];
        float x2 = p2[0], y2 = p2[1], z2 = p2[2];
        float d = (x1*x1 + y1*y1 + z1*z1) + (x2*x2 + y2*y2 + z2*z2)
                - 2.f*(x1*x2 + y1*y2 + z1*z2);
        wsh[nl*128 + s] = 1.f/(d + 1e-8f);
    }
    __syncthreads();
    if (tid < 8){
        float sum = 0.f;
        for (int s = 0; s < Sq; s++) sum += wsh[tid*128 + s];
        inv8[tid] = 1.f/sum;
    }
    __syncthreads();
    float acc[8][3];
#pragma unroll
    for (int n = 0; n < 8; n++){ acc[n][0] = 0.f; acc[n][1] = 0.f; acc[n][2] = 0.f; }
    const float* vb = vis + (long)b*Sq*Cq + tid;
    for (int s = 0; s < Sq; s++){
        float v0 = vb[s*Cq], v1 = vb[s*Cq + 128], v2 = vb[s*Cq + 256];
#pragma unroll
        for (int n = 0; n < 8; n++){
            float wq = wsh[n*128 + s];
            acc[n][0] += wq*v0; acc[n][1] += wq*v1; acc[n][2] += wq*v2;
        }
    }
#pragma unroll
    for (int n = 0; n < 8; n++){
        int gn = nt*8 + n;
        const float* xr = Xf + ((long)(b*NSEQ + Tq + gn))*Cq;
        float* orow = newx + ((long)(b*Gq + gn))*Cq;
        float sf = 0.4f * inv8[n];
        orow[tid]       = xr[tid]       + sf*acc[n][0];
        orow[tid + 128] = xr[tid + 128] + sf*acc[n][1];
        orow[tid + 256] = xr[tid + 256] + sf*acc[n][2];
    }
}

// ---------------- launch ----------------
extern "C" void kernel_launch(void* const* d_in, const int* in_sizes, int n_in,
                              void* d_out, int out_size, void* d_ws, size_t ws_size,
                              hipStream_t stream)
{
    const float* x_in  = (const float*)d_in[0];
    const float* mask  = (const float*)d_in[1];
    const float* c1p   = (const float*)d_in[2];
    const float* c2p   = (const float*)d_in[3];
    const float* pe    = (const float*)d_in[5];
    const float* n1g   = (const float*)d_in[6];
    const float* n1b   = (const float*)d_in[7];
    const float* qkvw  = (const float*)d_in[8];
    const float* projw = (const float*)d_in[9];
    const float* projb = (const float*)d_in[10];
    const float* n2g   = (const float*)d_in[11];
    const float* n2b   = (const float*)d_in[12];
    const float* fc1w  = (const float*)d_in[13];
    const float* fc1b  = (const float*)d_in[14];
    const float* fc2w  = (const float*)d_in[15];
    const float* fc2b  = (const float*)d_in[16];
    const float* gate  = (const float*)d_in[17];
    const float* addw  = (const float*)d_in[18];
    const float* addb  = (const float*)d_in[19];
    const float* aduw  = (const float*)d_in[20];
    const float* adub  = (const float*)d_in[21];
    const float* ad1dw = (const float*)d_in[22];
    const float* ad1db = (const float*)d_in[23];
    const float* ad1uw = (const float*)d_in[24];
    const float* ad1ub = (const float*)d_in[25];
    const float* bng   = (const float*)d_in[26];
    const float* bnb   = (const float*)d_in[27];
    const float* a1qkvw= (const float*)d_in[28];
    const float* a1pw  = (const float*)d_in[29];
    const float* a1pb  = (const float*)d_in[30];
    const float* n3g   = (const float*)d_in[31];
    const float* n3b   = (const float*)d_in[32];
    const int*   idxp  = (const int*)d_in[33];
    const int*   cidxp = (const int*)d_in[34];

    // ---- workspace layout (bytes), total 252.4 MB ----
    char* w = (char*)d_ws;
    float* X    = (float*)w;                       // 16896x384 f32   [0, 25952256)
    u16*   WB   = (u16*)(w + 25952256);            // bf16 weights
    u16*   Bb16 = (u16*)(w + 30670848);            // 16896x384 bf16
    char*  R1   = w + 43646976;                    // 100663296 B (bias16 / hid16 / aout16)
    char*  R2   = R1 + 100663296;                  // 100663296 B (QKVg / C1 / newx)
    float* V    = (float*)(R2 + 100663296);        // 4096x384 f32

    u16* qkvw16  = WB;
    u16* projw16 = WB +  442368;
    u16* fc1w16  = WB +  589824;
    u16* fc2w16  = WB + 1179648;
    u16* a1qkv16 = WB + 1769472;
    u16* a1pw16  = WB + 2211840;

    u16*   bias16 = (u16*)R1;       // 32x512x512 bf16 (16.8 MB; dead before fc1)
    u16*   hid16  = (u16*)R1;       // 16896x1536 bf16 (MLP phase)
    u16*   aout16 = (u16*)R1;       // 131072x384 bf16 (local phase)
    u16*   QKVg   = (u16*)R2;       // 16896x1152 bf16 (global then local)
    float* C1     = (float*)R2;     // 16896x384 f32 x_fn (MLP/adapter phase)
    float* newx   = (float*)R2;     // 16384x384 f32 (interp out)

    long totX = (long)ROWS*Cq;

    conv6<<<9216, 256, 0, stream>>>(qkvw, projw, fc1w, fc2w, a1qkvw, a1pw, WB);
    conv_mask<<<32768, 256, 0, stream>>>(mask, bias16);
    build_x<<<25344, 256, 0, stream>>>(x_in, pe, X, totX);
    ln_rows<<<4224, 256, 0, stream>>>(X, n1g, n1b, Bb16, ROWS);
    gemm_bf16<<<dim3(9, 132), 256, 0, stream>>>(Bb16, qkvw16, nullptr, nullptr, QKVg,
                                                ROWS, 1152, Cq, 4);
    attn_mfma<<<1728, 256, 0, stream>>>(QKVg, bias16, Bb16);
    gemm_bf16<<<dim3(3, 132), 256, 0, stream>>>(Bb16, projw16, projb, X, nullptr,
                                                ROWS, Cq, Cq, 3);
    ln_rows<<<4224, 256, 0, stream>>>(X, n2g, n2b, Bb16, ROWS);
    gemm_bf16<<<dim3(12, 132), 256, 0, stream>>>(Bb16, fc1w16, fc1b, nullptr, hid16,
                                                 ROWS, 1536, Cq, 2);
    gemm_bf16<<<dim3(3, 132), 256, 0, stream>>>(hid16, fc2w16, fc2b, C1, nullptr,
                                                ROWS, Cq, 1536, 1);
    // fused: x = gate*adapter(x_fn)+x ; Bb16 = LN3(x)
    adapter_fused<<<4224, 256, 0, stream>>>(C1, X, addw, addb, aduw, adub, gate,
                                            n3g, n3b, X, Bb16, ROWS);
    // local branch
    gemm_bf16<<<dim3(9, 132), 256, 0, stream>>>(Bb16, a1qkv16, nullptr, nullptr, QKVg,
                                                ROWS, 1152, Cq, 4);
    local_attn<<<4096, 256, 0, stream>>>(QKVg, idxp, aout16);
    gemm_pool<<<dim3(3, 1024), 256, 0, stream>>>(aout16, a1pw16, a1pb, idxp, cidxp,
                                                 X, bng, bnb, V, Cq);
    interp_k<<<2048, 128, 0, stream>>>(X, V, c1p, c2p, newx);
    // fused final adapter -> d_out
    adapter_fused<<<4096, 256, 0, stream>>>(newx, nullptr, ad1dw, ad1db, ad1uw, ad1ub,
                                            nullptr, nullptr, nullptr,
                                            (float*)d_out, nullptr, Bq*Gq);
}

// Round 8
// 866.172 us; speedup vs baseline: 17.2152x; 1.0417x over previous
//
#include <hip/hip_runtime.h>
#include <hip/hip_bf16.h>

// ---------------- constants ----------------
#define Bq 32
#define Tq 16
#define Gq 512
#define NSEQ 528           // T + G
#define Cq 384
#define Hq 6
#define Sq 128
#define Kg 32              // GROUP_SIZE
#define ROWS (Bq*NSEQ)     // 16896
#define LROWS (Bq*Sq*Kg)   // 131072 local tokens

typedef unsigned short u16;
typedef short bf16x8 __attribute__((ext_vector_type(8)));   // 8 bf16 in 4 VGPRs
typedef float f32x4  __attribute__((ext_vector_type(4)));

__device__ __forceinline__ float gelu_f(float x){
    return 0.5f * x * (1.0f + erff(x * 0.70710678118654752f));
}
__device__ __forceinline__ u16 f2b(float x){
    union { float f; unsigned u; } v; v.f = x;
    return (u16)((v.u + 0x7fffu + ((v.u >> 16) & 1u)) >> 16);
}
__device__ __forceinline__ float b2f(u16 h){
    union { float f; unsigned u; } v; v.u = ((unsigned)h) << 16; return v.f;
}

// ---------------- fused concat(prompt,x) + LayerNorm(n1) ----------------
// writes X fp32 and LN -> bf16
__global__ void __launch_bounds__(256) build_ln(const float* __restrict__ xin,
    const float* __restrict__ pe, const float* __restrict__ gw,
    const float* __restrict__ bw, float* __restrict__ X, u16* __restrict__ out)
{
    int w = threadIdx.x >> 6, lane = threadIdx.x & 63;
    int row = blockIdx.x*4 + w;
    if (row >= ROWS) return;
    int p = row % NSEQ; int b = row / NSEQ;
    const float* src = (p < Tq) ? (pe + (long)p*Cq)
                                : (xin + ((long)b*Gq + (p - Tq))*Cq);
    float v[6]; float s = 0.f, s2 = 0.f;
#pragma unroll
    for (int j = 0; j < 6; j++){ float x = src[lane + 64*j]; v[j] = x; s += x; s2 += x*x; }
#pragma unroll
    for (int m = 1; m < 64; m <<= 1){ s += __shfl_xor(s, m); s2 += __shfl_xor(s2, m); }
    float mean = s * (1.f/384.f);
    float var  = s2 * (1.f/384.f) - mean*mean;
    float rs   = rsqrtf(var + 1e-5f);
    float* xrow = X + (long)row*Cq;
    u16* orow = out + (long)row*Cq;
#pragma unroll
    for (int j = 0; j < 6; j++){
        int c = lane + 64*j;
        xrow[c] = v[j];
        orow[c] = f2b((v[j] - mean) * rs * gw[c] + bw[c]);
    }
}

// ---------------- weight conversion fp32 -> bf16 (6 matrices) ----------------
__global__ void __launch_bounds__(256) conv6(const float* __restrict__ s0,
    const float* __restrict__ s1, const float* __restrict__ s2,
    const float* __restrict__ s3, const float* __restrict__ s4,
    const float* __restrict__ s5, u16* __restrict__ dst)
{
    long i = (long)blockIdx.x*256 + threadIdx.x;
    if (i >= 2359296) return;
    float v;
    if      (i <  442368) v = s0[i];
    else if (i <  589824) v = s1[i -  442368];
    else if (i < 1179648) v = s2[i -  589824];
    else if (i < 1769472) v = s3[i - 1179648];
    else if (i < 2211840) v = s4[i - 1769472];
    else                  v = s5[i - 2211840];
    dst[i] = f2b(v);
}

// ---------------- mask fp32 -> bf16 additive bias ----------------
__global__ void __launch_bounds__(256) conv_mask(const float* __restrict__ m,
    u16* __restrict__ bias16)
{
    long i = (long)blockIdx.x*256 + threadIdx.x;
    if (i >= (long)Bq*Gq*Gq) return;
    bias16[i] = f2b(-100000.0f * m[i]);
}

// ---------------- LayerNorm, one wave per row, bf16 out ----------------
__global__ void __launch_bounds__(256) ln_rows(const float* __restrict__ in,
    const float* __restrict__ gw, const float* __restrict__ bw,
    u16* __restrict__ out, int rows)
{
    int w = threadIdx.x >> 6, lane = threadIdx.x & 63;
    int row = blockIdx.x*4 + w;
    if (row >= rows) return;
    const float* xr = in + (long)row*Cq;
    float v[6]; float s = 0.f, s2 = 0.f;
#pragma unroll
    for (int j = 0; j < 6; j++){ float x = xr[lane + 64*j]; v[j] = x; s += x; s2 += x*x; }
#pragma unroll
    for (int m = 1; m < 64; m <<= 1){ s += __shfl_xor(s, m); s2 += __shfl_xor(s2, m); }
    float mean = s * (1.f/384.f);
    float var  = s2 * (1.f/384.f) - mean*mean;
    float rs   = rsqrtf(var + 1e-5f);
    u16* orow = out + (long)row*Cq;
#pragma unroll
    for (int j = 0; j < 6; j++){
        int c = lane + 64*j;
        orow[c] = f2b((v[j] - mean) * rs * gw[c] + bw[c]);
    }
}

// ---------------- bf16 MFMA GEMM: C = epi(A @ W^T) ----------------
// epi: 0 none->f32, 1 +bias->f32, 2 gelu(+bias)->bf16, 3 Cf += acc+bias (f32 RMW),
//      4 (+bias if given)->bf16
__global__ void __launch_bounds__(256) gemm_bf16(const u16* __restrict__ A,
    const u16* __restrict__ W, const float* __restrict__ bias,
    float* __restrict__ Cf, u16* __restrict__ Cb, int M, int N, int K, int epi)
{
    __shared__ u16 As[128*40];
    __shared__ u16 Ws[128*40];
    int t = threadIdx.x;
    int m0 = blockIdx.y*128, n0 = blockIdx.x*128;
    int wv = t >> 6, lane = t & 63;
    int wm = (wv >> 1)*64, wn = (wv & 1)*64;
    int fm = lane & 15;
    int fk = (lane >> 4) * 8;
    int sr = t >> 2;
    int sc8 = (t & 3) * 8;
    f32x4 acc[4][4];
#pragma unroll
    for (int i = 0; i < 4; i++)
#pragma unroll
        for (int j = 0; j < 4; j++) acc[i][j] = (f32x4){0.f,0.f,0.f,0.f};

    for (int k0 = 0; k0 < K; k0 += 32){
        *(uint4*)&As[sr*40 + sc8]      = *(const uint4*)(A + (long)(m0+sr)*K    + k0 + sc8);
        *(uint4*)&As[(sr+64)*40 + sc8] = *(const uint4*)(A + (long)(m0+sr+64)*K + k0 + sc8);
        *(uint4*)&Ws[sr*40 + sc8]      = *(const uint4*)(W + (long)(n0+sr)*K    + k0 + sc8);
        *(uint4*)&Ws[(sr+64)*40 + sc8] = *(const uint4*)(W + (long)(n0+sr+64)*K + k0 + sc8);
        __syncthreads();
        bf16x8 af[4], bf[4];
#pragma unroll
        for (int im = 0; im < 4; im++) af[im] = *(const bf16x8*)&As[(wm + im*16 + fm)*40 + fk];
#pragma unroll
        for (int in = 0; in < 4; in++) bf[in] = *(const bf16x8*)&Ws[(wn + in*16 + fm)*40 + fk];
#pragma unroll
        for (int im = 0; im < 4; im++)
#pragma unroll
            for (int in = 0; in < 4; in++)
                acc[im][in] = __builtin_amdgcn_mfma_f32_16x16x32_bf16(af[im], bf[in], acc[im][in], 0, 0, 0);
        __syncthreads();
    }
    int lr = lane >> 4, lc = lane & 15;
#pragma unroll
    for (int im = 0; im < 4; im++){
#pragma unroll
        for (int in = 0; in < 4; in++){
#pragma unroll
            for (int r = 0; r < 4; r++){
                int m = m0 + wm + im*16 + lr*4 + r;
                int n = n0 + wn + in*16 + lc;
                float v = acc[im][in][r];
                if (epi >= 1 && bias) v += bias[n];
                if (epi == 2) v = gelu_f(v);
                long off = (long)m*N + n;
                if (epi == 3) v += Cf[off];
                if (epi == 2 || epi == 4) Cb[off] = f2b(v);
                else                      Cf[off] = v;
            }
        }
    }
}

// ---------------- local proj GEMM with fused pool epilogue ----------------
// gathers residual/center rows from bf16 X16 (halves gather bytes vs fp32)
__global__ void __launch_bounds__(256) gemm_pool(const u16* __restrict__ A,
    const u16* __restrict__ W, const float* __restrict__ bias,
    const int* __restrict__ idx, const int* __restrict__ cidx,
    const u16* __restrict__ X16, const float* __restrict__ bng,
    const float* __restrict__ bnb, float* __restrict__ vis, int K)
{
    __shared__ u16 As[128*40];
    __shared__ u16 Ws[128*40];
    __shared__ int idxl[128];
    __shared__ int cidxl[4];
    int t = threadIdx.x;
    int m0 = blockIdx.y*128, n0 = blockIdx.x*128;
    if (t < 128) idxl[t] = idx[m0 + t];
    if (t < 4)   cidxl[t] = cidx[(m0 >> 5) + t];
    int wv = t >> 6, lane = t & 63;
    int wm = (wv >> 1)*64, wn = (wv & 1)*64;
    int fm = lane & 15;
    int fk = (lane >> 4) * 8;
    int sr = t >> 2;
    int sc8 = (t & 3) * 8;
    f32x4 acc[4][4];
#pragma unroll
    for (int i = 0; i < 4; i++)
#pragma unroll
        for (int j = 0; j < 4; j++) acc[i][j] = (f32x4){0.f,0.f,0.f,0.f};

    for (int k0 = 0; k0 < K; k0 += 32){
        *(uint4*)&As[sr*40 + sc8]      = *(const uint4*)(A + (long)(m0+sr)*K    + k0 + sc8);
        *(uint4*)&As[(sr+64)*40 + sc8] = *(const uint4*)(A + (long)(m0+sr+64)*K + k0 + sc8);
        *(uint4*)&Ws[sr*40 + sc8]      = *(const uint4*)(W + (long)(n0+sr)*K    + k0 + sc8);
        *(uint4*)&Ws[(sr+64)*40 + sc8] = *(const uint4*)(W + (long)(n0+sr+64)*K + k0 + sc8);
        __syncthreads();
        bf16x8 af[4], bf[4];
#pragma unroll
        for (int im = 0; im < 4; im++) af[im] = *(const bf16x8*)&As[(wm + im*16 + fm)*40 + fk];
#pragma unroll
        for (int in = 0; in < 4; in++) bf[in] = *(const bf16x8*)&Ws[(wn + in*16 + fm)*40 + fk];
#pragma unroll
        for (int im = 0; im < 4; im++)
#pragma unroll
            for (int in = 0; in < 4; in++)
                acc[im][in] = __builtin_amdgcn_mfma_f32_16x16x32_bf16(af[im], bf[in], acc[im][in], 0, 0, 0);
        __syncthreads();
    }
    int lr = lane >> 4, lc = lane & 15;
#pragma unroll
    for (int in = 0; in < 4; in++){
        int c = n0 + wn + in*16 + lc;
        float pb = bias[c];
        float bg = bng[c], bb = bnb[c];
#pragma unroll
        for (int gl = 0; gl < 2; gl++){
            float vmax = -3e38f, vsum = 0.f;
#pragma unroll
            for (int i2 = 0; i2 < 2; i2++){
                int im = gl*2 + i2;
#pragma unroll
                for (int r = 0; r < 4; r++){
                    int rl = wm + im*16 + lr*4 + r;
                    float val = acc[im][in][r] + pb + b2f(X16[(long)idxl[rl]*Cq + c]);
                    vmax = fmaxf(vmax, val); vsum += val;
                }
            }
            vmax = fmaxf(vmax, __shfl_xor(vmax, 16)); vsum += __shfl_xor(vsum, 16);
            vmax = fmaxf(vmax, __shfl_xor(vmax, 32)); vsum += __shfl_xor(vsum, 32);
            if (lane < 16){
                int glb = (wm >> 5) + gl;
                float lcv = vmax + vsum*(1.f/32.f);
                float u = gelu_f(lcv*bg*0.9999950000374997f + bb);
                vis[((long)(m0 >> 5) + glb)*Cq + c] =
                    u + 0.4f*b2f(X16[(long)cidxl[glb]*Cq + c]);
            }
        }
    }
}

// ---------------- flash-style MFMA global attention v3 ----------------
__global__ void __launch_bounds__(256) attn_mfma(const u16* __restrict__ QKVg,
    const u16* __restrict__ bias16, u16* __restrict__ out)
{
    __shared__ u16 Ks[32*72];
    __shared__ u16 Vt[64*40];
    __shared__ u16 Bs[64*36];
    __shared__ u16 Pb[4][16*40];
    int blk = blockIdx.x;
    int xcd = blk & 7; int r0 = blk >> 3;
    int bb = r0 & 3;  int rr = r0 >> 2;
    int h = rr % 6;   int qt = rr / 6;
    int b = xcd + 8*bb;
    int t = threadIdx.x; int w = t >> 6; int lane = t & 63;
    int fr  = lane & 15;
    int fko = (lane >> 4) * 8;
    int colj = lane & 15;
    int rgrp = (lane >> 4) * 4;
    int qb0 = qt*64;
    int q0 = qb0 + w*16;

    int qr = q0 + fr; int qrc = qr < NSEQ ? qr : NSEQ-1;
    const u16* qbase = QKVg + (long)(b*NSEQ + qrc)*1152 + h*64;
    bf16x8 aq0 = *(const bf16x8*)(qbase + fko);
    bf16x8 aq1 = *(const bf16x8*)(qbase + 32 + fko);

    f32x4 oacc[4];
#pragma unroll
    for (int d = 0; d < 4; d++) oacc[d] = (f32x4){0.f,0.f,0.f,0.f};
    float lsum[4] = {0.f, 0.f, 0.f, 0.f};

    int skey = t >> 3;
    int sd8  = (t & 7) * 8;
    int brow = t >> 2;
    int bc8  = (t & 3) * 8;

    for (int kc = 0; kc < 17; kc++){
        __syncthreads();
        {
            int j = kc*32 + skey;
            bf16x8 kv = {0,0,0,0,0,0,0,0};
            bf16x8 vv = {0,0,0,0,0,0,0,0};
            if (j < NSEQ){
                const u16* kb = QKVg + (long)(b*NSEQ + j)*1152 + 384 + h*64 + sd8;
                kv = *(const bf16x8*)kb;
                vv = *(const bf16x8*)(kb + 384);
            }
            *(bf16x8*)&Ks[skey*72 + sd8] = kv;
#pragma unroll
            for (int e = 0; e < 8; e++) Vt[(sd8+e)*40 + skey] = (u16)vv[e];
        }
        {
            int qi = qb0 + brow;
            int jj = kc*32 + bc8;
            uint4 bz = make_uint4(0u,0u,0u,0u);
            if (qi < Gq && jj < Gq)
                bz = *(const uint4*)(bias16 + ((long)b*Gq + qi)*Gq + jj);
            *(uint4*)&Bs[brow*36 + bc8] = bz;
        }
        __syncthreads();
        f32x4 s[2];
#pragma unroll
        for (int sub = 0; sub < 2; sub++){
            bf16x8 bk0 = *(const bf16x8*)&Ks[(sub*16 + fr)*72 + fko];
            bf16x8 bk1 = *(const bf16x8*)&Ks[(sub*16 + fr)*72 + 32 + fko];
            f32x4 z = (f32x4){0.f,0.f,0.f,0.f};
            z = __builtin_amdgcn_mfma_f32_16x16x32_bf16(aq0, bk0, z, 0, 0, 0);
            z = __builtin_amdgcn_mfma_f32_16x16x32_bf16(aq1, bk1, z, 0, 0, 0);
            s[sub] = z;
        }
#pragma unroll
        for (int sub = 0; sub < 2; sub++){
#pragma unroll
            for (int r = 0; r < 4; r++){
                int jj = kc*32 + sub*16 + colj;
                float sv = s[sub][r] * 0.125f
                         + b2f(Bs[(w*16 + rgrp + r)*36 + sub*16 + colj]);
                if (jj >= NSEQ) sv = -1e30f;
                float e = __expf(sv);
                lsum[r] += e;
                Pb[w][(rgrp + r)*40 + sub*16 + colj] = f2b(e);
            }
        }
        __syncthreads();
        bf16x8 ap = *(const bf16x8*)&Pb[w][fr*40 + fko];
#pragma unroll
        for (int d = 0; d < 4; d++){
            bf16x8 bv = *(const bf16x8*)&Vt[(d*16 + fr)*40 + fko];
            oacc[d] = __builtin_amdgcn_mfma_f32_16x16x32_bf16(ap, bv, oacc[d], 0, 0, 0);
        }
    }
#pragma unroll
    for (int r = 0; r < 4; r++){
#pragma unroll
        for (int mm = 1; mm < 16; mm <<= 1) lsum[r] += __shfl_xor(lsum[r], mm);
    }
#pragma unroll
    for (int r = 0; r < 4; r++){
        int qi = q0 + rgrp + r;
        if (qi < NSEQ){
            float inv = 1.0f / lsum[r];
#pragma unroll
            for (int d = 0; d < 4; d++)
                out[((long)(b*NSEQ + qi))*Cq + h*64 + d*16 + colj] = f2b(oacc[d][r]*inv);
        }
    }
}

// ---------------- fused adapter (one wave per row) ----------------
// v = gate*(gelu(xfn@dw^T+db)@uw^T + ub + xfn) + resid; Xout=v;
// optional: x16out = bf16(v); optional lng: ln16 = LN(v)
__global__ void __launch_bounds__(256) adapter_fused(const float* __restrict__ xfn,
    const float* __restrict__ resid,
    const float* __restrict__ dw, const float* __restrict__ db,
    const float* __restrict__ uw, const float* __restrict__ ub,
    const float* __restrict__ gatep,
    const float* __restrict__ lng, const float* __restrict__ lnb,
    float* __restrict__ Xout, u16* __restrict__ x16out,
    u16* __restrict__ ln16, int rows)
{
    int w = threadIdx.x >> 6, lane = threadIdx.x & 63;
    int row = blockIdx.x*4 + w;
    if (row >= rows) return;
    const float* xr = xfn + (long)row*Cq;
    float xv[6];
#pragma unroll
    for (int j = 0; j < 6; j++) xv[j] = xr[lane + 64*j];
    float hid[16];
#pragma unroll
    for (int r = 0; r < 16; r++){
        const float* dr = dw + r*Cq;
        float p = 0.f;
#pragma unroll
        for (int j = 0; j < 6; j++) p += xv[j]*dr[lane + 64*j];
#pragma unroll
        for (int mm = 1; mm < 64; mm <<= 1) p += __shfl_xor(p, mm);
        hid[r] = gelu_f(p + db[r]);
    }
    float gate = gatep ? gatep[0] : 1.0f;
    float ov[6];
    float s = 0.f, s2 = 0.f;
#pragma unroll
    for (int j = 0; j < 6; j++){
        int c = lane + 64*j;
        const float* uc = uw + c*16;
        float a = 0.f;
#pragma unroll
        for (int r = 0; r < 16; r++) a += hid[r]*uc[r];
        float v = gate * (a + ub[c] + xv[j]);
        if (resid) v += resid[(long)row*Cq + c];
        ov[j] = v;
        Xout[(long)row*Cq + c] = v;
        if (x16out) x16out[(long)row*Cq + c] = f2b(v);
        s += v; s2 += v*v;
    }
    if (lng){
#pragma unroll
        for (int m = 1; m < 64; m <<= 1){ s += __shfl_xor(s, m); s2 += __shfl_xor(s2, m); }
        float mean = s * (1.f/384.f);
        float var  = s2 * (1.f/384.f) - mean*mean;
        float rs   = rsqrtf(var + 1e-5f);
        u16* orow = ln16 + (long)row*Cq;
#pragma unroll
        for (int j = 0; j < 6; j++){
            int c = lane + 64*j;
            orow[c] = f2b((ov[j] - mean)*rs*lng[c] + lnb[c]);
        }
    }
}

// ---------------- local branch: MFMA attention, 1 group / 256-thr block ------
__global__ void __launch_bounds__(256) local_attn(const u16* __restrict__ QKVg,
    const int* __restrict__ idx, u16* __restrict__ aout16)
{
    __shared__ u16 Qs[32*72];
    __shared__ u16 Ksm[32*72];
    __shared__ u16 Vt[64*40];
    __shared__ float sc[32*36];
    __shared__ u16 Pa[32*40];
    __shared__ float linv[32];
    __shared__ int rows[32];
    int g = blockIdx.x;
    int t = threadIdx.x;
    int w = t >> 6, lane = t & 63;
    if (t < 32) rows[t] = idx[g*Kg + t];
    __syncthreads();
    int srow = t & 31;
    int d8   = (t >> 5) * 8;
    int fr = lane & 15, fko = (lane >> 4)*8;
    int colj = lane & 15, rgrp = (lane >> 4)*4;
    int it = w >> 1, jt = w & 1;
    int smrow = w*8 + (lane >> 3);
    int smc   = (lane & 7) * 4;

    for (int h = 0; h < Hq; h++){
        {
            const u16* base = QKVg + (long)rows[srow]*1152 + h*64 + d8;
            bf16x8 qv = *(const bf16x8*)(base);
            bf16x8 kv = *(const bf16x8*)(base + 384);
            bf16x8 vv = *(const bf16x8*)(base + 768);
            *(bf16x8*)&Qs[srow*72 + d8]  = qv;
            *(bf16x8*)&Ksm[srow*72 + d8] = kv;
#pragma unroll
            for (int e = 0; e < 8; e++) Vt[(d8+e)*40 + srow] = (u16)vv[e];
        }
        __syncthreads();
        {
            bf16x8 a0 = *(const bf16x8*)&Qs[(it*16+fr)*72 + fko];
            bf16x8 a1 = *(const bf16x8*)&Qs[(it*16+fr)*72 + 32 + fko];
            bf16x8 b0 = *(const bf16x8*)&Ksm[(jt*16+fr)*72 + fko];
            bf16x8 b1 = *(const bf16x8*)&Ksm[(jt*16+fr)*72 + 32 + fko];
            f32x4 z = (f32x4){0.f,0.f,0.f,0.f};
            z = __builtin_amdgcn_mfma_f32_16x16x32_bf16(a0, b0, z, 0, 0, 0);
            z = __builtin_amdgcn_mfma_f32_16x16x32_bf16(a1, b1, z, 0, 0, 0);
#pragma unroll
            for (int r = 0; r < 4; r++)
                sc[(it*16 + rgrp + r)*36 + jt*16 + colj] = z[r]*0.125f;
        }
        __syncthreads();
        {
            float4 s4 = *(const float4*)&sc[smrow*36 + smc];
            float mx = fmaxf(fmaxf(s4.x, s4.y), fmaxf(s4.z, s4.w));
#pragma unroll
            for (int mm = 1; mm < 8; mm <<= 1) mx = fmaxf(mx, __shfl_xor(mx, mm));
            float p0 = __expf(s4.x - mx), p1 = __expf(s4.y - mx);
            float p2 = __expf(s4.z - mx), p3 = __expf(s4.w - mx);
            float sm = p0 + p1 + p2 + p3;
#pragma unroll
            for (int mm = 1; mm < 8; mm <<= 1) sm += __shfl_xor(sm, mm);
            if ((lane & 7) == 0) linv[smrow] = 1.0f / sm;
            Pa[smrow*40 + smc + 0] = f2b(p0);
            Pa[smrow*40 + smc + 1] = f2b(p1);
            Pa[smrow*40 + smc + 2] = f2b(p2);
            Pa[smrow*40 + smc + 3] = f2b(p3);
        }
        __syncthreads();
        {
            bf16x8 ap = *(const bf16x8*)&Pa[(it*16+fr)*40 + fko];
#pragma unroll
            for (int dd = 0; dd < 2; dd++){
                int dt = jt + dd*2;
                bf16x8 bv = *(const bf16x8*)&Vt[(dt*16+fr)*40 + fko];
                f32x4 o = (f32x4){0.f,0.f,0.f,0.f};
                o = __builtin_amdgcn_mfma_f32_16x16x32_bf16(ap, bv, o, 0, 0, 0);
#pragma unroll
                for (int r = 0; r < 4; r++){
                    int row = it*16 + rgrp + r;
                    aout16[((long)(g*32 + row))*Cq + h*64 + dt*16 + colj] =
                        f2b(o[r] * linv[row]);
                }
            }
        }
        __syncthreads();
    }
}

// ---------------- inverse-distance interp: 8 points/block share vis reads ----
__global__ void __launch_bounds__(128) interp_k(const float* __restrict__ Xf,
    const float* __restrict__ vis, const float* __restrict__ c1,
    const float* __restrict__ c2, float* __restrict__ newx)
{
    __shared__ float wsh[8*128];
    __shared__ float inv8[8];
    int blk = blockIdx.x;
    int b = blk >> 6, nt = blk & 63;
    int tid = threadIdx.x;
#pragma unroll
    for (int i = 0; i < 8; i++){
        int id = tid + i*128;
        int nl = id >> 7, s = id & 127;
        const float* p1 = c1 + ((long)b*Gq + nt*8 + nl)*3;
        const float* p2 = c2 + ((long)b*Sq + s)*3;
        float x1 = p1[0], y1 = p1[1], z1 = p1[2];
        float x2 = p2[0], y2 = p2[1], z2 = p2[2];
        float d = (x1*x1 + y1*y1 + z1*z1) + (x2*x2 + y2*y2 + z2*z2)
                - 2.f*(x1*x2 + y1*y2 + z1*z2);
        wsh[nl*128 + s] = 1.f/(d + 1e-8f);
    }
    __syncthreads();
    if (tid < 8){
        float sum = 0.f;
        for (int s = 0; s < Sq; s++) sum += wsh[tid*128 + s];
        inv8[tid] = 1.f/sum;
    }
    __syncthreads();
    float acc[8][3];
#pragma unroll
    for (int n = 0; n < 8; n++){ acc[n][0] = 0.f; acc[n][1] = 0.f; acc[n][2] = 0.f; }
    const float* vb = vis + (long)b*Sq*Cq + tid;
    for (int s = 0; s < Sq; s++){
        float v0 = vb[s*Cq], v1 = vb[s*Cq + 128], v2 = vb[s*Cq + 256];
#pragma unroll
        for (int n = 0; n < 8; n++){
            float wq = wsh[n*128 + s];
            acc[n][0] += wq*v0; acc[n][1] += wq*v1; acc[n][2] += wq*v2;
        }
    }
#pragma unroll
    for (int n = 0; n < 8; n++){
        int gn = nt*8 + n;
        const float* xr = Xf + ((long)(b*NSEQ + Tq + gn))*Cq;
        float* orow = newx + ((long)(b*Gq + gn))*Cq;
        float sf = 0.4f * inv8[n];
        orow[tid]       = xr[tid]       + sf*acc[n][0];
        orow[tid + 128] = xr[tid + 128] + sf*acc[n][1];
        orow[tid + 256] = xr[tid + 256] + sf*acc[n][2];
    }
}

// ---------------- launch ----------------
extern "C" void kernel_launch(void* const* d_in, const int* in_sizes, int n_in,
                              void* d_out, int out_size, void* d_ws, size_t ws_size,
                              hipStream_t stream)
{
    const float* x_in  = (const float*)d_in[0];
    const float* mask  = (const float*)d_in[1];
    const float* c1p   = (const float*)d_in[2];
    const float* c2p   = (const float*)d_in[3];
    const float* pe    = (const float*)d_in[5];
    const float* n1g   = (const float*)d_in[6];
    const float* n1b   = (const float*)d_in[7];
    const float* qkvw  = (const float*)d_in[8];
    const float* projw = (const float*)d_in[9];
    const float* projb = (const float*)d_in[10];
    const float* n2g   = (const float*)d_in[11];
    const float* n2b   = (const float*)d_in[12];
    const float* fc1w  = (const float*)d_in[13];
    const float* fc1b  = (const float*)d_in[14];
    const float* fc2w  = (const float*)d_in[15];
    const float* fc2b  = (const float*)d_in[16];
    const float* gate  = (const float*)d_in[17];
    const float* addw  = (const float*)d_in[18];
    const float* addb  = (const float*)d_in[19];
    const float* aduw  = (const float*)d_in[20];
    const float* adub  = (const float*)d_in[21];
    const float* ad1dw = (const float*)d_in[22];
    const float* ad1db = (const float*)d_in[23];
    const float* ad1uw = (const float*)d_in[24];
    const float* ad1ub = (const float*)d_in[25];
    const float* bng   = (const float*)d_in[26];
    const float* bnb   = (const float*)d_in[27];
    const float* a1qkvw= (const float*)d_in[28];
    const float* a1pw  = (const float*)d_in[29];
    const float* a1pb  = (const float*)d_in[30];
    const float* n3g   = (const float*)d_in[31];
    const float* n3b   = (const float*)d_in[32];
    const int*   idxp  = (const int*)d_in[33];
    const int*   cidxp = (const int*)d_in[34];

    // ---- workspace layout (bytes), total 252.4 MB ----
    char* w = (char*)d_ws;
    float* X    = (float*)w;                       // 16896x384 f32   [0, 25952256)
    u16*   WB   = (u16*)(w + 25952256);            // bf16 weights
    u16*   Bb16 = (u16*)(w + 30670848);            // 16896x384 bf16
    char*  R1   = w + 43646976;                    // 100663296 B (bias16 / hid16 / aout16)
    char*  R2   = R1 + 100663296;                  // 100663296 B (QKVg/C1/newx + X16)
    float* V    = (float*)(R2 + 100663296);        // 4096x384 f32

    u16* qkvw16  = WB;
    u16* projw16 = WB +  442368;
    u16* fc1w16  = WB +  589824;
    u16* fc2w16  = WB + 1179648;
    u16* a1qkv16 = WB + 1769472;
    u16* a1pw16  = WB + 2211840;

    u16*   bias16 = (u16*)R1;       // 32x512x512 bf16 (dead before fc1)
    u16*   hid16  = (u16*)R1;       // 16896x1536 bf16 (MLP phase)
    u16*   aout16 = (u16*)R1;       // 131072x384 bf16 (local phase)
    u16*   QKVg   = (u16*)R2;       // 16896x1152 bf16 [R2, R2+38.9MB)
    float* C1     = (float*)R2;     // 16896x384 f32 x_fn (dead after adapter#1)
    float* newx   = (float*)R2;     // 16384x384 f32 (interp out; QKVg dead then)
    u16*   X16    = (u16*)(R2 + 41943040);  // 16896x384 bf16 [40MB, 53MB) of R2

    conv6<<<9216, 256, 0, stream>>>(qkvw, projw, fc1w, fc2w, a1qkvw, a1pw, WB);
    conv_mask<<<32768, 256, 0, stream>>>(mask, bias16);
    build_ln<<<4224, 256, 0, stream>>>(x_in, pe, n1g, n1b, X, Bb16);
    gemm_bf16<<<dim3(9, 132), 256, 0, stream>>>(Bb16, qkvw16, nullptr, nullptr, QKVg,
                                                ROWS, 1152, Cq, 4);
    attn_mfma<<<1728, 256, 0, stream>>>(QKVg, bias16, Bb16);
    gemm_bf16<<<dim3(3, 132), 256, 0, stream>>>(Bb16, projw16, projb, X, nullptr,
                                                ROWS, Cq, Cq, 3);
    ln_rows<<<4224, 256, 0, stream>>>(X, n2g, n2b, Bb16, ROWS);
    gemm_bf16<<<dim3(12, 132), 256, 0, stream>>>(Bb16, fc1w16, fc1b, nullptr, hid16,
                                                 ROWS, 1536, Cq, 2);
    gemm_bf16<<<dim3(3, 132), 256, 0, stream>>>(hid16, fc2w16, fc2b, C1, nullptr,
                                                ROWS, Cq, 1536, 1);
    // fused: x = gate*adapter(x_fn)+x ; X16 = bf16(x); Bb16 = LN3(x)
    adapter_fused<<<4224, 256, 0, stream>>>(C1, X, addw, addb, aduw, adub, gate,
                                            n3g, n3b, X, X16, Bb16, ROWS);
    // local branch
    gemm_bf16<<<dim3(9, 132), 256, 0, stream>>>(Bb16, a1qkv16, nullptr, nullptr, QKVg,
                                                ROWS, 1152, Cq, 4);
    local_attn<<<4096, 256, 0, stream>>>(QKVg, idxp, aout16);
    gemm_pool<<<dim3(3, 1024), 256, 0, stream>>>(aout16, a1pw16, a1pb, idxp, cidxp,
                                                 X16, bng, bnb, V, Cq);
    interp_k<<<2048, 128, 0, stream>>>(X, V, c1p, c2p, newx);
    // fused final adapter -> d_out
    adapter_fused<<<4096, 256, 0, stream>>>(newx, nullptr, ad1dw, ad1db, ad1uw, ad1ub,
                                            nullptr, nullptr, nullptr,
                                            (float*)d_out, nullptr, nullptr, Bq*Gq);
}